// Round 6
// baseline (622.813 us; speedup 1.0000x reference)
//
#include <hip/hip_runtime.h>
#include <math.h>
#include <stdint.h>

#define N_NODES 50000
#define FEAT    256
#define EDGES   200000
#define HEADS   4
#define CH      128
#define HID     512   // HEADS*CH
#define NGRAPH  256
#define NCLS    10

typedef unsigned short ushort_t;
typedef unsigned int uint_t;
typedef __attribute__((ext_vector_type(8))) short bf16x8;
typedef __attribute__((ext_vector_type(4))) float f32x4;
typedef __attribute__((ext_vector_type(2))) float f32x2;

__device__ __forceinline__ ushort_t f2bf(float f) {  // round-to-nearest-even
  uint_t u = __float_as_uint(f);
  u += 0x7FFF + ((u >> 16) & 1);
  return (ushort_t)(u >> 16);
}
__device__ __forceinline__ float bf2f(ushort_t h) {
  return __uint_as_float(((uint_t)h) << 16);
}
__device__ __forceinline__ void unpack8(uint4 w, float* f) {
  f[0] = bf2f((ushort_t)w.x); f[1] = bf2f((ushort_t)(w.x >> 16));
  f[2] = bf2f((ushort_t)w.y); f[3] = bf2f((ushort_t)(w.y >> 16));
  f[4] = bf2f((ushort_t)w.z); f[5] = bf2f((ushort_t)(w.z >> 16));
  f[6] = bf2f((ushort_t)w.w); f[7] = bf2f((ushort_t)(w.w >> 16));
}
// 8 x fp8(e4m3) -> 8 x f32 via v_cvt_pk_f32_fp8 (4 insts)
__device__ __forceinline__ void unpack8_fp8(uint2 w, float* f) {
  f32x2 a = __builtin_amdgcn_cvt_pk_f32_fp8((int)w.x, false);
  f32x2 b = __builtin_amdgcn_cvt_pk_f32_fp8((int)w.x, true);
  f32x2 c = __builtin_amdgcn_cvt_pk_f32_fp8((int)w.y, false);
  f32x2 d = __builtin_amdgcn_cvt_pk_f32_fp8((int)w.y, true);
  f[0] = a[0]; f[1] = a[1]; f[2] = b[0]; f[3] = b[1];
  f[4] = c[0]; f[5] = c[1]; f[6] = d[0]; f[7] = d[1];
}
__device__ __forceinline__ uint_t pack4_fp8(float f0, float f1, float f2, float f3) {
  int v = __builtin_amdgcn_cvt_pk_fp8_f32(f0, f1, 0, false);
  v = __builtin_amdgcn_cvt_pk_fp8_f32(f2, f3, v, true);
  return (uint_t)v;
}

// ---------------------------------------------------------------------------
// L2 GEMM — round-3 kernel VERBATIM (measured passing: 119.4 us, MfmaUtil 33%).
// 256x256 tile, BK=32, 8 waves (2Mx4N, per-wave 128x64), 512 threads,
// triple-buffered 96 KB LDS, single-region K-tile loop with counted vmcnt(4).
// Round-16 note: the unmeasured 256x128 2-block variant killed the container
// twice (rounds 4/5); reverting to this verified form to bank the L1 win and
// isolate infra-vs-source next round.
// Output rows, byte-addressed, per-128-col-block mapping:
//  mode 1 (L1 pair): row 1536 B, per head (768 B): q bf16 @0, s bf16 @256,
//                    k fp8 @512, v fp8 @640.  Weight col order q,k,v,s.
//  mode 2 (L2 all):  row 2304 B, per head (512 B, hh=0..3): q bf16 @hh*512,
//                    k fp8 @+256, v fp8 @+384; skip bf16 @2048
//                    (cols [768,896) in W2t order h0 h1 | skip | h2 h3).
// ---------------------------------------------------------------------------
__global__ __launch_bounds__(512, 2) void gemm_bt(
    const ushort_t* __restrict__ A, const ushort_t* __restrict__ Bt,
    const float* __restrict__ bias, char* __restrict__ Cb,
    int M, int K, int nct, int Ntot, int mode) {
  __shared__ __align__(16) ushort_t smem[49152];   // 3 x 32 KB K-tile buffers
  const int tid = threadIdx.x;
  const int lane = tid & 63, wave = tid >> 6;
  const int wr = wave >> 2, wc = wave & 3;         // 2M x 4N waves

  // XCD-aware decode: rowTile = grp*8 + (b%8), ct = (b/8)%nct
  int b = blockIdx.x;
  int per = nct << 3;
  int grp = b / per;
  int rem = b - grp * per;
  int rloc = rem & 7;
  int ct = rem >> 3;
  const int rowBase = (grp * 8 + rloc) * 256;
  const int colBase = ct * 256;
  if (rowBase >= M) return;

  // ---- staging addresses: 2 A slots + 2 B slots per thread per K-tile ----
  const int s0 = tid, s1 = tid + 512;              // slot = row*4 + pos
  const int rl0 = s0 >> 2, cg0 = (s0 & 3) ^ ((rl0 >> 1) & 3);
  const int rl1 = s1 >> 2, cg1 = (s1 & 3) ^ ((rl1 >> 1) & 3);
  int ra0 = rowBase + rl0; ra0 = ra0 < M ? ra0 : M - 1;       // M-tail clamp
  int ra1 = rowBase + rl1; ra1 = ra1 < M ? ra1 : M - 1;
  int nb0 = colBase + rl0; nb0 = nb0 < Ntot ? nb0 : Ntot - 1; // N-tail clamp
  int nb1 = colBase + rl1; nb1 = nb1 < Ntot ? nb1 : Ntot - 1;
  const ushort_t* pa0 = A + (size_t)ra0 * K + cg0 * 8;
  const ushort_t* pa1 = A + (size_t)ra1 * K + cg1 * 8;
  const ushort_t* pb0 = Bt + (size_t)nb0 * K + cg0 * 8;
  const ushort_t* pb1 = Bt + (size_t)nb1 * K + cg1 * 8;
  const int dA0 = s0 * 8, dA1 = s1 * 8;            // LDS element offsets

#define GLL(gp, loff)  __builtin_amdgcn_global_load_lds( \
      (const __attribute__((address_space(1))) uint_t*)(gp), \
      (__attribute__((address_space(3))) uint_t*)(smem + (loff)), 16, 0, 0)

  const int nt = K >> 5;                           // K-tiles of 32
  // ---- prologue: stage tiles 0 (buf0) and 1 (buf1) ----
  GLL(pa0, dA0);                GLL(pa1, dA1);
  GLL(pb0, 8192 + dA0);         GLL(pb1, 8192 + dA1);
  GLL(pa0 + 32, 16384 + dA0);   GLL(pa1 + 32, 16384 + dA1);
  GLL(pb0 + 32, 24576 + dA0);   GLL(pb1 + 32, 24576 + dA1);
  pa0 += 64; pa1 += 64; pb0 += 64; pb1 += 64;      // now point at tile 2

  // ---- fragment read offsets (element units) ----
  const int fr = lane & 15, c0 = lane >> 4;
  const int pswz = (c0 ^ ((fr >> 1) & 3)) * 8;     // same swizzle as stage
  const int aOff = (wr * 128 + fr) * 32 + pswz;
  const int bOff = 8192 + (wc * 64 + fr) * 32 + pswz;

  f32x4 acc[8][4] = {};
  asm volatile("s_waitcnt vmcnt(4)" ::: "memory"); // tile0 landed, tile1 in flight
  __builtin_amdgcn_s_barrier();
  __builtin_amdgcn_sched_barrier(0);

  int cur = 0, nxt = 2;
  for (int t = 0; t < nt; ++t) {
    const ushort_t* bufc = smem + cur * 16384;
    const bool pf = (t + 2) < nt;
    bf16x8 af[8], bfr[4];
    // reads ordered so the first MFMA (af[0] x bfr[0]) unblocks earliest
    af[0] = *(const bf16x8*)(bufc + aOff);
#pragma unroll
    for (int j = 0; j < 4; ++j) bfr[j] = *(const bf16x8*)(bufc + bOff + j * 512);
#pragma unroll
    for (int i = 1; i < 8; ++i) af[i] = *(const bf16x8*)(bufc + aOff + i * 512);
    // prefetch tile t+2 into buf[nxt] (dead since its lgkmcnt(0) last tile)
    if (pf) {
      GLL(pa0, nxt * 16384 + dA0);        GLL(pa1, nxt * 16384 + dA1);
      GLL(pb0, nxt * 16384 + 8192 + dA0); GLL(pb1, nxt * 16384 + 8192 + dA1);
      pa0 += 32; pa1 += 32; pb0 += 32; pb1 += 32;
    }
    // 32 MFMA in one region: compiler inserts fine-grained lgkm waits and
    // overlaps the ds_read drain + GLL issue with the accumulate chain.
#pragma unroll
    for (int i = 0; i < 8; ++i)
#pragma unroll
      for (int j = 0; j < 4; ++j)
        acc[i][j] = __builtin_amdgcn_mfma_f32_16x16x32_bf16(af[i], bfr[j], acc[i][j], 0, 0, 0);
    asm volatile("s_waitcnt lgkmcnt(0)" ::: "memory");  // all reads of bufc drained
    if (pf)                asm volatile("s_waitcnt vmcnt(4)" ::: "memory"); // t+1 landed
    else if (t + 1 < nt)   asm volatile("s_waitcnt vmcnt(0)" ::: "memory"); // tail drain
    __builtin_amdgcn_s_barrier();
    __builtin_amdgcn_sched_barrier(0);
    cur = cur == 2 ? 0 : cur + 1;
    nxt = nxt == 2 ? 0 : nxt + 1;
  }
#undef GLL

  // ---- output block -> (byte offset, dtype), wave-uniform ----
  const int colE = colBase + ((wc >> 1) << 7);     // this wave's 128-col block
  const int wcE = wc & 1;                          // 64-col half within block
  const bool colValid = colE < Ntot;
  int koff, rowStride, isfp8;
  if (mode == 1) {
    rowStride = 1536;
    int hh = colE >> 9, sel = (colE >> 7) & 3;     // q,k,v,s
    koff = hh * 768 + (sel == 0 ? 0 : sel == 3 ? 256 : sel == 1 ? 512 : 640);
    isfp8 = (sel == 1 || sel == 2);
  } else {
    rowStride = 2304;
    if (colE >= 768 && colE < 896) { koff = 2048; isfp8 = 0; }
    else if (colValid) {
      int n2 = (colE < 768) ? colE : colE - 896;
      int hb = (colE < 768) ? 0 : 2;
      int hh = hb + n2 / 384, r = n2 % 384, sel = r >> 7;  // q,k,v
      koff = hh * 512 + (sel == 0 ? 0 : sel == 1 ? 256 : 384);
      isfp8 = (sel >= 1);
    } else { koff = 0; isfp8 = 0; }
  }

  // Epilogue: per-wave LDS repack in four 32-row halves (4 KB/wave region).
  // C/D layout col=lane&15, row=(lane>>4)*4+reg (m89-verified).
  __builtin_amdgcn_s_barrier();                    // all waves done with bufs
  __builtin_amdgcn_sched_barrier(0);
  ushort_t* wbuf = smem + wave * 2048;             // 32 x 64 bf16
  const int rq = lane >> 4, fc = lane & 15;
  float bv[4];
#pragma unroll
  for (int j = 0; j < 4; ++j) {
    int bi = colBase + wc * 64 + j * 16 + fc;
    bv[j] = bias[bi < Ntot ? bi : Ntot - 1];
  }
#pragma unroll
  for (int h = 0; h < 4; ++h) {
#pragma unroll
    for (int ii = 0; ii < 2; ++ii) {
      int i = h * 2 + ii;
#pragma unroll
      for (int j = 0; j < 4; ++j)
#pragma unroll
        for (int r = 0; r < 4; ++r) {
          int rl = ii * 16 + rq * 4 + r;          // 0..31 ; (rl>>2)&3 == rq
          int cl = j * 16 + fc;                   // 0..63
          int cs = cl ^ (rq << 4);                // rq -> bank octet
          wbuf[rl * 64 + cs] = f2bf(acc[i][j][r] + bv[j]);
        }
    }
    // read back: lanes 0..7 cover all 32 banks (ci*4); remap chunk by rq
    int ci = lane & 7;
    int rbase = lane >> 3;                         // 0..7
#pragma unroll
    for (int rg = 0; rg < 4; ++rg) {
      int rr = rg * 8 + rbase;                     // 0..31
      int rowg = rowBase + wr * 128 + h * 32 + rr;
      int cg = ci ^ (((rr >> 2) & 3) << 1);
      uint4 val = *(const uint4*)(wbuf + rr * 64 + (ci << 3));
      if (rowg < M && colValid) {
        char* dstRow = Cb + (size_t)rowg * rowStride + koff;
        if (!isfp8) {
          *(uint4*)(dstRow + (wcE * 64 + cg * 8) * 2) = val;
        } else {
          float f[8];
          f[0] = bf2f((ushort_t)val.x); f[1] = bf2f((ushort_t)(val.x >> 16));
          f[2] = bf2f((ushort_t)val.y); f[3] = bf2f((ushort_t)(val.y >> 16));
          f[4] = bf2f((ushort_t)val.z); f[5] = bf2f((ushort_t)(val.z >> 16));
          f[6] = bf2f((ushort_t)val.w); f[7] = bf2f((ushort_t)(val.w >> 16));
          uint2 o;
          o.x = pack4_fp8(f[0], f[1], f[2], f[3]);
          o.y = pack4_fp8(f[4], f[5], f[6], f[7]);
          *(uint2*)(dstRow + wcE * 64 + cg * 8) = o;
        }
      }
    }
  }
}

// ---------------------------------------------------------------------------
// L1 GEMM (round-0 128x128 kernel, passed at 596.7 us; mode-1 hardcoded).
// Round 0->3 attribution: the 256^2 conversion cost L1 ~+16 us (K=256/N=1024:
// too few blocks, 1 resident/CU). This form: 16 KB LDS, ~2.4 blocks/CU.
// Output: row 1536 B, per head (768 B): q bf16 @0, s bf16 @256, k fp8 @512,
// v fp8 @640. Weight col order q,k,v,s; hh = local head within the pair.
// ---------------------------------------------------------------------------
__global__ __launch_bounds__(256) void gemm_bt1(
    const ushort_t* __restrict__ A, const ushort_t* __restrict__ Bt,
    const float* __restrict__ bias, char* __restrict__ Cb,
    int M, int K, int ncol) {
  __shared__ __align__(16) ushort_t smem[8192];   // 16 KB total
  ushort_t* sA = smem;                            // 128 x 32
  ushort_t* sB = smem + 4096;                     // 128 x 32
  const int tid = threadIdx.x;
  const int lane = tid & 63, wave = tid >> 6;
  const int wr = wave >> 1, wc = wave & 1;

  int b = blockIdx.x;
  int per = ncol << 3;
  int grp = b / per;
  int rem = b - grp * per;
  int rloc = rem & 7;
  int c = rem >> 3;
  const int rowBase = (grp * 8 + rloc) * 128;
  const int colBase = c * 128;
  if (rowBase >= M) return;

  f32x4 acc[4][4] = {};

  for (int k0 = 0; k0 < K; k0 += 32) {
#pragma unroll
    for (int l = 0; l < 2; ++l) {
      int slot = l * 256 + tid;           // 0..511
      int rl = slot >> 2;                 // row/col 0..127
      int pos = slot & 3;                 // stored chunk slot
      int cg = pos ^ ((rl >> 1) & 3);     // swizzled global chunk
      {
        int row = rowBase + rl;
        row = row < M ? row : M - 1;      // clamp tail (epilogue guards)
        const ushort_t* gp = A + (size_t)row * K + k0 + cg * 8;
        __builtin_amdgcn_global_load_lds(
            (const __attribute__((address_space(1))) uint_t*)gp,
            (__attribute__((address_space(3))) uint_t*)(sA + slot * 8),
            16, 0, 0);
      }
      {
        int n = colBase + rl;
        const ushort_t* gp = Bt + (size_t)n * K + k0 + cg * 8;
        __builtin_amdgcn_global_load_lds(
            (const __attribute__((address_space(1))) uint_t*)gp,
            (__attribute__((address_space(3))) uint_t*)(sB + slot * 8),
            16, 0, 0);
      }
    }
    __syncthreads();
    const int fr = lane & 15, c0 = lane >> 4;
    bf16x8 af[4], bfr[4];
#pragma unroll
    for (int i = 0; i < 4; ++i) {
      int r = wr * 64 + i * 16 + fr;
      af[i] = *(const bf16x8*)(sA + r * 32 + ((c0 ^ ((r >> 1) & 3)) * 8));
      int n = wc * 64 + i * 16 + fr;
      bfr[i] = *(const bf16x8*)(sB + n * 32 + ((c0 ^ ((n >> 1) & 3)) * 8));
    }
#pragma unroll
    for (int i = 0; i < 4; ++i)
#pragma unroll
      for (int j = 0; j < 4; ++j)
        acc[i][j] = __builtin_amdgcn_mfma_f32_16x16x32_bf16(af[i], bfr[j], acc[i][j], 0, 0, 0);
    __syncthreads();
  }

  // ---- output block -> (byte offset, dtype), mode-1 mapping ----
  const int hh = colBase >> 9, sel = (colBase >> 7) & 3;   // q,k,v,s
  const int koff = hh * 768 + (sel == 0 ? 0 : sel == 3 ? 256 : sel == 1 ? 512 : 640);
  const int isfp8 = (sel == 1 || sel == 2);

  // Epilogue: per-wave LDS repack in two 32-row halves (4 KB/wave region).
  ushort_t* wbuf = smem + wave * 2048;    // 32 x 64 bf16
  const int rq = lane >> 4, fc = lane & 15;
  float bv[4];
#pragma unroll
  for (int j = 0; j < 4; ++j) bv[j] = bias[colBase + wc * 64 + j * 16 + fc];
#pragma unroll
  for (int h = 0; h < 2; ++h) {
#pragma unroll
    for (int ii = 0; ii < 2; ++ii) {
      int i = h * 2 + ii;
#pragma unroll
      for (int j = 0; j < 4; ++j)
#pragma unroll
        for (int r = 0; r < 4; ++r) {
          int rl = ii * 16 + rq * 4 + r;          // 0..31 ; (rl>>2)&3 == rq
          int cl = j * 16 + fc;                   // 0..63
          int cs = cl ^ (rq << 4);                // rq -> bank octet
          wbuf[rl * 64 + cs] = f2bf(acc[i][j][r] + bv[j]);
        }
    }
    int ci = lane & 7;
    int rbase = lane >> 3;                         // 0..7
#pragma unroll
    for (int rg = 0; rg < 4; ++rg) {
      int rr = rg * 8 + rbase;                     // 0..31
      int rowg = rowBase + wr * 64 + h * 32 + rr;
      int cg = ci ^ (((rr >> 2) & 3) << 1);
      uint4 val = *(const uint4*)(wbuf + rr * 64 + (ci << 3));
      if (rowg < M) {
        char* dstRow = Cb + (size_t)rowg * 1536 + koff;
        if (!isfp8) {
          *(uint4*)(dstRow + (wc * 64 + cg * 8) * 2) = val;
        } else {
          float f[8];
          f[0] = bf2f((ushort_t)val.x); f[1] = bf2f((ushort_t)(val.x >> 16));
          f[2] = bf2f((ushort_t)val.y); f[3] = bf2f((ushort_t)(val.y >> 16));
          f[4] = bf2f((ushort_t)val.z); f[5] = bf2f((ushort_t)(val.z >> 16));
          f[6] = bf2f((ushort_t)val.w); f[7] = bf2f((ushort_t)(val.w >> 16));
          uint2 o;
          o.x = pack4_fp8(f[0], f[1], f[2], f[3]);
          o.y = pack4_fp8(f[4], f[5], f[6], f[7]);
          *(uint2*)(dstRow + wc * 64 + cg * 8) = o;
        }
      }
    }
  }
}

// ---------------------------------------------------------------------------
// prep_all: one launch, four independent regions branch on blockIdx.x:
//  [0, NB_CVT)           : x fp32 -> bf16 (vectorized)
//  [NB_CVT, +NB_TP)      : weight 32x32 tile transposes -> W1t / W2t
//  [.., +NB_BIAS)        : bias permute -> Bh1 / Bh2
//  [.., +NB_ZERO)        : zero deg/counter/gstart/gend
// ---------------------------------------------------------------------------
#define L1_W   (2048 * FEAT)
#define L2_W   (1664 * HID)
#define T1     512   // (2048/32)*(256/32)
#define T2     832   // (1664/32)*(512/32)
#define NB_CVT  12500
#define NB_TP   (T1 + T2)
#define NB_BIAS 15
#define NB_ZERO 196

__global__ __launch_bounds__(256) void prep_all(
    const float* __restrict__ x, ushort_t* __restrict__ xb,
    const float* __restrict__ Wq1, const float* __restrict__ Wk1,
    const float* __restrict__ Wv1, const float* __restrict__ Ws1,
    const float* __restrict__ Wq2, const float* __restrict__ Wk2,
    const float* __restrict__ Wv2, const float* __restrict__ Ws2,
    const float* __restrict__ bq1, const float* __restrict__ bk1,
    const float* __restrict__ bv1, const float* __restrict__ bs1,
    const float* __restrict__ bq2, const float* __restrict__ bk2,
    const float* __restrict__ bv2, const float* __restrict__ bs2,
    ushort_t* __restrict__ W1t, ushort_t* __restrict__ W2t,
    float* __restrict__ Bh1, float* __restrict__ Bh2,
    int* __restrict__ deg, int* __restrict__ counter,
    int* __restrict__ gstart, int* __restrict__ gend) {
  __shared__ float tile[32][33];
  int blk = blockIdx.x;
  if (blk < NB_CVT) {
    int i = blk * 256 + threadIdx.x;            // n4 = 3.2M exactly
    float4 f = *(const float4*)(x + (size_t)i * 4);
    uint_t lo = (uint_t)f2bf(f.x) | ((uint_t)f2bf(f.y) << 16);
    uint_t hi = (uint_t)f2bf(f.z) | ((uint_t)f2bf(f.w) << 16);
    ((uint2*)xb)[i] = make_uint2(lo, hi);
    return;
  }
  blk -= NB_CVT;
  if (blk < NB_TP) {
    int t = blk;
    const float* W; int ldw, c0, n0, k0, ldk; ushort_t* dst;
    if (t < T1) {
      int nb = t >> 3, kb = t & 7;
      n0 = nb * 32; k0 = kb * 32; ldk = FEAT; dst = W1t;
      int p = n0 >> 10, n1 = n0 & 1023, hh = n1 >> 9, sel = (n1 >> 7) & 3;
      c0 = (2 * p + hh) * CH + (n1 & (CH - 1));
      W = sel == 0 ? Wq1 : sel == 1 ? Wk1 : sel == 2 ? Wv1 : Ws1;
      ldw = HID;
    } else {
      t -= T1;
      int nb = t >> 4, kb = t & 15;
      n0 = nb * 32; k0 = kb * 32; ldk = HID; dst = W2t;
      if (n0 < 768 || n0 >= 896) {
        int n2 = (n0 < 768) ? n0 : n0 - 896;
        int hb = (n0 < 768) ? 0 : 2;
        int hh = hb + n2 / 384, r = n2 % 384, sel = r >> 7;
        c0 = hh * CH + (r & (CH - 1));
        W = sel == 0 ? Wq2 : sel == 1 ? Wk2 : Wv2;
        ldw = HID;
      } else {
        c0 = n0 - 768; W = Ws2; ldw = CH;
      }
    }
    int col = threadIdx.x & 31, rw = threadIdx.x >> 5;
#pragma unroll
    for (int ph = 0; ph < 4; ++ph) {
      int kk = rw + ph * 8;
      tile[kk][col] = W[(size_t)(k0 + kk) * ldw + c0 + col];
    }
    __syncthreads();
#pragma unroll
    for (int ph = 0; ph < 4; ++ph) {
      int dn = rw + ph * 8;
      dst[(size_t)(n0 + dn) * ldk + k0 + col] = f2bf(tile[col][dn]);
    }
    return;
  }
  blk -= NB_TP;
  if (blk < NB_BIAS) {
    int n = blk * 256 + threadIdx.x;
    if (n < 2048) {
      int p = n >> 10, n1 = n & 1023, hh = n1 >> 9, sel = (n1 >> 7) & 3;
      int c = (2 * p + hh) * CH + (n1 & (CH - 1));
      const float* bb = sel == 0 ? bq1 : sel == 1 ? bk1 : sel == 2 ? bv1 : bs1;
      Bh1[n] = bb[c];
    } else if (n < 2048 + 1664) {
      int n2 = n - 2048;
      if (n2 < 768 || n2 >= 896) {
        int nn = (n2 < 768) ? n2 : n2 - 896;
        int hb = (n2 < 768) ? 0 : 2;
        int hh = hb + nn / 384, r = nn % 384, sel = r >> 7;
        int c = hh * CH + (r & (CH - 1));
        const float* bb = sel == 0 ? bq2 : sel == 1 ? bk2 : bv2;
        Bh2[n2] = bb[c];
      } else {
        Bh2[n2] = bs2[n2 - 768];
      }
    }
    return;
  }
  blk -= NB_BIAS;
  {
    int i = blk * 256 + threadIdx.x;
    if (i < N_NODES) deg[i] = 0;
    if (i < NGRAPH) { gstart[i] = 0; gend[i] = 0; }
    if (i == 0) counter[0] = 0;
  }
}

// ---------------------------------------------------------------------------
// CSR build: hist+bounds -> alloc (wave atomic) -> scatter
// ---------------------------------------------------------------------------
__global__ void hist_bounds_kernel(const int* __restrict__ dst, int* __restrict__ deg,
                                   const int* __restrict__ batch,
                                   int* __restrict__ gstart, int* __restrict__ gend) {
  int t = blockIdx.x * blockDim.x + threadIdx.x;
  if (t < EDGES) atomicAdd(&deg[dst[t]], 1);
  if (t < N_NODES) {
    int b = batch[t];
    if (t == 0 || batch[t - 1] != b) gstart[b] = t;
    if (t == N_NODES - 1 || batch[t + 1] != b) gend[b] = t + 1;
  }
}

__global__ void alloc_kernel(const int* __restrict__ deg, int* __restrict__ counter,
                             int* __restrict__ start, int* __restrict__ cursor) {
  int i = blockIdx.x * blockDim.x + threadIdx.x;
  int lane = threadIdx.x & 63;
  int v = (i < N_NODES) ? deg[i] : 0;
  int sum = v;
#pragma unroll
  for (int off = 1; off < 64; off <<= 1) {
    int t = __shfl_up(sum, off);
    if (lane >= off) sum += t;
  }
  int excl = sum - v;
  int waveTot = __shfl(sum, 63);
  int base = 0;
  if (lane == 63) base = atomicAdd(counter, waveTot);
  base = __shfl(base, 63);
  if (i < N_NODES) {
    start[i] = base + excl;
    cursor[i] = base + excl;
  }
}

__global__ void scatter_kernel(const int* __restrict__ src, const int* __restrict__ dst,
                               int* __restrict__ cursor, int* __restrict__ csr) {
  int e = blockIdx.x * blockDim.x + threadIdx.x;
  if (e < EDGES) {
    int pos = atomicAdd(&cursor[dst[e]], 1);
    csr[pos] = src[e];
  }
}

// ---------------------------------------------------------------------------
// Attention. No-max softmax (round-10 verified: alpha bounded, shift-invariant)
// + __expf. K/V fp8 (4-inst decode); Q/skip bf16.
// attn1: one wave per (node, head); attn2: one wave per (node, head-pair),
// dual-head. 4 x 16-lane groups process 4 edges in parallel; merges = adds.
// ---------------------------------------------------------------------------
#define INV_SQRT_CH 0.08838834764831845f

// layer 1 (pair p, hh = blockIdx.y): row 1536 B; head base hh*768:
// q bf16 @0, s bf16 @256, k fp8 @512, v fp8 @640.
__global__ __launch_bounds__(256) void attn1_kernel(
    const char* __restrict__ BIG, const int* __restrict__ start,
    const int* __restrict__ deg, const int* __restrict__ csr,
    ushort_t* __restrict__ H1b, int p) {
  int wave = threadIdx.x >> 6, lane = threadIdx.x & 63;
  int li = lane & 15, g = lane >> 4;
  int i = blockIdx.x * 4 + wave;
  if (i >= N_NODES) return;
  int hh = blockIdx.y;
  int beg = start[i], end = beg + deg[i];
  const char* hb = BIG + hh * 768;
  float q[8];
  unpack8(*(const uint4*)(hb + (size_t)i * 1536 + li * 16), q);
  float s = 0.f, a[8] = {};
  for (int e0 = beg; e0 < end; e0 += 4) {
    int eg = e0 + g;
    bool valid = eg < end;
    int j = csr[valid ? eg : beg];
    const char* jp = hb + (size_t)j * 1536;
    uint2 kw = *(const uint2*)(jp + 512 + li * 8);
    uint2 vw = *(const uint2*)(jp + 640 + li * 8);
    float kf[8]; unpack8_fp8(kw, kf);
    float pd = q[0]*kf[0]+q[1]*kf[1]+q[2]*kf[2]+q[3]*kf[3]+
               q[4]*kf[4]+q[5]*kf[5]+q[6]*kf[6]+q[7]*kf[7];
    pd += __shfl_xor(pd, 1);
    pd += __shfl_xor(pd, 2);
    pd += __shfl_xor(pd, 4);
    pd += __shfl_xor(pd, 8);
    float w = valid ? __expf(pd * INV_SQRT_CH) : 0.f;
    float vf[8]; unpack8_fp8(vw, vf);
    s += w;
#pragma unroll
    for (int c = 0; c < 8; ++c) a[c] = fmaf(w, vf[c], a[c]);
  }
#pragma unroll
  for (int ox = 16; ox <= 32; ox <<= 1) {
    s += __shfl_xor(s, ox);
#pragma unroll
    for (int c = 0; c < 8; ++c) a[c] += __shfl_xor(a[c], ox);
  }
  if (g != 0) return;
  float inv = 1.f / (s + 1e-16f);
  float sk[8];
  unpack8(*(const uint4*)(hb + (size_t)i * 1536 + 256 + li * 16), sk);
  uint4 ow;
  uint_t* op = (uint_t*)&ow;
#pragma unroll
  for (int c = 0; c < 4; ++c) {
    float o0 = a[2 * c] * inv + sk[2 * c];
    float o1 = a[2 * c + 1] * inv + sk[2 * c + 1];
    o0 = o0 > 0.f ? o0 : expm1f(o0);
    o1 = o1 > 0.f ? o1 : expm1f(o1);
    op[c] = (uint_t)f2bf(o0) | ((uint_t)f2bf(o1) << 16);
  }
  *(uint4*)(H1b + (size_t)i * HID + (2 * p + hh) * CH + li * 8) = ow;
}

// layer 2: row 2304 B; head hh base hh*512: q bf16 @0, k fp8 @256, v fp8 @384;
// pair p = blockIdx.y handles hh = 2p, 2p+1. Writes 0.25*(m0+m1) as bf16 to
// PairOut[p][i][c]; pool adds skip (BIG @2048) + both pairs.
__global__ __launch_bounds__(256) void attn2_kernel(
    const char* __restrict__ BIG, const int* __restrict__ start,
    const int* __restrict__ deg, const int* __restrict__ csr,
    ushort_t* __restrict__ PairOut) {
  int wave = threadIdx.x >> 6, lane = threadIdx.x & 63;
  int li = lane & 15, g = lane >> 4;
  int i = blockIdx.x * 4 + wave;
  if (i >= N_NODES) return;
  int p = blockIdx.y;
  int qo0 = p * 1024, qo1 = p * 1024 + 512;
  int beg = start[i], end = beg + deg[i];
  const char* ip = BIG + (size_t)i * 2304;
  float q0[8], q1[8];
  unpack8(*(const uint4*)(ip + qo0 + li * 16), q0);
  unpack8(*(const uint4*)(ip + qo1 + li * 16), q1);
  float s0 = 0.f, s1 = 0.f, a0[8] = {}, a1[8] = {};
  for (int e0 = beg; e0 < end; e0 += 4) {
    int eg = e0 + g;
    bool valid = eg < end;
    int j = csr[valid ? eg : beg];
    const char* jp = BIG + (size_t)j * 2304;
    uint2 kw0 = *(const uint2*)(jp + qo0 + 256 + li * 8);
    uint2 vw0 = *(const uint2*)(jp + qo0 + 384 + li * 8);
    uint2 kw1 = *(const uint2*)(jp + qo1 + 256 + li * 8);
    uint2 vw1 = *(const uint2*)(jp + qo1 + 384 + li * 8);
    float kf[8];
    unpack8_fp8(kw0, kf);
    float p0 = q0[0]*kf[0]+q0[1]*kf[1]+q0[2]*kf[2]+q0[3]*kf[3]+
               q0[4]*kf[4]+q0[5]*kf[5]+q0[6]*kf[6]+q0[7]*kf[7];
    unpack8_fp8(kw1, kf);
    float p1 = q1[0]*kf[0]+q1[1]*kf[1]+q1[2]*kf[2]+q1[3]*kf[3]+
               q1[4]*kf[4]+q1[5]*kf[5]+q1[6]*kf[6]+q1[7]*kf[7];
#pragma unroll
    for (int ox = 1; ox <= 8; ox <<= 1) {
      p0 += __shfl_xor(p0, ox);
      p1 += __shfl_xor(p1, ox);
    }
    float w0 = valid ? __expf(p0 * INV_SQRT_CH) : 0.f;
    float w1 = valid ? __expf(p1 * INV_SQRT_CH) : 0.f;
    float vf[8];
    unpack8_fp8(vw0, vf);
    s0 += w0;
#pragma unroll
    for (int c = 0; c < 8; ++c) a0[c] = fmaf(w0, vf[c], a0[c]);
    unpack8_fp8(vw1, vf);
    s1 += w1;
#pragma unroll
    for (int c = 0; c < 8; ++c) a1[c] = fmaf(w1, vf[c], a1[c]);
  }
#pragma unroll
  for (int ox = 16; ox <= 32; ox <<= 1) {
    s0 += __shfl_xor(s0, ox);
    s1 += __shfl_xor(s1, ox);
#pragma unroll
    for (int c = 0; c < 8; ++c) {
      a0[c] += __shfl_xor(a0[c], ox);
      a1[c] += __shfl_xor(a1[c], ox);
    }
  }
  if (g != 0) return;
  float inv0 = 0.25f / (s0 + 1e-16f), inv1 = 0.25f / (s1 + 1e-16f);
  uint4 ow;
  uint_t* op = (uint_t*)&ow;
#pragma unroll
  for (int c = 0; c < 4; ++c) {
    float o0 = a0[2 * c] * inv0 + a1[2 * c] * inv1;
    float o1 = a0[2 * c + 1] * inv0 + a1[2 * c + 1] * inv1;
    op[c] = (uint_t)f2bf(o0) | ((uint_t)f2bf(o1) << 16);
  }
  *(uint4*)(PairOut + ((size_t)p * N_NODES + i) * CH + li * 8) = ow;
}

// ---------------------------------------------------------------------------
// Fused pool + ELU + classifier + log_softmax. One block of 256 per graph.
// h2[i][c] = elu(skip(BIG@2048) + PairOut0 + PairOut1).
// ---------------------------------------------------------------------------
__global__ __launch_bounds__(256) void pool_cls(
    const ushort_t* __restrict__ PairOut, const char* __restrict__ BIG,
    const int* __restrict__ gstart, const int* __restrict__ gend,
    const float* __restrict__ Wfc, const float* __restrict__ bfc,
    float* __restrict__ out) {
  int g = blockIdx.x;
  int t = threadIdx.x;
  int c = t & (CH - 1), rr = t >> 7;
  int s0 = gstart[g], e0 = gend[g];
  const ushort_t* P1 = PairOut + (size_t)N_NODES * CH;
  float sum = 0.f;
  for (int i = s0 + rr; i < e0; i += 2) {
    float sk = bf2f(*(const ushort_t*)(BIG + (size_t)i * 2304 + 2048 + c * 2));
    float m0 = bf2f(PairOut[(size_t)i * CH + c]);
    float m1 = bf2f(P1[(size_t)i * CH + c]);
    float v = sk + m0 + m1;
    v = v > 0.f ? v : expm1f(v);
    sum += v;
  }
  __shared__ float sh[256];
  __shared__ float p[CH];
  __shared__ float red[CH];
  __shared__ float logits[NCLS];
  sh[t] = sum;
  __syncthreads();
  if (t < CH) {
    float cnt = fmaxf((float)(e0 - s0), 1.f);
    p[t] = (sh[t] + sh[t + CH]) / cnt;
  }
  for (int cc = 0; cc < NCLS; ++cc) {
    __syncthreads();
    if (t < CH) red[t] = p[t] * Wfc[t * NCLS + cc];
    __syncthreads();
    for (int off = 64; off > 0; off >>= 1) {
      if (t < off) red[t] += red[t + off];
      __syncthreads();
    }
    if (t == 0) logits[cc] = red[0] + bfc[cc];
  }
  __syncthreads();
  if (t == 0) {
    float mx = -INFINITY;
    for (int cc = 0; cc < NCLS; ++cc) mx = fmaxf(mx, logits[cc]);
    float se = 0.f;
    for (int cc = 0; cc < NCLS; ++cc) se += expf(logits[cc] - mx);
    float ls = mx + logf(se);
    for (int cc = 0; cc < NCLS; ++cc) out[g * NCLS + cc] = logits[cc] - ls;
  }
}

// ---------------------------------------------------------------------------
extern "C" void kernel_launch(void* const* d_in, const int* in_sizes, int n_in,
                              void* d_out, int out_size, void* d_ws, size_t ws_size,
                              hipStream_t stream) {
  const float* x    = (const float*)d_in[0];
  const int*   ei   = (const int*)d_in[1];
  const int*   batch= (const int*)d_in[2];
  const float* Wq1 = (const float*)d_in[3];  const float* bq1 = (const float*)d_in[4];
  const float* Wk1 = (const float*)d_in[5];  const float* bk1 = (const float*)d_in[6];
  const float* Wv1 = (const float*)d_in[7];  const float* bv1 = (const float*)d_in[8];
  const float* Ws1 = (const float*)d_in[9];  const float* bs1 = (const float*)d_in[10];
  const float* Wq2 = (const float*)d_in[11]; const float* bq2 = (const float*)d_in[12];
  const float* Wk2 = (const float*)d_in[13]; const float* bk2 = (const float*)d_in[14];
  const float* Wv2 = (const float*)d_in[15]; const float* bv2 = (const float*)d_in[16];
  const float* Ws2 = (const float*)d_in[17]; const float* bs2 = (const float*)d_in[18];
  const float* Wfc = (const float*)d_in[19]; const float* bfc = (const float*)d_in[20];
  float* out = (float*)d_out;

  // Workspace (~195 MB). PairOut (bf16 2*N*128 = 25.6MB) aliases xb (dead
  // after L1 GEMMs). BIG sized for L2's 2304 B rows; L1 uses stride 1536.
  ushort_t* xb     = (ushort_t*)d_ws;                   // N x 256 bf16 (25.6 MB)
  ushort_t* PairOut= (ushort_t*)d_ws;                   // 2 x N x 128 bf16 (alias)
  char*     BIG    = (char*)(xb + (size_t)N_NODES * FEAT);  // N x 2304 B (115.2 MB)
  ushort_t* H1b    = (ushort_t*)(BIG + (size_t)N_NODES * 2304); // N x 512 bf16
  ushort_t* W1t    = H1b + (size_t)N_NODES * HID;       // 2048*256
  float*    Bh1    = (float*)(W1t + L1_W);              // 2048
  ushort_t* W2t    = (ushort_t*)(Bh1 + 2048);           // 1664*512
  float*    Bh2    = (float*)(W2t + L2_W);              // 1664
  int* deg    = (int*)(Bh2 + 1664);
  int* start  = deg + N_NODES;
  int* cursor = start + N_NODES;
  int* csr    = cursor + N_NODES;
  int* gstart = csr + EDGES;
  int* gend   = gstart + NGRAPH;
  int* counter= gend + NGRAPH;

  const int* srcp = ei;
  const int* dstp = ei + EDGES;

  // ---- prep (single launch) + CSR build ----
  prep_all<<<NB_CVT + NB_TP + NB_BIAS + NB_ZERO, 256, 0, stream>>>(
      x, xb, Wq1, Wk1, Wv1, Ws1, Wq2, Wk2, Wv2, Ws2,
      bq1, bk1, bv1, bs1, bq2, bk2, bv2, bs2,
      W1t, W2t, Bh1, Bh2, deg, counter, gstart, gend);
  hist_bounds_kernel<<<(EDGES + 255) / 256, 256, 0, stream>>>(dstp, deg, batch, gstart, gend);
  alloc_kernel<<<(N_NODES + 255) / 256, 256, 0, stream>>>(deg, counter, start, cursor);
  scatter_kernel<<<(EDGES + 255) / 256, 256, 0, stream>>>(srcp, dstp, cursor, csr);

  const int ga = (N_NODES + 3) / 4;     // 12500

  // ---- layer 1: per head-pair, 128^2 GEMM (8 col tiles) + attention ----
  for (int p = 0; p < 2; ++p) {
    gemm_bt1<<<49 * 8 * 8, 256, 0, stream>>>(
        xb, W1t + (size_t)p * 1024 * FEAT, Bh1 + p * 1024, BIG, N_NODES, FEAT, 8);
    attn1_kernel<<<dim3(ga, 2), 256, 0, stream>>>(BIG, start, deg, csr, H1b, p);
  }

  // ---- layer 2: ONE GEMM (round-3 256^2 kernel, 7 col tiles, mode 2) ----
  gemm_bt<<<25 * 8 * 7, 512, 0, stream>>>(H1b, W2t, Bh2, BIG, N_NODES, HID, 7, 1664, 2);
  attn2_kernel<<<dim3(ga, 2), 256, 0, stream>>>(BIG, start, deg, csr, PairOut);

  // ---- fused pool + classify ----
  pool_cls<<<NGRAPH, 256, 0, stream>>>(PairOut, BIG, gstart, gend, Wfc, bfc, out);
}

// Round 7
// 616.134 us; speedup vs baseline: 1.0108x; 1.0108x over previous
//
#include <hip/hip_runtime.h>
#include <math.h>
#include <stdint.h>

#define N_NODES 50000
#define FEAT    256
#define EDGES   200000
#define HEADS   4
#define CH      128
#define HID     512   // HEADS*CH
#define NGRAPH  256
#define NCLS    10

typedef unsigned short ushort_t;
typedef unsigned int uint_t;
typedef __attribute__((ext_vector_type(8))) short bf16x8;
typedef __attribute__((ext_vector_type(4))) float f32x4;
typedef __attribute__((ext_vector_type(2))) float f32x2;

__device__ __forceinline__ ushort_t f2bf(float f) {  // round-to-nearest-even
  uint_t u = __float_as_uint(f);
  u += 0x7FFF + ((u >> 16) & 1);
  return (ushort_t)(u >> 16);
}
__device__ __forceinline__ float bf2f(ushort_t h) {
  return __uint_as_float(((uint_t)h) << 16);
}
__device__ __forceinline__ void unpack8(uint4 w, float* f) {
  f[0] = bf2f((ushort_t)w.x); f[1] = bf2f((ushort_t)(w.x >> 16));
  f[2] = bf2f((ushort_t)w.y); f[3] = bf2f((ushort_t)(w.y >> 16));
  f[4] = bf2f((ushort_t)w.z); f[5] = bf2f((ushort_t)(w.z >> 16));
  f[6] = bf2f((ushort_t)w.w); f[7] = bf2f((ushort_t)(w.w >> 16));
}
// 8 x fp8(e4m3) -> 8 x f32 via v_cvt_pk_f32_fp8 (4 insts)
__device__ __forceinline__ void unpack8_fp8(uint2 w, float* f) {
  f32x2 a = __builtin_amdgcn_cvt_pk_f32_fp8((int)w.x, false);
  f32x2 b = __builtin_amdgcn_cvt_pk_f32_fp8((int)w.x, true);
  f32x2 c = __builtin_amdgcn_cvt_pk_f32_fp8((int)w.y, false);
  f32x2 d = __builtin_amdgcn_cvt_pk_f32_fp8((int)w.y, true);
  f[0] = a[0]; f[1] = a[1]; f[2] = b[0]; f[3] = b[1];
  f[4] = c[0]; f[5] = c[1]; f[6] = d[0]; f[7] = d[1];
}
__device__ __forceinline__ uint_t pack4_fp8(float f0, float f1, float f2, float f3) {
  int v = __builtin_amdgcn_cvt_pk_fp8_f32(f0, f1, 0, false);
  v = __builtin_amdgcn_cvt_pk_fp8_f32(f2, f3, v, true);
  return (uint_t)v;
}

// ---------------------------------------------------------------------------
// Round-17 LAYOUT CHANGE (attention request fusion). Budget analysis: attn1x2
// + attn2 ~ 370-400 us (60% of total) vs L2 GEMM 123 us. Attention is
// gather-request-bound; layouts are remapped so each edge needs HALF the
// gathers, and attn1 processes both heads of a pair per wave (one csr walk).
//  L1 row (1536 B): q0 @0, q1 @256, s0 @512, s1 @768, kv0 @1024, kv1 @1280.
//  L2 row (2304 B): q_h @h*256 (h=0..3), kv_h @1024+h*256, skip @2048.
//  kv block (256 B): chunk c in [0,16): k-bytes [c*16,c*16+8), v [+8,+16).
//  One uint4 gather/lane => lane li gets k+v for channels li*8..li*8+8.
// GEMM loops untouched; only epilogue byte mapping changed (fp8 stores are
// 8 B at stride 16). attn read offsets updated to match. pool_cls unchanged.
// ---------------------------------------------------------------------------

// ---------------------------------------------------------------------------
// L2 GEMM — round-3 loop structure VERBATIM (measured: 119-123 us, MfmaUtil
// ~32%, SQ_LDS_BANK_CONFLICT 0). 256x256 tile, BK=32, 8 waves, 512 threads,
// triple-buffered 96 KB LDS, single-region K-tile, counted vmcnt(4).
// ---------------------------------------------------------------------------
__global__ __launch_bounds__(512, 2) void gemm_bt(
    const ushort_t* __restrict__ A, const ushort_t* __restrict__ Bt,
    const float* __restrict__ bias, char* __restrict__ Cb,
    int M, int K, int nct, int Ntot, int mode) {
  __shared__ __align__(16) ushort_t smem[49152];   // 3 x 32 KB K-tile buffers
  const int tid = threadIdx.x;
  const int lane = tid & 63, wave = tid >> 6;
  const int wr = wave >> 2, wc = wave & 3;         // 2M x 4N waves

  // XCD-aware decode: rowTile = grp*8 + (b%8), ct = (b/8)%nct
  int b = blockIdx.x;
  int per = nct << 3;
  int grp = b / per;
  int rem = b - grp * per;
  int rloc = rem & 7;
  int ct = rem >> 3;
  const int rowBase = (grp * 8 + rloc) * 256;
  const int colBase = ct * 256;
  if (rowBase >= M) return;

  // ---- staging addresses: 2 A slots + 2 B slots per thread per K-tile ----
  const int s0 = tid, s1 = tid + 512;              // slot = row*4 + pos
  const int rl0 = s0 >> 2, cg0 = (s0 & 3) ^ ((rl0 >> 1) & 3);
  const int rl1 = s1 >> 2, cg1 = (s1 & 3) ^ ((rl1 >> 1) & 3);
  int ra0 = rowBase + rl0; ra0 = ra0 < M ? ra0 : M - 1;       // M-tail clamp
  int ra1 = rowBase + rl1; ra1 = ra1 < M ? ra1 : M - 1;
  int nb0 = colBase + rl0; nb0 = nb0 < Ntot ? nb0 : Ntot - 1; // N-tail clamp
  int nb1 = colBase + rl1; nb1 = nb1 < Ntot ? nb1 : Ntot - 1;
  const ushort_t* pa0 = A + (size_t)ra0 * K + cg0 * 8;
  const ushort_t* pa1 = A + (size_t)ra1 * K + cg1 * 8;
  const ushort_t* pb0 = Bt + (size_t)nb0 * K + cg0 * 8;
  const ushort_t* pb1 = Bt + (size_t)nb1 * K + cg1 * 8;
  const int dA0 = s0 * 8, dA1 = s1 * 8;            // LDS element offsets

#define GLL(gp, loff)  __builtin_amdgcn_global_load_lds( \
      (const __attribute__((address_space(1))) uint_t*)(gp), \
      (__attribute__((address_space(3))) uint_t*)(smem + (loff)), 16, 0, 0)

  const int nt = K >> 5;                           // K-tiles of 32
  // ---- prologue: stage tiles 0 (buf0) and 1 (buf1) ----
  GLL(pa0, dA0);                GLL(pa1, dA1);
  GLL(pb0, 8192 + dA0);         GLL(pb1, 8192 + dA1);
  GLL(pa0 + 32, 16384 + dA0);   GLL(pa1 + 32, 16384 + dA1);
  GLL(pb0 + 32, 24576 + dA0);   GLL(pb1 + 32, 24576 + dA1);
  pa0 += 64; pa1 += 64; pb0 += 64; pb1 += 64;      // now point at tile 2

  // ---- fragment read offsets (element units) ----
  const int fr = lane & 15, c0 = lane >> 4;
  const int pswz = (c0 ^ ((fr >> 1) & 3)) * 8;     // same swizzle as stage
  const int aOff = (wr * 128 + fr) * 32 + pswz;
  const int bOff = 8192 + (wc * 64 + fr) * 32 + pswz;

  f32x4 acc[8][4] = {};
  asm volatile("s_waitcnt vmcnt(4)" ::: "memory"); // tile0 landed, tile1 in flight
  __builtin_amdgcn_s_barrier();
  __builtin_amdgcn_sched_barrier(0);

  int cur = 0, nxt = 2;
  for (int t = 0; t < nt; ++t) {
    const ushort_t* bufc = smem + cur * 16384;
    const bool pf = (t + 2) < nt;
    bf16x8 af[8], bfr[4];
    // reads ordered so the first MFMA (af[0] x bfr[0]) unblocks earliest
    af[0] = *(const bf16x8*)(bufc + aOff);
#pragma unroll
    for (int j = 0; j < 4; ++j) bfr[j] = *(const bf16x8*)(bufc + bOff + j * 512);
#pragma unroll
    for (int i = 1; i < 8; ++i) af[i] = *(const bf16x8*)(bufc + aOff + i * 512);
    // prefetch tile t+2 into buf[nxt] (dead since its lgkmcnt(0) last tile)
    if (pf) {
      GLL(pa0, nxt * 16384 + dA0);        GLL(pa1, nxt * 16384 + dA1);
      GLL(pb0, nxt * 16384 + 8192 + dA0); GLL(pb1, nxt * 16384 + 8192 + dA1);
      pa0 += 32; pa1 += 32; pb0 += 32; pb1 += 32;
    }
#pragma unroll
    for (int i = 0; i < 8; ++i)
#pragma unroll
      for (int j = 0; j < 4; ++j)
        acc[i][j] = __builtin_amdgcn_mfma_f32_16x16x32_bf16(af[i], bfr[j], acc[i][j], 0, 0, 0);
    asm volatile("s_waitcnt lgkmcnt(0)" ::: "memory");  // all reads of bufc drained
    if (pf)                asm volatile("s_waitcnt vmcnt(4)" ::: "memory"); // t+1 landed
    else if (t + 1 < nt)   asm volatile("s_waitcnt vmcnt(0)" ::: "memory"); // tail drain
    __builtin_amdgcn_s_barrier();
    __builtin_amdgcn_sched_barrier(0);
    cur = cur == 2 ? 0 : cur + 1;
    nxt = nxt == 2 ? 0 : nxt + 1;
  }
#undef GLL

  // ---- output block -> (byte offset, dtype), wave-uniform (new layout) ----
  const int colE = colBase + ((wc >> 1) << 7);     // this wave's 128-col block
  const int wcE = wc & 1;                          // 64-col half within block
  const bool colValid = colE < Ntot;
  int koff, rowStride, isfp8;
  if (mode == 1) {
    rowStride = 1536;
    int hh = colE >> 9, sel = (colE >> 7) & 3;     // q,k,v,s
    if (sel == 0)      { koff = hh * 256; isfp8 = 0; }
    else if (sel == 3) { koff = 512 + hh * 256; isfp8 = 0; }
    else               { koff = 1024 + hh * 256 + (sel == 2 ? 8 : 0); isfp8 = 1; }
  } else {
    rowStride = 2304;
    if (colE >= 768 && colE < 896) { koff = 2048; isfp8 = 0; }
    else if (colValid) {
      int n2 = (colE < 768) ? colE : colE - 896;
      int hb = (colE < 768) ? 0 : 2;
      int hh = hb + n2 / 384, r = n2 % 384, sel = r >> 7;  // q,k,v
      if (sel == 0) { koff = hh * 256; isfp8 = 0; }
      else          { koff = 1024 + hh * 256 + (sel == 2 ? 8 : 0); isfp8 = 1; }
    } else { koff = 0; isfp8 = 0; }
  }

  // Epilogue: per-wave LDS repack in four 32-row halves (4 KB/wave region).
  // C/D layout col=lane&15, row=(lane>>4)*4+reg (m89-verified).
  __builtin_amdgcn_s_barrier();                    // all waves done with bufs
  __builtin_amdgcn_sched_barrier(0);
  ushort_t* wbuf = smem + wave * 2048;             // 32 x 64 bf16
  const int rq = lane >> 4, fc = lane & 15;
  float bv[4];
#pragma unroll
  for (int j = 0; j < 4; ++j) {
    int bi = colBase + wc * 64 + j * 16 + fc;
    bv[j] = bias[bi < Ntot ? bi : Ntot - 1];
  }
#pragma unroll
  for (int h = 0; h < 4; ++h) {
#pragma unroll
    for (int ii = 0; ii < 2; ++ii) {
      int i = h * 2 + ii;
#pragma unroll
      for (int j = 0; j < 4; ++j)
#pragma unroll
        for (int r = 0; r < 4; ++r) {
          int rl = ii * 16 + rq * 4 + r;          // 0..31 ; (rl>>2)&3 == rq
          int cl = j * 16 + fc;                   // 0..63
          int cs = cl ^ (rq << 4);                // rq -> bank octet
          wbuf[rl * 64 + cs] = f2bf(acc[i][j][r] + bv[j]);
        }
    }
    // read back: lanes 0..7 cover all 32 banks (ci*4); remap chunk by rq
    int ci = lane & 7;
    int rbase = lane >> 3;                         // 0..7
#pragma unroll
    for (int rg = 0; rg < 4; ++rg) {
      int rr = rg * 8 + rbase;                     // 0..31
      int rowg = rowBase + wr * 128 + h * 32 + rr;
      int cg = ci ^ (((rr >> 2) & 3) << 1);
      uint4 val = *(const uint4*)(wbuf + rr * 64 + (ci << 3));
      if (rowg < M && colValid) {
        char* dstRow = Cb + (size_t)rowg * rowStride + koff;
        if (!isfp8) {
          *(uint4*)(dstRow + (wcE * 64 + cg * 8) * 2) = val;
        } else {
          float f[8];
          f[0] = bf2f((ushort_t)val.x); f[1] = bf2f((ushort_t)(val.x >> 16));
          f[2] = bf2f((ushort_t)val.y); f[3] = bf2f((ushort_t)(val.y >> 16));
          f[4] = bf2f((ushort_t)val.z); f[5] = bf2f((ushort_t)(val.z >> 16));
          f[6] = bf2f((ushort_t)val.w); f[7] = bf2f((ushort_t)(val.w >> 16));
          uint2 o;
          o.x = pack4_fp8(f[0], f[1], f[2], f[3]);
          o.y = pack4_fp8(f[4], f[5], f[6], f[7]);
          *(uint2*)(dstRow + ((wcE * 8 + cg) << 4)) = o;   // kv interleave
        }
      }
    }
  }
}

// ---------------------------------------------------------------------------
// L1 GEMM (round-0 128x128 loop, mode-1 only; epilogue remapped to new
// L1 row layout: q_hh @hh*256, s_hh @512+hh*256, kv_hh @1024+hh*256 with
// k @chunk*16, v @chunk*16+8).
// ---------------------------------------------------------------------------
__global__ __launch_bounds__(256) void gemm_bt1(
    const ushort_t* __restrict__ A, const ushort_t* __restrict__ Bt,
    const float* __restrict__ bias, char* __restrict__ Cb,
    int M, int K, int ncol) {
  __shared__ __align__(16) ushort_t smem[8192];   // 16 KB total
  ushort_t* sA = smem;                            // 128 x 32
  ushort_t* sB = smem + 4096;                     // 128 x 32
  const int tid = threadIdx.x;
  const int lane = tid & 63, wave = tid >> 6;
  const int wr = wave >> 1, wc = wave & 1;

  int b = blockIdx.x;
  int per = ncol << 3;
  int grp = b / per;
  int rem = b - grp * per;
  int rloc = rem & 7;
  int c = rem >> 3;
  const int rowBase = (grp * 8 + rloc) * 128;
  const int colBase = c * 128;
  if (rowBase >= M) return;

  f32x4 acc[4][4] = {};

  for (int k0 = 0; k0 < K; k0 += 32) {
#pragma unroll
    for (int l = 0; l < 2; ++l) {
      int slot = l * 256 + tid;           // 0..511
      int rl = slot >> 2;                 // row/col 0..127
      int pos = slot & 3;                 // stored chunk slot
      int cg = pos ^ ((rl >> 1) & 3);     // swizzled global chunk
      {
        int row = rowBase + rl;
        row = row < M ? row : M - 1;      // clamp tail (epilogue guards)
        const ushort_t* gp = A + (size_t)row * K + k0 + cg * 8;
        __builtin_amdgcn_global_load_lds(
            (const __attribute__((address_space(1))) uint_t*)gp,
            (__attribute__((address_space(3))) uint_t*)(sA + slot * 8),
            16, 0, 0);
      }
      {
        int n = colBase + rl;
        const ushort_t* gp = Bt + (size_t)n * K + k0 + cg * 8;
        __builtin_amdgcn_global_load_lds(
            (const __attribute__((address_space(1))) uint_t*)gp,
            (__attribute__((address_space(3))) uint_t*)(sB + slot * 8),
            16, 0, 0);
      }
    }
    __syncthreads();
    const int fr = lane & 15, c0 = lane >> 4;
    bf16x8 af[4], bfr[4];
#pragma unroll
    for (int i = 0; i < 4; ++i) {
      int r = wr * 64 + i * 16 + fr;
      af[i] = *(const bf16x8*)(sA + r * 32 + ((c0 ^ ((r >> 1) & 3)) * 8));
      int n = wc * 64 + i * 16 + fr;
      bfr[i] = *(const bf16x8*)(sB + n * 32 + ((c0 ^ ((n >> 1) & 3)) * 8));
    }
#pragma unroll
    for (int i = 0; i < 4; ++i)
#pragma unroll
      for (int j = 0; j < 4; ++j)
        acc[i][j] = __builtin_amdgcn_mfma_f32_16x16x32_bf16(af[i], bfr[j], acc[i][j], 0, 0, 0);
    __syncthreads();
  }

  // ---- output block -> (byte offset, dtype), NEW mode-1 mapping ----
  const int hh = colBase >> 9, sel = (colBase >> 7) & 3;   // q,k,v,s
  int koff, isfp8;
  if (sel == 0)      { koff = hh * 256; isfp8 = 0; }
  else if (sel == 3) { koff = 512 + hh * 256; isfp8 = 0; }
  else               { koff = 1024 + hh * 256 + (sel == 2 ? 8 : 0); isfp8 = 1; }

  // Epilogue: per-wave LDS repack in two 32-row halves (4 KB/wave region).
  ushort_t* wbuf = smem + wave * 2048;    // 32 x 64 bf16
  const int rq = lane >> 4, fc = lane & 15;
  float bv[4];
#pragma unroll
  for (int j = 0; j < 4; ++j) bv[j] = bias[colBase + wc * 64 + j * 16 + fc];
#pragma unroll
  for (int h = 0; h < 2; ++h) {
#pragma unroll
    for (int ii = 0; ii < 2; ++ii) {
      int i = h * 2 + ii;
#pragma unroll
      for (int j = 0; j < 4; ++j)
#pragma unroll
        for (int r = 0; r < 4; ++r) {
          int rl = ii * 16 + rq * 4 + r;          // 0..31 ; (rl>>2)&3 == rq
          int cl = j * 16 + fc;                   // 0..63
          int cs = cl ^ (rq << 4);                // rq -> bank octet
          wbuf[rl * 64 + cs] = f2bf(acc[i][j][r] + bv[j]);
        }
    }
    int ci = lane & 7;
    int rbase = lane >> 3;                         // 0..7
#pragma unroll
    for (int rg = 0; rg < 4; ++rg) {
      int rr = rg * 8 + rbase;                     // 0..31
      int rowg = rowBase + wr * 64 + h * 32 + rr;
      int cg = ci ^ (((rr >> 2) & 3) << 1);
      uint4 val = *(const uint4*)(wbuf + rr * 64 + (ci << 3));
      if (rowg < M) {
        char* dstRow = Cb + (size_t)rowg * 1536 + koff;
        if (!isfp8) {
          *(uint4*)(dstRow + (wc * 64 + cg * 8) * 2) = val;
        } else {
          float f[8];
          f[0] = bf2f((ushort_t)val.x); f[1] = bf2f((ushort_t)(val.x >> 16));
          f[2] = bf2f((ushort_t)val.y); f[3] = bf2f((ushort_t)(val.y >> 16));
          f[4] = bf2f((ushort_t)val.z); f[5] = bf2f((ushort_t)(val.z >> 16));
          f[6] = bf2f((ushort_t)val.w); f[7] = bf2f((ushort_t)(val.w >> 16));
          uint2 o;
          o.x = pack4_fp8(f[0], f[1], f[2], f[3]);
          o.y = pack4_fp8(f[4], f[5], f[6], f[7]);
          *(uint2*)(dstRow + ((wc * 8 + cg) << 4)) = o;    // kv interleave
        }
      }
    }
  }
}

// ---------------------------------------------------------------------------
// prep_all: unchanged (W1t/W2t column order and bias permute are layout-
// independent; only GEMM epilogue byte mapping moved).
// ---------------------------------------------------------------------------
#define L1_W   (2048 * FEAT)
#define L2_W   (1664 * HID)
#define T1     512   // (2048/32)*(256/32)
#define T2     832   // (1664/32)*(512/32)
#define NB_CVT  12500
#define NB_TP   (T1 + T2)
#define NB_BIAS 15
#define NB_ZERO 196

__global__ __launch_bounds__(256) void prep_all(
    const float* __restrict__ x, ushort_t* __restrict__ xb,
    const float* __restrict__ Wq1, const float* __restrict__ Wk1,
    const float* __restrict__ Wv1, const float* __restrict__ Ws1,
    const float* __restrict__ Wq2, const float* __restrict__ Wk2,
    const float* __restrict__ Wv2, const float* __restrict__ Ws2,
    const float* __restrict__ bq1, const float* __restrict__ bk1,
    const float* __restrict__ bv1, const float* __restrict__ bs1,
    const float* __restrict__ bq2, const float* __restrict__ bk2,
    const float* __restrict__ bv2, const float* __restrict__ bs2,
    ushort_t* __restrict__ W1t, ushort_t* __restrict__ W2t,
    float* __restrict__ Bh1, float* __restrict__ Bh2,
    int* __restrict__ deg, int* __restrict__ counter,
    int* __restrict__ gstart, int* __restrict__ gend) {
  __shared__ float tile[32][33];
  int blk = blockIdx.x;
  if (blk < NB_CVT) {
    int i = blk * 256 + threadIdx.x;            // n4 = 3.2M exactly
    float4 f = *(const float4*)(x + (size_t)i * 4);
    uint_t lo = (uint_t)f2bf(f.x) | ((uint_t)f2bf(f.y) << 16);
    uint_t hi = (uint_t)f2bf(f.z) | ((uint_t)f2bf(f.w) << 16);
    ((uint2*)xb)[i] = make_uint2(lo, hi);
    return;
  }
  blk -= NB_CVT;
  if (blk < NB_TP) {
    int t = blk;
    const float* W; int ldw, c0, n0, k0, ldk; ushort_t* dst;
    if (t < T1) {
      int nb = t >> 3, kb = t & 7;
      n0 = nb * 32; k0 = kb * 32; ldk = FEAT; dst = W1t;
      int p = n0 >> 10, n1 = n0 & 1023, hh = n1 >> 9, sel = (n1 >> 7) & 3;
      c0 = (2 * p + hh) * CH + (n1 & (CH - 1));
      W = sel == 0 ? Wq1 : sel == 1 ? Wk1 : sel == 2 ? Wv1 : Ws1;
      ldw = HID;
    } else {
      t -= T1;
      int nb = t >> 4, kb = t & 15;
      n0 = nb * 32; k0 = kb * 32; ldk = HID; dst = W2t;
      if (n0 < 768 || n0 >= 896) {
        int n2 = (n0 < 768) ? n0 : n0 - 896;
        int hb = (n0 < 768) ? 0 : 2;
        int hh = hb + n2 / 384, r = n2 % 384, sel = r >> 7;
        c0 = hh * CH + (r & (CH - 1));
        W = sel == 0 ? Wq2 : sel == 1 ? Wk2 : Wv2;
        ldw = HID;
      } else {
        c0 = n0 - 768; W = Ws2; ldw = CH;
      }
    }
    int col = threadIdx.x & 31, rw = threadIdx.x >> 5;
#pragma unroll
    for (int ph = 0; ph < 4; ++ph) {
      int kk = rw + ph * 8;
      tile[kk][col] = W[(size_t)(k0 + kk) * ldw + c0 + col];
    }
    __syncthreads();
#pragma unroll
    for (int ph = 0; ph < 4; ++ph) {
      int dn = rw + ph * 8;
      dst[(size_t)(n0 + dn) * ldk + k0 + col] = f2bf(tile[col][dn]);
    }
    return;
  }
  blk -= NB_TP;
  if (blk < NB_BIAS) {
    int n = blk * 256 + threadIdx.x;
    if (n < 2048) {
      int p = n >> 10, n1 = n & 1023, hh = n1 >> 9, sel = (n1 >> 7) & 3;
      int c = (2 * p + hh) * CH + (n1 & (CH - 1));
      const float* bb = sel == 0 ? bq1 : sel == 1 ? bk1 : sel == 2 ? bv1 : bs1;
      Bh1[n] = bb[c];
    } else if (n < 2048 + 1664) {
      int n2 = n - 2048;
      if (n2 < 768 || n2 >= 896) {
        int nn = (n2 < 768) ? n2 : n2 - 896;
        int hb = (n2 < 768) ? 0 : 2;
        int hh = hb + nn / 384, r = nn % 384, sel = r >> 7;
        int c = hh * CH + (r & (CH - 1));
        const float* bb = sel == 0 ? bq2 : sel == 1 ? bk2 : bv2;
        Bh2[n2] = bb[c];
      } else {
        Bh2[n2] = bs2[n2 - 768];
      }
    }
    return;
  }
  blk -= NB_BIAS;
  {
    int i = blk * 256 + threadIdx.x;
    if (i < N_NODES) deg[i] = 0;
    if (i < NGRAPH) { gstart[i] = 0; gend[i] = 0; }
    if (i == 0) counter[0] = 0;
  }
}

// ---------------------------------------------------------------------------
// CSR build: hist+bounds -> alloc (wave atomic) -> scatter
// ---------------------------------------------------------------------------
__global__ void hist_bounds_kernel(const int* __restrict__ dst, int* __restrict__ deg,
                                   const int* __restrict__ batch,
                                   int* __restrict__ gstart, int* __restrict__ gend) {
  int t = blockIdx.x * blockDim.x + threadIdx.x;
  if (t < EDGES) atomicAdd(&deg[dst[t]], 1);
  if (t < N_NODES) {
    int b = batch[t];
    if (t == 0 || batch[t - 1] != b) gstart[b] = t;
    if (t == N_NODES - 1 || batch[t + 1] != b) gend[b] = t + 1;
  }
}

__global__ void alloc_kernel(const int* __restrict__ deg, int* __restrict__ counter,
                             int* __restrict__ start, int* __restrict__ cursor) {
  int i = blockIdx.x * blockDim.x + threadIdx.x;
  int lane = threadIdx.x & 63;
  int v = (i < N_NODES) ? deg[i] : 0;
  int sum = v;
#pragma unroll
  for (int off = 1; off < 64; off <<= 1) {
    int t = __shfl_up(sum, off);
    if (lane >= off) sum += t;
  }
  int excl = sum - v;
  int waveTot = __shfl(sum, 63);
  int base = 0;
  if (lane == 63) base = atomicAdd(counter, waveTot);
  base = __shfl(base, 63);
  if (i < N_NODES) {
    start[i] = base + excl;
    cursor[i] = base + excl;
  }
}

__global__ void scatter_kernel(const int* __restrict__ src, const int* __restrict__ dst,
                               int* __restrict__ cursor, int* __restrict__ csr) {
  int e = blockIdx.x * blockDim.x + threadIdx.x;
  if (e < EDGES) {
    int pos = atomicAdd(&cursor[dst[e]], 1);
    csr[pos] = src[e];
  }
}

// ---------------------------------------------------------------------------
// Attention (round-17): dual-head waves + fused kv gathers.
// One uint4 gather per (edge, head): .xy = k bytes, .zw = v bytes.
// ---------------------------------------------------------------------------
#define INV_SQRT_CH 0.08838834764831845f

// layer 1, pair p: row 1536 B: q0 @0, q1 @256, s0 @512, s1 @768,
// kv0 @1024, kv1 @1280. One wave = one node, BOTH heads of the pair.
__global__ __launch_bounds__(256) void attn1_kernel(
    const char* __restrict__ BIG, const int* __restrict__ start,
    const int* __restrict__ deg, const int* __restrict__ csr,
    ushort_t* __restrict__ H1b, int p) {
  int wave = threadIdx.x >> 6, lane = threadIdx.x & 63;
  int li = lane & 15, g = lane >> 4;
  int i = blockIdx.x * 4 + wave;
  if (i >= N_NODES) return;
  int beg = start[i], end = beg + deg[i];
  const char* ip = BIG + (size_t)i * 1536;
  float q0[8], q1[8], sk0[8], sk1[8];
  unpack8(*(const uint4*)(ip + li * 16), q0);
  unpack8(*(const uint4*)(ip + 256 + li * 16), q1);
  unpack8(*(const uint4*)(ip + 512 + li * 16), sk0);   // hoisted: hides in loop
  unpack8(*(const uint4*)(ip + 768 + li * 16), sk1);
  float s0 = 0.f, s1 = 0.f, a0[8] = {}, a1[8] = {};
  for (int e0 = beg; e0 < end; e0 += 4) {
    int eg = e0 + g;
    bool valid = eg < end;
    int j = csr[valid ? eg : beg];
    const char* jp = BIG + (size_t)j * 1536;
    uint4 kv0 = *(const uint4*)(jp + 1024 + li * 16);
    uint4 kv1 = *(const uint4*)(jp + 1280 + li * 16);
    float kf[8];
    unpack8_fp8(make_uint2(kv0.x, kv0.y), kf);
    float p0 = q0[0]*kf[0]+q0[1]*kf[1]+q0[2]*kf[2]+q0[3]*kf[3]+
               q0[4]*kf[4]+q0[5]*kf[5]+q0[6]*kf[6]+q0[7]*kf[7];
    unpack8_fp8(make_uint2(kv1.x, kv1.y), kf);
    float p1 = q1[0]*kf[0]+q1[1]*kf[1]+q1[2]*kf[2]+q1[3]*kf[3]+
               q1[4]*kf[4]+q1[5]*kf[5]+q1[6]*kf[6]+q1[7]*kf[7];
#pragma unroll
    for (int ox = 1; ox <= 8; ox <<= 1) {
      p0 += __shfl_xor(p0, ox);
      p1 += __shfl_xor(p1, ox);
    }
    float w0 = valid ? __expf(p0 * INV_SQRT_CH) : 0.f;
    float w1 = valid ? __expf(p1 * INV_SQRT_CH) : 0.f;
    float vf[8];
    unpack8_fp8(make_uint2(kv0.z, kv0.w), vf);
    s0 += w0;
#pragma unroll
    for (int c = 0; c < 8; ++c) a0[c] = fmaf(w0, vf[c], a0[c]);
    unpack8_fp8(make_uint2(kv1.z, kv1.w), vf);
    s1 += w1;
#pragma unroll
    for (int c = 0; c < 8; ++c) a1[c] = fmaf(w1, vf[c], a1[c]);
  }
#pragma unroll
  for (int ox = 16; ox <= 32; ox <<= 1) {
    s0 += __shfl_xor(s0, ox);
    s1 += __shfl_xor(s1, ox);
#pragma unroll
    for (int c = 0; c < 8; ++c) {
      a0[c] += __shfl_xor(a0[c], ox);
      a1[c] += __shfl_xor(a1[c], ox);
    }
  }
  if (g != 0) return;
  float inv0 = 1.f / (s0 + 1e-16f), inv1 = 1.f / (s1 + 1e-16f);
  uint4 ow0, ow1;
  uint_t* op0 = (uint_t*)&ow0;
  uint_t* op1 = (uint_t*)&ow1;
#pragma unroll
  for (int c = 0; c < 4; ++c) {
    float x0 = a0[2 * c] * inv0 + sk0[2 * c];
    float x1 = a0[2 * c + 1] * inv0 + sk0[2 * c + 1];
    x0 = x0 > 0.f ? x0 : expm1f(x0);
    x1 = x1 > 0.f ? x1 : expm1f(x1);
    op0[c] = (uint_t)f2bf(x0) | ((uint_t)f2bf(x1) << 16);
    float y0 = a1[2 * c] * inv1 + sk1[2 * c];
    float y1 = a1[2 * c + 1] * inv1 + sk1[2 * c + 1];
    y0 = y0 > 0.f ? y0 : expm1f(y0);
    y1 = y1 > 0.f ? y1 : expm1f(y1);
    op1[c] = (uint_t)f2bf(y0) | ((uint_t)f2bf(y1) << 16);
  }
  ushort_t* orow = H1b + (size_t)i * HID + (2 * p) * CH + li * 8;
  *(uint4*)orow = ow0;
  *(uint4*)(orow + CH) = ow1;
}

// layer 2: row 2304 B: q_h @h*256, kv_h @1024+h*256, skip @2048.
// pair p = blockIdx.y handles heads 2p, 2p+1 (q @p*512, kv @1024+p*512).
__global__ __launch_bounds__(256) void attn2_kernel(
    const char* __restrict__ BIG, const int* __restrict__ start,
    const int* __restrict__ deg, const int* __restrict__ csr,
    ushort_t* __restrict__ PairOut) {
  int wave = threadIdx.x >> 6, lane = threadIdx.x & 63;
  int li = lane & 15, g = lane >> 4;
  int i = blockIdx.x * 4 + wave;
  if (i >= N_NODES) return;
  int p = blockIdx.y;
  int qo = p * 512, kvo = 1024 + p * 512;
  int beg = start[i], end = beg + deg[i];
  const char* ip = BIG + (size_t)i * 2304;
  float q0[8], q1[8];
  unpack8(*(const uint4*)(ip + qo + li * 16), q0);
  unpack8(*(const uint4*)(ip + qo + 256 + li * 16), q1);
  float s0 = 0.f, s1 = 0.f, a0[8] = {}, a1[8] = {};
  for (int e0 = beg; e0 < end; e0 += 4) {
    int eg = e0 + g;
    bool valid = eg < end;
    int j = csr[valid ? eg : beg];
    const char* jp = BIG + (size_t)j * 2304;
    uint4 kv0 = *(const uint4*)(jp + kvo + li * 16);
    uint4 kv1 = *(const uint4*)(jp + kvo + 256 + li * 16);
    float kf[8];
    unpack8_fp8(make_uint2(kv0.x, kv0.y), kf);
    float p0 = q0[0]*kf[0]+q0[1]*kf[1]+q0[2]*kf[2]+q0[3]*kf[3]+
               q0[4]*kf[4]+q0[5]*kf[5]+q0[6]*kf[6]+q0[7]*kf[7];
    unpack8_fp8(make_uint2(kv1.x, kv1.y), kf);
    float p1 = q1[0]*kf[0]+q1[1]*kf[1]+q1[2]*kf[2]+q1[3]*kf[3]+
               q1[4]*kf[4]+q1[5]*kf[5]+q1[6]*kf[6]+q1[7]*kf[7];
#pragma unroll
    for (int ox = 1; ox <= 8; ox <<= 1) {
      p0 += __shfl_xor(p0, ox);
      p1 += __shfl_xor(p1, ox);
    }
    float w0 = valid ? __expf(p0 * INV_SQRT_CH) : 0.f;
    float w1 = valid ? __expf(p1 * INV_SQRT_CH) : 0.f;
    float vf[8];
    unpack8_fp8(make_uint2(kv0.z, kv0.w), vf);
    s0 += w0;
#pragma unroll
    for (int c = 0; c < 8; ++c) a0[c] = fmaf(w0, vf[c], a0[c]);
    unpack8_fp8(make_uint2(kv1.z, kv1.w), vf);
    s1 += w1;
#pragma unroll
    for (int c = 0; c < 8; ++c) a1[c] = fmaf(w1, vf[c], a1[c]);
  }
#pragma unroll
  for (int ox = 16; ox <= 32; ox <<= 1) {
    s0 += __shfl_xor(s0, ox);
    s1 += __shfl_xor(s1, ox);
#pragma unroll
    for (int c = 0; c < 8; ++c) {
      a0[c] += __shfl_xor(a0[c], ox);
      a1[c] += __shfl_xor(a1[c], ox);
    }
  }
  if (g != 0) return;
  float inv0 = 0.25f / (s0 + 1e-16f), inv1 = 0.25f / (s1 + 1e-16f);
  uint4 ow;
  uint_t* op = (uint_t*)&ow;
#pragma unroll
  for (int c = 0; c < 4; ++c) {
    float o0 = a0[2 * c] * inv0 + a1[2 * c] * inv1;
    float o1 = a0[2 * c + 1] * inv0 + a1[2 * c + 1] * inv1;
    op[c] = (uint_t)f2bf(o0) | ((uint_t)f2bf(o1) << 16);
  }
  *(uint4*)(PairOut + ((size_t)p * N_NODES + i) * CH + li * 8) = ow;
}

// ---------------------------------------------------------------------------
// Fused pool + ELU + classifier + log_softmax. One block of 256 per graph.
// h2[i][c] = elu(skip(BIG@2048) + PairOut0 + PairOut1).  (skip offset same)
// ---------------------------------------------------------------------------
__global__ __launch_bounds__(256) void pool_cls(
    const ushort_t* __restrict__ PairOut, const char* __restrict__ BIG,
    const int* __restrict__ gstart, const int* __restrict__ gend,
    const float* __restrict__ Wfc, const float* __restrict__ bfc,
    float* __restrict__ out) {
  int g = blockIdx.x;
  int t = threadIdx.x;
  int c = t & (CH - 1), rr = t >> 7;
  int s0 = gstart[g], e0 = gend[g];
  const ushort_t* P1 = PairOut + (size_t)N_NODES * CH;
  float sum = 0.f;
  for (int i = s0 + rr; i < e0; i += 2) {
    float sk = bf2f(*(const ushort_t*)(BIG + (size_t)i * 2304 + 2048 + c * 2));
    float m0 = bf2f(PairOut[(size_t)i * CH + c]);
    float m1 = bf2f(P1[(size_t)i * CH + c]);
    float v = sk + m0 + m1;
    v = v > 0.f ? v : expm1f(v);
    sum += v;
  }
  __shared__ float sh[256];
  __shared__ float p[CH];
  __shared__ float red[CH];
  __shared__ float logits[NCLS];
  sh[t] = sum;
  __syncthreads();
  if (t < CH) {
    float cnt = fmaxf((float)(e0 - s0), 1.f);
    p[t] = (sh[t] + sh[t + CH]) / cnt;
  }
  for (int cc = 0; cc < NCLS; ++cc) {
    __syncthreads();
    if (t < CH) red[t] = p[t] * Wfc[t * NCLS + cc];
    __syncthreads();
    for (int off = 64; off > 0; off >>= 1) {
      if (t < off) red[t] += red[t + off];
      __syncthreads();
    }
    if (t == 0) logits[cc] = red[0] + bfc[cc];
  }
  __syncthreads();
  if (t == 0) {
    float mx = -INFINITY;
    for (int cc = 0; cc < NCLS; ++cc) mx = fmaxf(mx, logits[cc]);
    float se = 0.f;
    for (int cc = 0; cc < NCLS; ++cc) se += expf(logits[cc] - mx);
    float ls = mx + logf(se);
    for (int cc = 0; cc < NCLS; ++cc) out[g * NCLS + cc] = logits[cc] - ls;
  }
}

// ---------------------------------------------------------------------------
extern "C" void kernel_launch(void* const* d_in, const int* in_sizes, int n_in,
                              void* d_out, int out_size, void* d_ws, size_t ws_size,
                              hipStream_t stream) {
  const float* x    = (const float*)d_in[0];
  const int*   ei   = (const int*)d_in[1];
  const int*   batch= (const int*)d_in[2];
  const float* Wq1 = (const float*)d_in[3];  const float* bq1 = (const float*)d_in[4];
  const float* Wk1 = (const float*)d_in[5];  const float* bk1 = (const float*)d_in[6];
  const float* Wv1 = (const float*)d_in[7];  const float* bv1 = (const float*)d_in[8];
  const float* Ws1 = (const float*)d_in[9];  const float* bs1 = (const float*)d_in[10];
  const float* Wq2 = (const float*)d_in[11]; const float* bq2 = (const float*)d_in[12];
  const float* Wk2 = (const float*)d_in[13]; const float* bk2 = (const float*)d_in[14];
  const float* Wv2 = (const float*)d_in[15]; const float* bv2 = (const float*)d_in[16];
  const float* Ws2 = (const float*)d_in[17]; const float* bs2 = (const float*)d_in[18];
  const float* Wfc = (const float*)d_in[19]; const float* bfc = (const float*)d_in[20];
  float* out = (float*)d_out;

  // Workspace (~195 MB). PairOut (bf16 2*N*128 = 25.6MB) aliases xb (dead
  // after L1 GEMMs). BIG sized for L2's 2304 B rows; L1 uses stride 1536.
  ushort_t* xb     = (ushort_t*)d_ws;                   // N x 256 bf16 (25.6 MB)
  ushort_t* PairOut= (ushort_t*)d_ws;                   // 2 x N x 128 bf16 (alias)
  char*     BIG    = (char*)(xb + (size_t)N_NODES * FEAT);  // N x 2304 B (115.2 MB)
  ushort_t* H1b    = (ushort_t*)(BIG + (size_t)N_NODES * 2304); // N x 512 bf16
  ushort_t* W1t    = H1b + (size_t)N_NODES * HID;       // 2048*256
  float*    Bh1    = (float*)(W1t + L1_W);              // 2048
  ushort_t* W2t    = (ushort_t*)(Bh1 + 2048);           // 1664*512
  float*    Bh2    = (float*)(W2t + L2_W);              // 1664
  int* deg    = (int*)(Bh2 + 1664);
  int* start  = deg + N_NODES;
  int* cursor = start + N_NODES;
  int* csr    = cursor + N_NODES;
  int* gstart = csr + EDGES;
  int* gend   = gstart + NGRAPH;
  int* counter= gend + NGRAPH;

  const int* srcp = ei;
  const int* dstp = ei + EDGES;

  // ---- prep (single launch) + CSR build ----
  prep_all<<<NB_CVT + NB_TP + NB_BIAS + NB_ZERO, 256, 0, stream>>>(
      x, xb, Wq1, Wk1, Wv1, Ws1, Wq2, Wk2, Wv2, Ws2,
      bq1, bk1, bv1, bs1, bq2, bk2, bv2, bs2,
      W1t, W2t, Bh1, Bh2, deg, counter, gstart, gend);
  hist_bounds_kernel<<<(EDGES + 255) / 256, 256, 0, stream>>>(dstp, deg, batch, gstart, gend);
  alloc_kernel<<<(N_NODES + 255) / 256, 256, 0, stream>>>(deg, counter, start, cursor);
  scatter_kernel<<<(EDGES + 255) / 256, 256, 0, stream>>>(srcp, dstp, cursor, csr);

  const int ga = (N_NODES + 3) / 4;     // 12500

  // ---- layer 1: per head-pair, 128^2 GEMM (8 col tiles) + dual-head attn ----
  for (int p = 0; p < 2; ++p) {
    gemm_bt1<<<49 * 8 * 8, 256, 0, stream>>>(
        xb, W1t + (size_t)p * 1024 * FEAT, Bh1 + p * 1024, BIG, N_NODES, FEAT, 8);
    attn1_kernel<<<ga, 256, 0, stream>>>(BIG, start, deg, csr, H1b, p);
  }

  // ---- layer 2: ONE GEMM (round-3 256^2 kernel, 7 col tiles, mode 2) ----
  gemm_bt<<<25 * 8 * 7, 512, 0, stream>>>(H1b, W2t, Bh2, BIG, N_NODES, HID, 7, 1664, 2);
  attn2_kernel<<<dim3(ga, 2), 256, 0, stream>>>(BIG, start, deg, csr, PairOut);

  // ---- fused pool + classify ----
  pool_cls<<<NGRAPH, 256, 0, stream>>>(PairOut, BIG, gstart, gend, Wfc, bfc, out);
}

// Round 8
// 574.238 us; speedup vs baseline: 1.0846x; 1.0730x over previous
//
#include <hip/hip_runtime.h>
#include <math.h>
#include <stdint.h>

#define N_NODES 50000
#define FEAT    256
#define EDGES   200000
#define HEADS   4
#define CH      128
#define HID     512   // HEADS*CH
#define NGRAPH  256
#define NCLS    10

typedef unsigned short ushort_t;
typedef unsigned int uint_t;
typedef __attribute__((ext_vector_type(8))) short bf16x8;
typedef __attribute__((ext_vector_type(4))) float f32x4;
typedef __attribute__((ext_vector_type(2))) float f32x2;

__device__ __forceinline__ ushort_t f2bf(float f) {  // round-to-nearest-even
  uint_t u = __float_as_uint(f);
  u += 0x7FFF + ((u >> 16) & 1);
  return (ushort_t)(u >> 16);
}
__device__ __forceinline__ float bf2f(ushort_t h) {
  return __uint_as_float(((uint_t)h) << 16);
}
__device__ __forceinline__ void unpack8(uint4 w, float* f) {
  f[0] = bf2f((ushort_t)w.x); f[1] = bf2f((ushort_t)(w.x >> 16));
  f[2] = bf2f((ushort_t)w.y); f[3] = bf2f((ushort_t)(w.y >> 16));
  f[4] = bf2f((ushort_t)w.z); f[5] = bf2f((ushort_t)(w.z >> 16));
  f[6] = bf2f((ushort_t)w.w); f[7] = bf2f((ushort_t)(w.w >> 16));
}
// 8 x fp8(e4m3) -> 8 x f32 via v_cvt_pk_f32_fp8 (4 insts)
__device__ __forceinline__ void unpack8_fp8(uint2 w, float* f) {
  f32x2 a = __builtin_amdgcn_cvt_pk_f32_fp8((int)w.x, false);
  f32x2 b = __builtin_amdgcn_cvt_pk_f32_fp8((int)w.x, true);
  f32x2 c = __builtin_amdgcn_cvt_pk_f32_fp8((int)w.y, false);
  f32x2 d = __builtin_amdgcn_cvt_pk_f32_fp8((int)w.y, true);
  f[0] = a[0]; f[1] = a[1]; f[2] = b[0]; f[3] = b[1];
  f[4] = c[0]; f[5] = c[1]; f[6] = d[0]; f[7] = d[1];
}
__device__ __forceinline__ uint_t pack4_fp8(float f0, float f1, float f2, float f3) {
  int v = __builtin_amdgcn_cvt_pk_fp8_f32(f0, f1, 0, false);
  v = __builtin_amdgcn_cvt_pk_fp8_f32(f2, f3, v, true);
  return (uint_t)v;
}

// ---------------------------------------------------------------------------
// Round-18 GEMM: 128x128 tile, BK=32, 4 waves (2x2, per-wave 64x64), 256
// threads, TRIPLE-buffered 48 KB LDS -> THREE blocks/CU. Same single-region
// counted-vmcnt K-tile loop as the verified round-12 256^2 form (which ran
// 3 rounds at 119-123 us / MfmaUtil 32% but was pinned at 1 block/CU by
// 96 KB LDS). Mechanism: co-resident blocks run anti-phase, so block B's
// MFMA clusters fill block A's barrier/vmcnt/epilogue dead time (m97's
// 37%-util structure had ~3 blocks/CU; deep prefetch alone plateaued).
// Per K-tile per thread: 4 global_load_lds; vmcnt(4) at boundary keeps
// tile t+2's loads in flight (never 0 mid-loop). Chunk swizzle (r>>1)&3 on
// stage-source AND read side (verified SQ_LDS_BANK_CONFLICT == 0).
// N tiles exact: 1024=8x128 (mode 1), 1664=13x128 (mode 2) -> no N clamps.
// Output mapping = round-7 verified kv-interleaved layouts:
//  mode 1 (row 1536 B): q_hh @hh*256, s_hh @512+hh*256, kv_hh @1024+hh*256
//                       (k @chunk*16, v @chunk*16+8).
//  mode 2 (row 2304 B): q_h @h*256, kv_h @1024+h*256, skip @2048.
// ---------------------------------------------------------------------------
__global__ __launch_bounds__(256) void gemm_bt(
    const ushort_t* __restrict__ A, const ushort_t* __restrict__ Bt,
    const float* __restrict__ bias, char* __restrict__ Cb,
    int M, int K, int nct, int mode) {
  __shared__ __align__(16) ushort_t smem[24576];   // 3 x 16 KB K-tile buffers
  const int tid = threadIdx.x;
  const int lane = tid & 63, wave = tid >> 6;
  const int wr = wave >> 1, wc = wave & 1;         // 2M x 2N waves

  // XCD-aware decode: rowTile = grp*8 + (b%8), ct = (b/8)%nct
  int b = blockIdx.x;
  int per = nct << 3;
  int grp = b / per;
  int rem = b - grp * per;
  int rloc = rem & 7;
  int ct = rem >> 3;
  const int rowBase = (grp * 8 + rloc) * 128;
  const int colBase = ct * 128;
  if (rowBase >= M) return;

  // ---- staging: 2 A slots + 2 B slots per thread per K-tile (4 GLL) ----
  const int s0 = tid, s1 = tid + 256;              // slot = row*4 + pos
  const int rl0 = s0 >> 2, cg0 = (s0 & 3) ^ ((rl0 >> 1) & 3);
  const int rl1 = s1 >> 2, cg1 = (s1 & 3) ^ ((rl1 >> 1) & 3);
  int ra0 = rowBase + rl0; ra0 = ra0 < M ? ra0 : M - 1;   // M-tail clamp
  int ra1 = rowBase + rl1; ra1 = ra1 < M ? ra1 : M - 1;
  const ushort_t* pa0 = A + (size_t)ra0 * K + cg0 * 8;
  const ushort_t* pa1 = A + (size_t)ra1 * K + cg1 * 8;
  const ushort_t* pb0 = Bt + (size_t)(colBase + rl0) * K + cg0 * 8;
  const ushort_t* pb1 = Bt + (size_t)(colBase + rl1) * K + cg1 * 8;
  const int dA0 = s0 * 8, dA1 = s1 * 8;            // A region [0,4096) elems
  const int dB0 = 4096 + s0 * 8, dB1 = 4096 + s1 * 8;  // B region [4096,8192)

#define GLL(gp, loff)  __builtin_amdgcn_global_load_lds( \
      (const __attribute__((address_space(1))) uint_t*)(gp), \
      (__attribute__((address_space(3))) uint_t*)(smem + (loff)), 16, 0, 0)

  const int nt = K >> 5;                           // K-tiles of 32 (8 or 16)
  // ---- prologue: stage tiles 0 (buf0) and 1 (buf1) ----
  GLL(pa0, dA0);            GLL(pa1, dA1);
  GLL(pb0, dB0);            GLL(pb1, dB1);
  GLL(pa0 + 32, 8192 + dA0); GLL(pa1 + 32, 8192 + dA1);
  GLL(pb0 + 32, 8192 + dB0); GLL(pb1 + 32, 8192 + dB1);
  pa0 += 64; pa1 += 64; pb0 += 64; pb1 += 64;      // now point at tile 2

  // ---- fragment read offsets (element units) ----
  const int fr = lane & 15, c0 = lane >> 4;
  const int pswz = (c0 ^ ((fr >> 1) & 3)) * 8;     // same swizzle as stage
  const int aOff = (wr * 64 + fr) * 32 + pswz;
  const int bOff = 4096 + (wc * 64 + fr) * 32 + pswz;

  f32x4 acc[4][4] = {};
  asm volatile("s_waitcnt vmcnt(4)" ::: "memory"); // tile0 landed, tile1 in flight
  __builtin_amdgcn_s_barrier();
  __builtin_amdgcn_sched_barrier(0);

  int cur = 0, nxt = 2;
  for (int t = 0; t < nt; ++t) {
    const ushort_t* bufc = smem + cur * 8192;
    const bool pf = (t + 2) < nt;
    bf16x8 af[4], bfr[4];
    // reads ordered so the first MFMA (af[0] x bfr[0]) unblocks earliest
    af[0] = *(const bf16x8*)(bufc + aOff);
#pragma unroll
    for (int j = 0; j < 4; ++j) bfr[j] = *(const bf16x8*)(bufc + bOff + j * 512);
#pragma unroll
    for (int i = 1; i < 4; ++i) af[i] = *(const bf16x8*)(bufc + aOff + i * 512);
    // prefetch tile t+2 into buf[nxt] (drained since its lgkmcnt(0) last tile)
    if (pf) {
      int lo = nxt * 8192;
      GLL(pa0, lo + dA0); GLL(pa1, lo + dA1);
      GLL(pb0, lo + dB0); GLL(pb1, lo + dB1);
      pa0 += 32; pa1 += 32; pb0 += 32; pb1 += 32;
    }
#pragma unroll
    for (int i = 0; i < 4; ++i)
#pragma unroll
      for (int j = 0; j < 4; ++j)
        acc[i][j] = __builtin_amdgcn_mfma_f32_16x16x32_bf16(af[i], bfr[j], acc[i][j], 0, 0, 0);
    asm volatile("s_waitcnt lgkmcnt(0)" ::: "memory");  // all reads of bufc drained
    if (pf)                asm volatile("s_waitcnt vmcnt(4)" ::: "memory"); // t+1 landed
    else if (t + 1 < nt)   asm volatile("s_waitcnt vmcnt(0)" ::: "memory"); // tail drain
    __builtin_amdgcn_s_barrier();
    __builtin_amdgcn_sched_barrier(0);
    cur = cur == 2 ? 0 : cur + 1;
    nxt = nxt == 2 ? 0 : nxt + 1;
  }
#undef GLL

  // ---- output block -> (byte offset, dtype), wave-uniform ----
  int koff, rowStride, isfp8;
  if (mode == 1) {
    rowStride = 1536;
    int hh = colBase >> 9, sel = (colBase >> 7) & 3;   // q,k,v,s
    if (sel == 0)      { koff = hh * 256; isfp8 = 0; }
    else if (sel == 3) { koff = 512 + hh * 256; isfp8 = 0; }
    else               { koff = 1024 + hh * 256 + (sel == 2 ? 8 : 0); isfp8 = 1; }
  } else {
    rowStride = 2304;
    if (colBase == 768) { koff = 2048; isfp8 = 0; }
    else {
      int n2 = (colBase < 768) ? colBase : colBase - 896;
      int hb = (colBase < 768) ? 0 : 2;
      int hh = hb + n2 / 384, r = n2 % 384, sel = r >> 7;  // q,k,v
      if (sel == 0) { koff = hh * 256; isfp8 = 0; }
      else          { koff = 1024 + hh * 256 + (sel == 2 ? 8 : 0); isfp8 = 1; }
    }
  }

  // Epilogue: per-wave LDS repack in two 32-row halves (4 KB/wave region).
  // C/D layout col=lane&15, row=(lane>>4)*4+reg (m89-verified).
  ushort_t* wbuf = smem + wave * 2048;             // 32 x 64 bf16
  const int rq = lane >> 4, fc = lane & 15;
  float bv[4];
#pragma unroll
  for (int j = 0; j < 4; ++j) bv[j] = bias[colBase + wc * 64 + j * 16 + fc];
#pragma unroll
  for (int h = 0; h < 2; ++h) {
#pragma unroll
    for (int ii = 0; ii < 2; ++ii) {
      int i = h * 2 + ii;
#pragma unroll
      for (int j = 0; j < 4; ++j)
#pragma unroll
        for (int r = 0; r < 4; ++r) {
          int rl = ii * 16 + rq * 4 + r;          // 0..31 ; (rl>>2)&3 == rq
          int cl = j * 16 + fc;                   // 0..63
          int cs = cl ^ (rq << 4);                // rq -> bank octet
          wbuf[rl * 64 + cs] = f2bf(acc[i][j][r] + bv[j]);
        }
    }
    // read back: lanes 0..7 cover all 32 banks (ci*4); remap chunk by rq
    int ci = lane & 7;
    int rbase = lane >> 3;                         // 0..7
#pragma unroll
    for (int rg = 0; rg < 4; ++rg) {
      int rr = rg * 8 + rbase;                     // 0..31
      int rowg = rowBase + wr * 64 + h * 32 + rr;
      int cg = ci ^ (((rr >> 2) & 3) << 1);
      uint4 val = *(const uint4*)(wbuf + rr * 64 + (ci << 3));
      if (rowg < M) {
        char* dstRow = Cb + (size_t)rowg * rowStride + koff;
        if (!isfp8) {
          *(uint4*)(dstRow + (wc * 64 + cg * 8) * 2) = val;
        } else {
          float f[8];
          f[0] = bf2f((ushort_t)val.x); f[1] = bf2f((ushort_t)(val.x >> 16));
          f[2] = bf2f((ushort_t)val.y); f[3] = bf2f((ushort_t)(val.y >> 16));
          f[4] = bf2f((ushort_t)val.z); f[5] = bf2f((ushort_t)(val.z >> 16));
          f[6] = bf2f((ushort_t)val.w); f[7] = bf2f((ushort_t)(val.w >> 16));
          uint2 o;
          o.x = pack4_fp8(f[0], f[1], f[2], f[3]);
          o.y = pack4_fp8(f[4], f[5], f[6], f[7]);
          *(uint2*)(dstRow + ((wc * 8 + cg) << 4)) = o;   // kv interleave
        }
      }
    }
  }
}

// ---------------------------------------------------------------------------
// prep_all: one launch, four independent regions branch on blockIdx.x:
//  [0, NB_CVT)           : x fp32 -> bf16 (vectorized)
//  [NB_CVT, +NB_TP)      : weight 32x32 tile transposes -> W1t / W2t
//  [.., +NB_BIAS)        : bias permute -> Bh1 / Bh2
//  [.., +NB_ZERO)        : zero deg/counter/gstart/gend
// ---------------------------------------------------------------------------
#define L1_W   (2048 * FEAT)
#define L2_W   (1664 * HID)
#define T1     512   // (2048/32)*(256/32)
#define T2     832   // (1664/32)*(512/32)
#define NB_CVT  12500
#define NB_TP   (T1 + T2)
#define NB_BIAS 15
#define NB_ZERO 196

__global__ __launch_bounds__(256) void prep_all(
    const float* __restrict__ x, ushort_t* __restrict__ xb,
    const float* __restrict__ Wq1, const float* __restrict__ Wk1,
    const float* __restrict__ Wv1, const float* __restrict__ Ws1,
    const float* __restrict__ Wq2, const float* __restrict__ Wk2,
    const float* __restrict__ Wv2, const float* __restrict__ Ws2,
    const float* __restrict__ bq1, const float* __restrict__ bk1,
    const float* __restrict__ bv1, const float* __restrict__ bs1,
    const float* __restrict__ bq2, const float* __restrict__ bk2,
    const float* __restrict__ bv2, const float* __restrict__ bs2,
    ushort_t* __restrict__ W1t, ushort_t* __restrict__ W2t,
    float* __restrict__ Bh1, float* __restrict__ Bh2,
    int* __restrict__ deg, int* __restrict__ counter,
    int* __restrict__ gstart, int* __restrict__ gend) {
  __shared__ float tile[32][33];
  int blk = blockIdx.x;
  if (blk < NB_CVT) {
    int i = blk * 256 + threadIdx.x;            // n4 = 3.2M exactly
    float4 f = *(const float4*)(x + (size_t)i * 4);
    uint_t lo = (uint_t)f2bf(f.x) | ((uint_t)f2bf(f.y) << 16);
    uint_t hi = (uint_t)f2bf(f.z) | ((uint_t)f2bf(f.w) << 16);
    ((uint2*)xb)[i] = make_uint2(lo, hi);
    return;
  }
  blk -= NB_CVT;
  if (blk < NB_TP) {
    int t = blk;
    const float* W; int ldw, c0, n0, k0, ldk; ushort_t* dst;
    if (t < T1) {
      int nb = t >> 3, kb = t & 7;
      n0 = nb * 32; k0 = kb * 32; ldk = FEAT; dst = W1t;
      int p = n0 >> 10, n1 = n0 & 1023, hh = n1 >> 9, sel = (n1 >> 7) & 3;
      c0 = (2 * p + hh) * CH + (n1 & (CH - 1));
      W = sel == 0 ? Wq1 : sel == 1 ? Wk1 : sel == 2 ? Wv1 : Ws1;
      ldw = HID;
    } else {
      t -= T1;
      int nb = t >> 4, kb = t & 15;
      n0 = nb * 32; k0 = kb * 32; ldk = HID; dst = W2t;
      if (n0 < 768 || n0 >= 896) {
        int n2 = (n0 < 768) ? n0 : n0 - 896;
        int hb = (n0 < 768) ? 0 : 2;
        int hh = hb + n2 / 384, r = n2 % 384, sel = r >> 7;
        c0 = hh * CH + (r & (CH - 1));
        W = sel == 0 ? Wq2 : sel == 1 ? Wk2 : Wv2;
        ldw = HID;
      } else {
        c0 = n0 - 768; W = Ws2; ldw = CH;
      }
    }
    int col = threadIdx.x & 31, rw = threadIdx.x >> 5;
#pragma unroll
    for (int ph = 0; ph < 4; ++ph) {
      int kk = rw + ph * 8;
      tile[kk][col] = W[(size_t)(k0 + kk) * ldw + c0 + col];
    }
    __syncthreads();
#pragma unroll
    for (int ph = 0; ph < 4; ++ph) {
      int dn = rw + ph * 8;
      dst[(size_t)(n0 + dn) * ldk + k0 + col] = f2bf(tile[col][dn]);
    }
    return;
  }
  blk -= NB_TP;
  if (blk < NB_BIAS) {
    int n = blk * 256 + threadIdx.x;
    if (n < 2048) {
      int p = n >> 10, n1 = n & 1023, hh = n1 >> 9, sel = (n1 >> 7) & 3;
      int c = (2 * p + hh) * CH + (n1 & (CH - 1));
      const float* bb = sel == 0 ? bq1 : sel == 1 ? bk1 : sel == 2 ? bv1 : bs1;
      Bh1[n] = bb[c];
    } else if (n < 2048 + 1664) {
      int n2 = n - 2048;
      if (n2 < 768 || n2 >= 896) {
        int nn = (n2 < 768) ? n2 : n2 - 896;
        int hb = (n2 < 768) ? 0 : 2;
        int hh = hb + nn / 384, r = nn % 384, sel = r >> 7;
        int c = hh * CH + (r & (CH - 1));
        const float* bb = sel == 0 ? bq2 : sel == 1 ? bk2 : bv2;
        Bh2[n2] = bb[c];
      } else {
        Bh2[n2] = bs2[n2 - 768];
      }
    }
    return;
  }
  blk -= NB_BIAS;
  {
    int i = blk * 256 + threadIdx.x;
    if (i < N_NODES) deg[i] = 0;
    if (i < NGRAPH) { gstart[i] = 0; gend[i] = 0; }
    if (i == 0) counter[0] = 0;
  }
}

// ---------------------------------------------------------------------------
// CSR build: hist+bounds -> alloc (wave atomic) -> scatter
// ---------------------------------------------------------------------------
__global__ void hist_bounds_kernel(const int* __restrict__ dst, int* __restrict__ deg,
                                   const int* __restrict__ batch,
                                   int* __restrict__ gstart, int* __restrict__ gend) {
  int t = blockIdx.x * blockDim.x + threadIdx.x;
  if (t < EDGES) atomicAdd(&deg[dst[t]], 1);
  if (t < N_NODES) {
    int b = batch[t];
    if (t == 0 || batch[t - 1] != b) gstart[b] = t;
    if (t == N_NODES - 1 || batch[t + 1] != b) gend[b] = t + 1;
  }
}

__global__ void alloc_kernel(const int* __restrict__ deg, int* __restrict__ counter,
                             int* __restrict__ start, int* __restrict__ cursor) {
  int i = blockIdx.x * blockDim.x + threadIdx.x;
  int lane = threadIdx.x & 63;
  int v = (i < N_NODES) ? deg[i] : 0;
  int sum = v;
#pragma unroll
  for (int off = 1; off < 64; off <<= 1) {
    int t = __shfl_up(sum, off);
    if (lane >= off) sum += t;
  }
  int excl = sum - v;
  int waveTot = __shfl(sum, 63);
  int base = 0;
  if (lane == 63) base = atomicAdd(counter, waveTot);
  base = __shfl(base, 63);
  if (i < N_NODES) {
    start[i] = base + excl;
    cursor[i] = base + excl;
  }
}

__global__ void scatter_kernel(const int* __restrict__ src, const int* __restrict__ dst,
                               int* __restrict__ cursor, int* __restrict__ csr) {
  int e = blockIdx.x * blockDim.x + threadIdx.x;
  if (e < EDGES) {
    int pos = atomicAdd(&cursor[dst[e]], 1);
    csr[pos] = src[e];
  }
}

// ---------------------------------------------------------------------------
// Attention (round-17 form, unchanged): dual-head waves + fused kv gathers.
// One uint4 gather per (edge, head): .xy = k bytes, .zw = v bytes.
// ---------------------------------------------------------------------------
#define INV_SQRT_CH 0.08838834764831845f

// layer 1, pair p: row 1536 B: q0 @0, q1 @256, s0 @512, s1 @768,
// kv0 @1024, kv1 @1280. One wave = one node, BOTH heads of the pair.
__global__ __launch_bounds__(256) void attn1_kernel(
    const char* __restrict__ BIG, const int* __restrict__ start,
    const int* __restrict__ deg, const int* __restrict__ csr,
    ushort_t* __restrict__ H1b, int p) {
  int wave = threadIdx.x >> 6, lane = threadIdx.x & 63;
  int li = lane & 15, g = lane >> 4;
  int i = blockIdx.x * 4 + wave;
  if (i >= N_NODES) return;
  int beg = start[i], end = beg + deg[i];
  const char* ip = BIG + (size_t)i * 1536;
  float q0[8], q1[8], sk0[8], sk1[8];
  unpack8(*(const uint4*)(ip + li * 16), q0);
  unpack8(*(const uint4*)(ip + 256 + li * 16), q1);
  unpack8(*(const uint4*)(ip + 512 + li * 16), sk0);   // hoisted: hides in loop
  unpack8(*(const uint4*)(ip + 768 + li * 16), sk1);
  float s0 = 0.f, s1 = 0.f, a0[8] = {}, a1[8] = {};
  for (int e0 = beg; e0 < end; e0 += 4) {
    int eg = e0 + g;
    bool valid = eg < end;
    int j = csr[valid ? eg : beg];
    const char* jp = BIG + (size_t)j * 1536;
    uint4 kv0 = *(const uint4*)(jp + 1024 + li * 16);
    uint4 kv1 = *(const uint4*)(jp + 1280 + li * 16);
    float kf[8];
    unpack8_fp8(make_uint2(kv0.x, kv0.y), kf);
    float p0 = q0[0]*kf[0]+q0[1]*kf[1]+q0[2]*kf[2]+q0[3]*kf[3]+
               q0[4]*kf[4]+q0[5]*kf[5]+q0[6]*kf[6]+q0[7]*kf[7];
    unpack8_fp8(make_uint2(kv1.x, kv1.y), kf);
    float p1 = q1[0]*kf[0]+q1[1]*kf[1]+q1[2]*kf[2]+q1[3]*kf[3]+
               q1[4]*kf[4]+q1[5]*kf[5]+q1[6]*kf[6]+q1[7]*kf[7];
#pragma unroll
    for (int ox = 1; ox <= 8; ox <<= 1) {
      p0 += __shfl_xor(p0, ox);
      p1 += __shfl_xor(p1, ox);
    }
    float w0 = valid ? __expf(p0 * INV_SQRT_CH) : 0.f;
    float w1 = valid ? __expf(p1 * INV_SQRT_CH) : 0.f;
    float vf[8];
    unpack8_fp8(make_uint2(kv0.z, kv0.w), vf);
    s0 += w0;
#pragma unroll
    for (int c = 0; c < 8; ++c) a0[c] = fmaf(w0, vf[c], a0[c]);
    unpack8_fp8(make_uint2(kv1.z, kv1.w), vf);
    s1 += w1;
#pragma unroll
    for (int c = 0; c < 8; ++c) a1[c] = fmaf(w1, vf[c], a1[c]);
  }
#pragma unroll
  for (int ox = 16; ox <= 32; ox <<= 1) {
    s0 += __shfl_xor(s0, ox);
    s1 += __shfl_xor(s1, ox);
#pragma unroll
    for (int c = 0; c < 8; ++c) {
      a0[c] += __shfl_xor(a0[c], ox);
      a1[c] += __shfl_xor(a1[c], ox);
    }
  }
  if (g != 0) return;
  float inv0 = 1.f / (s0 + 1e-16f), inv1 = 1.f / (s1 + 1e-16f);
  uint4 ow0, ow1;
  uint_t* op0 = (uint_t*)&ow0;
  uint_t* op1 = (uint_t*)&ow1;
#pragma unroll
  for (int c = 0; c < 4; ++c) {
    float x0 = a0[2 * c] * inv0 + sk0[2 * c];
    float x1 = a0[2 * c + 1] * inv0 + sk0[2 * c + 1];
    x0 = x0 > 0.f ? x0 : expm1f(x0);
    x1 = x1 > 0.f ? x1 : expm1f(x1);
    op0[c] = (uint_t)f2bf(x0) | ((uint_t)f2bf(x1) << 16);
    float y0 = a1[2 * c] * inv1 + sk1[2 * c];
    float y1 = a1[2 * c + 1] * inv1 + sk1[2 * c + 1];
    y0 = y0 > 0.f ? y0 : expm1f(y0);
    y1 = y1 > 0.f ? y1 : expm1f(y1);
    op1[c] = (uint_t)f2bf(y0) | ((uint_t)f2bf(y1) << 16);
  }
  ushort_t* orow = H1b + (size_t)i * HID + (2 * p) * CH + li * 8;
  *(uint4*)orow = ow0;
  *(uint4*)(orow + CH) = ow1;
}

// layer 2: row 2304 B: q_h @h*256, kv_h @1024+h*256, skip @2048.
// pair p = blockIdx.y handles heads 2p, 2p+1 (q @p*512, kv @1024+p*512).
__global__ __launch_bounds__(256) void attn2_kernel(
    const char* __restrict__ BIG, const int* __restrict__ start,
    const int* __restrict__ deg, const int* __restrict__ csr,
    ushort_t* __restrict__ PairOut) {
  int wave = threadIdx.x >> 6, lane = threadIdx.x & 63;
  int li = lane & 15, g = lane >> 4;
  int i = blockIdx.x * 4 + wave;
  if (i >= N_NODES) return;
  int p = blockIdx.y;
  int qo = p * 512, kvo = 1024 + p * 512;
  int beg = start[i], end = beg + deg[i];
  const char* ip = BIG + (size_t)i * 2304;
  float q0[8], q1[8];
  unpack8(*(const uint4*)(ip + qo + li * 16), q0);
  unpack8(*(const uint4*)(ip + qo + 256 + li * 16), q1);
  float s0 = 0.f, s1 = 0.f, a0[8] = {}, a1[8] = {};
  for (int e0 = beg; e0 < end; e0 += 4) {
    int eg = e0 + g;
    bool valid = eg < end;
    int j = csr[valid ? eg : beg];
    const char* jp = BIG + (size_t)j * 2304;
    uint4 kv0 = *(const uint4*)(jp + kvo + li * 16);
    uint4 kv1 = *(const uint4*)(jp + kvo + 256 + li * 16);
    float kf[8];
    unpack8_fp8(make_uint2(kv0.x, kv0.y), kf);
    float p0 = q0[0]*kf[0]+q0[1]*kf[1]+q0[2]*kf[2]+q0[3]*kf[3]+
               q0[4]*kf[4]+q0[5]*kf[5]+q0[6]*kf[6]+q0[7]*kf[7];
    unpack8_fp8(make_uint2(kv1.x, kv1.y), kf);
    float p1 = q1[0]*kf[0]+q1[1]*kf[1]+q1[2]*kf[2]+q1[3]*kf[3]+
               q1[4]*kf[4]+q1[5]*kf[5]+q1[6]*kf[6]+q1[7]*kf[7];
#pragma unroll
    for (int ox = 1; ox <= 8; ox <<= 1) {
      p0 += __shfl_xor(p0, ox);
      p1 += __shfl_xor(p1, ox);
    }
    float w0 = valid ? __expf(p0 * INV_SQRT_CH) : 0.f;
    float w1 = valid ? __expf(p1 * INV_SQRT_CH) : 0.f;
    float vf[8];
    unpack8_fp8(make_uint2(kv0.z, kv0.w), vf);
    s0 += w0;
#pragma unroll
    for (int c = 0; c < 8; ++c) a0[c] = fmaf(w0, vf[c], a0[c]);
    unpack8_fp8(make_uint2(kv1.z, kv1.w), vf);
    s1 += w1;
#pragma unroll
    for (int c = 0; c < 8; ++c) a1[c] = fmaf(w1, vf[c], a1[c]);
  }
#pragma unroll
  for (int ox = 16; ox <= 32; ox <<= 1) {
    s0 += __shfl_xor(s0, ox);
    s1 += __shfl_xor(s1, ox);
#pragma unroll
    for (int c = 0; c < 8; ++c) {
      a0[c] += __shfl_xor(a0[c], ox);
      a1[c] += __shfl_xor(a1[c], ox);
    }
  }
  if (g != 0) return;
  float inv0 = 0.25f / (s0 + 1e-16f), inv1 = 0.25f / (s1 + 1e-16f);
  uint4 ow;
  uint_t* op = (uint_t*)&ow;
#pragma unroll
  for (int c = 0; c < 4; ++c) {
    float o0 = a0[2 * c] * inv0 + a1[2 * c] * inv1;
    float o1 = a0[2 * c + 1] * inv0 + a1[2 * c + 1] * inv1;
    op[c] = (uint_t)f2bf(o0) | ((uint_t)f2bf(o1) << 16);
  }
  *(uint4*)(PairOut + ((size_t)p * N_NODES + i) * CH + li * 8) = ow;
}

// ---------------------------------------------------------------------------
// Fused pool + ELU + classifier + log_softmax. One block of 256 per graph.
// h2[i][c] = elu(skip(BIG@2048) + PairOut0 + PairOut1).  (skip offset same)
// ---------------------------------------------------------------------------
__global__ __launch_bounds__(256) void pool_cls(
    const ushort_t* __restrict__ PairOut, const char* __restrict__ BIG,
    const int* __restrict__ gstart, const int* __restrict__ gend,
    const float* __restrict__ Wfc, const float* __restrict__ bfc,
    float* __restrict__ out) {
  int g = blockIdx.x;
  int t = threadIdx.x;
  int c = t & (CH - 1), rr = t >> 7;
  int s0 = gstart[g], e0 = gend[g];
  const ushort_t* P1 = PairOut + (size_t)N_NODES * CH;
  float sum = 0.f;
  for (int i = s0 + rr; i < e0; i += 2) {
    float sk = bf2f(*(const ushort_t*)(BIG + (size_t)i * 2304 + 2048 + c * 2));
    float m0 = bf2f(PairOut[(size_t)i * CH + c]);
    float m1 = bf2f(P1[(size_t)i * CH + c]);
    float v = sk + m0 + m1;
    v = v > 0.f ? v : expm1f(v);
    sum += v;
  }
  __shared__ float sh[256];
  __shared__ float p[CH];
  __shared__ float red[CH];
  __shared__ float logits[NCLS];
  sh[t] = sum;
  __syncthreads();
  if (t < CH) {
    float cnt = fmaxf((float)(e0 - s0), 1.f);
    p[t] = (sh[t] + sh[t + CH]) / cnt;
  }
  for (int cc = 0; cc < NCLS; ++cc) {
    __syncthreads();
    if (t < CH) red[t] = p[t] * Wfc[t * NCLS + cc];
    __syncthreads();
    for (int off = 64; off > 0; off >>= 1) {
      if (t < off) red[t] += red[t + off];
      __syncthreads();
    }
    if (t == 0) logits[cc] = red[0] + bfc[cc];
  }
  __syncthreads();
  if (t == 0) {
    float mx = -INFINITY;
    for (int cc = 0; cc < NCLS; ++cc) mx = fmaxf(mx, logits[cc]);
    float se = 0.f;
    for (int cc = 0; cc < NCLS; ++cc) se += expf(logits[cc] - mx);
    float ls = mx + logf(se);
    for (int cc = 0; cc < NCLS; ++cc) out[g * NCLS + cc] = logits[cc] - ls;
  }
}

// ---------------------------------------------------------------------------
extern "C" void kernel_launch(void* const* d_in, const int* in_sizes, int n_in,
                              void* d_out, int out_size, void* d_ws, size_t ws_size,
                              hipStream_t stream) {
  const float* x    = (const float*)d_in[0];
  const int*   ei   = (const int*)d_in[1];
  const int*   batch= (const int*)d_in[2];
  const float* Wq1 = (const float*)d_in[3];  const float* bq1 = (const float*)d_in[4];
  const float* Wk1 = (const float*)d_in[5];  const float* bk1 = (const float*)d_in[6];
  const float* Wv1 = (const float*)d_in[7];  const float* bv1 = (const float*)d_in[8];
  const float* Ws1 = (const float*)d_in[9];  const float* bs1 = (const float*)d_in[10];
  const float* Wq2 = (const float*)d_in[11]; const float* bq2 = (const float*)d_in[12];
  const float* Wk2 = (const float*)d_in[13]; const float* bk2 = (const float*)d_in[14];
  const float* Wv2 = (const float*)d_in[15]; const float* bv2 = (const float*)d_in[16];
  const float* Ws2 = (const float*)d_in[17]; const float* bs2 = (const float*)d_in[18];
  const float* Wfc = (const float*)d_in[19]; const float* bfc = (const float*)d_in[20];
  float* out = (float*)d_out;

  // Workspace (~195 MB). PairOut (bf16 2*N*128 = 25.6MB) aliases xb (dead
  // after L1 GEMMs). BIG sized for L2's 2304 B rows; L1 uses stride 1536.
  ushort_t* xb     = (ushort_t*)d_ws;                   // N x 256 bf16 (25.6 MB)
  ushort_t* PairOut= (ushort_t*)d_ws;                   // 2 x N x 128 bf16 (alias)
  char*     BIG    = (char*)(xb + (size_t)N_NODES * FEAT);  // N x 2304 B (115.2 MB)
  ushort_t* H1b    = (ushort_t*)(BIG + (size_t)N_NODES * 2304); // N x 512 bf16
  ushort_t* W1t    = H1b + (size_t)N_NODES * HID;       // 2048*256
  float*    Bh1    = (float*)(W1t + L1_W);              // 2048
  ushort_t* W2t    = (ushort_t*)(Bh1 + 2048);           // 1664*512
  float*    Bh2    = (float*)(W2t + L2_W);              // 1664
  int* deg    = (int*)(Bh2 + 1664);
  int* start  = deg + N_NODES;
  int* cursor = start + N_NODES;
  int* csr    = cursor + N_NODES;
  int* gstart = csr + EDGES;
  int* gend   = gstart + NGRAPH;
  int* counter= gend + NGRAPH;

  const int* srcp = ei;
  const int* dstp = ei + EDGES;

  // ---- prep (single launch) + CSR build ----
  prep_all<<<NB_CVT + NB_TP + NB_BIAS + NB_ZERO, 256, 0, stream>>>(
      x, xb, Wq1, Wk1, Wv1, Ws1, Wq2, Wk2, Wv2, Ws2,
      bq1, bk1, bv1, bs1, bq2, bk2, bv2, bs2,
      W1t, W2t, Bh1, Bh2, deg, counter, gstart, gend);
  hist_bounds_kernel<<<(EDGES + 255) / 256, 256, 0, stream>>>(dstp, deg, batch, gstart, gend);
  alloc_kernel<<<(N_NODES + 255) / 256, 256, 0, stream>>>(deg, counter, start, cursor);
  scatter_kernel<<<(EDGES + 255) / 256, 256, 0, stream>>>(srcp, dstp, cursor, csr);

  const int ga = (N_NODES + 3) / 4;     // 12500

  // ---- layer 1: per head-pair, 128^2 pipelined GEMM + dual-head attn ----
  for (int p = 0; p < 2; ++p) {
    gemm_bt<<<49 * 8 * 8, 256, 0, stream>>>(
        xb, W1t + (size_t)p * 1024 * FEAT, Bh1 + p * 1024, BIG, N_NODES, FEAT, 8, 1);
    attn1_kernel<<<ga, 256, 0, stream>>>(BIG, start, deg, csr, H1b, p);
  }

  // ---- layer 2: ONE GEMM (128^2 pipelined, 13 col tiles, mode 2) ----
  gemm_bt<<<49 * 8 * 13, 256, 0, stream>>>(H1b, W2t, Bh2, BIG, N_NODES, HID, 13, 2);
  attn2_kernel<<<dim3(ga, 2), 256, 0, stream>>>(BIG, start, deg, csr, PairOut);

  // ---- fused pool + classify ----
  pool_cls<<<NGRAPH, 256, 0, stream>>>(PairOut, BIG, gstart, gend, Wfc, bfc, out);
}

// Round 9
// 569.718 us; speedup vs baseline: 1.0932x; 1.0079x over previous
//
#include <hip/hip_runtime.h>
#include <math.h>
#include <stdint.h>

#define N_NODES 50000
#define FEAT    256
#define EDGES   200000
#define HEADS   4
#define CH      128
#define HID     512   // HEADS*CH
#define NGRAPH  256
#define NCLS    10

typedef unsigned short ushort_t;
typedef unsigned int uint_t;
typedef __attribute__((ext_vector_type(8))) short bf16x8;
typedef __attribute__((ext_vector_type(4))) float f32x4;
typedef __attribute__((ext_vector_type(2))) float f32x2;

__device__ __forceinline__ ushort_t f2bf(float f) {  // round-to-nearest-even
  uint_t u = __float_as_uint(f);
  u += 0x7FFF + ((u >> 16) & 1);
  return (ushort_t)(u >> 16);
}
__device__ __forceinline__ float bf2f(ushort_t h) {
  return __uint_as_float(((uint_t)h) << 16);
}
__device__ __forceinline__ void unpack8(uint4 w, float* f) {
  f[0] = bf2f((ushort_t)w.x); f[1] = bf2f((ushort_t)(w.x >> 16));
  f[2] = bf2f((ushort_t)w.y); f[3] = bf2f((ushort_t)(w.y >> 16));
  f[4] = bf2f((ushort_t)w.z); f[5] = bf2f((ushort_t)(w.z >> 16));
  f[6] = bf2f((ushort_t)w.w); f[7] = bf2f((ushort_t)(w.w >> 16));
}
// 8 x fp8(e4m3) -> 8 x f32 via v_cvt_pk_f32_fp8 (4 insts)
__device__ __forceinline__ void unpack8_fp8(uint2 w, float* f) {
  f32x2 a = __builtin_amdgcn_cvt_pk_f32_fp8((int)w.x, false);
  f32x2 b = __builtin_amdgcn_cvt_pk_f32_fp8((int)w.x, true);
  f32x2 c = __builtin_amdgcn_cvt_pk_f32_fp8((int)w.y, false);
  f32x2 d = __builtin_amdgcn_cvt_pk_f32_fp8((int)w.y, true);
  f[0] = a[0]; f[1] = a[1]; f[2] = b[0]; f[3] = b[1];
  f[4] = c[0]; f[5] = c[1]; f[6] = d[0]; f[7] = d[1];
}
__device__ __forceinline__ uint_t pack4_fp8(float f0, float f1, float f2, float f3) {
  int v = __builtin_amdgcn_cvt_pk_fp8_f32(f0, f1, 0, false);
  v = __builtin_amdgcn_cvt_pk_fp8_f32(f2, f3, v, true);
  return (uint_t)v;
}

// ---------------------------------------------------------------------------
// GEMM (round-8 verified: L2 111.5 us, MfmaUtil 34, Occ 29.4, bank-conf 0):
// 128x128 tile, BK=32, 4 waves (2x2, per-wave 64x64), 256 threads, TRIPLE-
// buffered 48 KB LDS -> 3 blocks/CU. Single-region counted-vmcnt K-tile loop.
// Per K-tile per thread: 4 global_load_lds; vmcnt(4) at boundary keeps tile
// t+2's loads in flight (never 0 mid-loop). Chunk swizzle (r>>1)&3 on stage-
// source AND read side. N tiles exact: 1024=8x128 (mode 1), 1664=13x128
// (mode 2) -> no N clamps. Output = round-7 kv-interleaved layouts:
//  mode 1 (row 1536 B): q_hh @hh*256, s_hh @512+hh*256, kv_hh @1024+hh*256
//                       (k @chunk*16, v @chunk*16+8).
//  mode 2 (row 2304 B): q_h @h*256, kv_h @1024+h*256, skip @2048.
// ---------------------------------------------------------------------------
__global__ __launch_bounds__(256) void gemm_bt(
    const ushort_t* __restrict__ A, const ushort_t* __restrict__ Bt,
    const float* __restrict__ bias, char* __restrict__ Cb,
    int M, int K, int nct, int mode) {
  __shared__ __align__(16) ushort_t smem[24576];   // 3 x 16 KB K-tile buffers
  const int tid = threadIdx.x;
  const int lane = tid & 63, wave = tid >> 6;
  const int wr = wave >> 1, wc = wave & 1;         // 2M x 2N waves

  // XCD-aware decode: rowTile = grp*8 + (b%8), ct = (b/8)%nct
  int b = blockIdx.x;
  int per = nct << 3;
  int grp = b / per;
  int rem = b - grp * per;
  int rloc = rem & 7;
  int ct = rem >> 3;
  const int rowBase = (grp * 8 + rloc) * 128;
  const int colBase = ct * 128;
  if (rowBase >= M) return;

  // ---- staging: 2 A slots + 2 B slots per thread per K-tile (4 GLL) ----
  const int s0 = tid, s1 = tid + 256;              // slot = row*4 + pos
  const int rl0 = s0 >> 2, cg0 = (s0 & 3) ^ ((rl0 >> 1) & 3);
  const int rl1 = s1 >> 2, cg1 = (s1 & 3) ^ ((rl1 >> 1) & 3);
  int ra0 = rowBase + rl0; ra0 = ra0 < M ? ra0 : M - 1;   // M-tail clamp
  int ra1 = rowBase + rl1; ra1 = ra1 < M ? ra1 : M - 1;
  const ushort_t* pa0 = A + (size_t)ra0 * K + cg0 * 8;
  const ushort_t* pa1 = A + (size_t)ra1 * K + cg1 * 8;
  const ushort_t* pb0 = Bt + (size_t)(colBase + rl0) * K + cg0 * 8;
  const ushort_t* pb1 = Bt + (size_t)(colBase + rl1) * K + cg1 * 8;
  const int dA0 = s0 * 8, dA1 = s1 * 8;            // A region [0,4096) elems
  const int dB0 = 4096 + s0 * 8, dB1 = 4096 + s1 * 8;  // B region [4096,8192)

#define GLL(gp, loff)  __builtin_amdgcn_global_load_lds( \
      (const __attribute__((address_space(1))) uint_t*)(gp), \
      (__attribute__((address_space(3))) uint_t*)(smem + (loff)), 16, 0, 0)

  const int nt = K >> 5;                           // K-tiles of 32 (8 or 16)
  // ---- prologue: stage tiles 0 (buf0) and 1 (buf1) ----
  GLL(pa0, dA0);            GLL(pa1, dA1);
  GLL(pb0, dB0);            GLL(pb1, dB1);
  GLL(pa0 + 32, 8192 + dA0); GLL(pa1 + 32, 8192 + dA1);
  GLL(pb0 + 32, 8192 + dB0); GLL(pb1 + 32, 8192 + dB1);
  pa0 += 64; pa1 += 64; pb0 += 64; pb1 += 64;      // now point at tile 2

  // ---- fragment read offsets (element units) ----
  const int fr = lane & 15, c0 = lane >> 4;
  const int pswz = (c0 ^ ((fr >> 1) & 3)) * 8;     // same swizzle as stage
  const int aOff = (wr * 64 + fr) * 32 + pswz;
  const int bOff = 4096 + (wc * 64 + fr) * 32 + pswz;

  f32x4 acc[4][4] = {};
  asm volatile("s_waitcnt vmcnt(4)" ::: "memory"); // tile0 landed, tile1 in flight
  __builtin_amdgcn_s_barrier();
  __builtin_amdgcn_sched_barrier(0);

  int cur = 0, nxt = 2;
  for (int t = 0; t < nt; ++t) {
    const ushort_t* bufc = smem + cur * 8192;
    const bool pf = (t + 2) < nt;
    bf16x8 af[4], bfr[4];
    // reads ordered so the first MFMA (af[0] x bfr[0]) unblocks earliest
    af[0] = *(const bf16x8*)(bufc + aOff);
#pragma unroll
    for (int j = 0; j < 4; ++j) bfr[j] = *(const bf16x8*)(bufc + bOff + j * 512);
#pragma unroll
    for (int i = 1; i < 4; ++i) af[i] = *(const bf16x8*)(bufc + aOff + i * 512);
    // prefetch tile t+2 into buf[nxt] (drained since its lgkmcnt(0) last tile)
    if (pf) {
      int lo = nxt * 8192;
      GLL(pa0, lo + dA0); GLL(pa1, lo + dA1);
      GLL(pb0, lo + dB0); GLL(pb1, lo + dB1);
      pa0 += 32; pa1 += 32; pb0 += 32; pb1 += 32;
    }
#pragma unroll
    for (int i = 0; i < 4; ++i)
#pragma unroll
      for (int j = 0; j < 4; ++j)
        acc[i][j] = __builtin_amdgcn_mfma_f32_16x16x32_bf16(af[i], bfr[j], acc[i][j], 0, 0, 0);
    asm volatile("s_waitcnt lgkmcnt(0)" ::: "memory");  // all reads of bufc drained
    if (pf)                asm volatile("s_waitcnt vmcnt(4)" ::: "memory"); // t+1 landed
    else if (t + 1 < nt)   asm volatile("s_waitcnt vmcnt(0)" ::: "memory"); // tail drain
    __builtin_amdgcn_s_barrier();
    __builtin_amdgcn_sched_barrier(0);
    cur = cur == 2 ? 0 : cur + 1;
    nxt = nxt == 2 ? 0 : nxt + 1;
  }
#undef GLL

  // ---- output block -> (byte offset, dtype), wave-uniform ----
  int koff, rowStride, isfp8;
  if (mode == 1) {
    rowStride = 1536;
    int hh = colBase >> 9, sel = (colBase >> 7) & 3;   // q,k,v,s
    if (sel == 0)      { koff = hh * 256; isfp8 = 0; }
    else if (sel == 3) { koff = 512 + hh * 256; isfp8 = 0; }
    else               { koff = 1024 + hh * 256 + (sel == 2 ? 8 : 0); isfp8 = 1; }
  } else {
    rowStride = 2304;
    if (colBase == 768) { koff = 2048; isfp8 = 0; }
    else {
      int n2 = (colBase < 768) ? colBase : colBase - 896;
      int hb = (colBase < 768) ? 0 : 2;
      int hh = hb + n2 / 384, r = n2 % 384, sel = r >> 7;  // q,k,v
      if (sel == 0) { koff = hh * 256; isfp8 = 0; }
      else          { koff = 1024 + hh * 256 + (sel == 2 ? 8 : 0); isfp8 = 1; }
    }
  }

  // Epilogue: per-wave LDS repack in two 32-row halves (4 KB/wave region).
  // C/D layout col=lane&15, row=(lane>>4)*4+reg (m89-verified).
  ushort_t* wbuf = smem + wave * 2048;             // 32 x 64 bf16
  const int rq = lane >> 4, fc = lane & 15;
  float bv[4];
#pragma unroll
  for (int j = 0; j < 4; ++j) bv[j] = bias[colBase + wc * 64 + j * 16 + fc];
#pragma unroll
  for (int h = 0; h < 2; ++h) {
#pragma unroll
    for (int ii = 0; ii < 2; ++ii) {
      int i = h * 2 + ii;
#pragma unroll
      for (int j = 0; j < 4; ++j)
#pragma unroll
        for (int r = 0; r < 4; ++r) {
          int rl = ii * 16 + rq * 4 + r;          // 0..31 ; (rl>>2)&3 == rq
          int cl = j * 16 + fc;                   // 0..63
          int cs = cl ^ (rq << 4);                // rq -> bank octet
          wbuf[rl * 64 + cs] = f2bf(acc[i][j][r] + bv[j]);
        }
    }
    // read back: lanes 0..7 cover all 32 banks (ci*4); remap chunk by rq
    int ci = lane & 7;
    int rbase = lane >> 3;                         // 0..7
#pragma unroll
    for (int rg = 0; rg < 4; ++rg) {
      int rr = rg * 8 + rbase;                     // 0..31
      int rowg = rowBase + wr * 64 + h * 32 + rr;
      int cg = ci ^ (((rr >> 2) & 3) << 1);
      uint4 val = *(const uint4*)(wbuf + rr * 64 + (ci << 3));
      if (rowg < M) {
        char* dstRow = Cb + (size_t)rowg * rowStride + koff;
        if (!isfp8) {
          *(uint4*)(dstRow + (wc * 64 + cg * 8) * 2) = val;
        } else {
          float f[8];
          f[0] = bf2f((ushort_t)val.x); f[1] = bf2f((ushort_t)(val.x >> 16));
          f[2] = bf2f((ushort_t)val.y); f[3] = bf2f((ushort_t)(val.y >> 16));
          f[4] = bf2f((ushort_t)val.z); f[5] = bf2f((ushort_t)(val.z >> 16));
          f[6] = bf2f((ushort_t)val.w); f[7] = bf2f((ushort_t)(val.w >> 16));
          uint2 o;
          o.x = pack4_fp8(f[0], f[1], f[2], f[3]);
          o.y = pack4_fp8(f[4], f[5], f[6], f[7]);
          *(uint2*)(dstRow + ((wc * 8 + cg) << 4)) = o;   // kv interleave
        }
      }
    }
  }
}

// ---------------------------------------------------------------------------
// prep_all: one launch, four independent regions branch on blockIdx.x:
//  [0, NB_CVT)           : x fp32 -> bf16 (vectorized)
//  [NB_CVT, +NB_TP)      : weight 32x32 tile transposes -> W1t / W2t
//  [.., +NB_BIAS)        : bias permute -> Bh1 / Bh2
//  [.., +NB_ZERO)        : zero deg/counter/gstart/gend
// ---------------------------------------------------------------------------
#define L1_W   (2048 * FEAT)
#define L2_W   (1664 * HID)
#define T1     512   // (2048/32)*(256/32)
#define T2     832   // (1664/32)*(512/32)
#define NB_CVT  12500
#define NB_TP   (T1 + T2)
#define NB_BIAS 15
#define NB_ZERO 196

__global__ __launch_bounds__(256) void prep_all(
    const float* __restrict__ x, ushort_t* __restrict__ xb,
    const float* __restrict__ Wq1, const float* __restrict__ Wk1,
    const float* __restrict__ Wv1, const float* __restrict__ Ws1,
    const float* __restrict__ Wq2, const float* __restrict__ Wk2,
    const float* __restrict__ Wv2, const float* __restrict__ Ws2,
    const float* __restrict__ bq1, const float* __restrict__ bk1,
    const float* __restrict__ bv1, const float* __restrict__ bs1,
    const float* __restrict__ bq2, const float* __restrict__ bk2,
    const float* __restrict__ bv2, const float* __restrict__ bs2,
    ushort_t* __restrict__ W1t, ushort_t* __restrict__ W2t,
    float* __restrict__ Bh1, float* __restrict__ Bh2,
    int* __restrict__ deg, int* __restrict__ counter,
    int* __restrict__ gstart, int* __restrict__ gend) {
  __shared__ float tile[32][33];
  int blk = blockIdx.x;
  if (blk < NB_CVT) {
    int i = blk * 256 + threadIdx.x;            // n4 = 3.2M exactly
    float4 f = *(const float4*)(x + (size_t)i * 4);
    uint_t lo = (uint_t)f2bf(f.x) | ((uint_t)f2bf(f.y) << 16);
    uint_t hi = (uint_t)f2bf(f.z) | ((uint_t)f2bf(f.w) << 16);
    ((uint2*)xb)[i] = make_uint2(lo, hi);
    return;
  }
  blk -= NB_CVT;
  if (blk < NB_TP) {
    int t = blk;
    const float* W; int ldw, c0, n0, k0, ldk; ushort_t* dst;
    if (t < T1) {
      int nb = t >> 3, kb = t & 7;
      n0 = nb * 32; k0 = kb * 32; ldk = FEAT; dst = W1t;
      int p = n0 >> 10, n1 = n0 & 1023, hh = n1 >> 9, sel = (n1 >> 7) & 3;
      c0 = (2 * p + hh) * CH + (n1 & (CH - 1));
      W = sel == 0 ? Wq1 : sel == 1 ? Wk1 : sel == 2 ? Wv1 : Ws1;
      ldw = HID;
    } else {
      t -= T1;
      int nb = t >> 4, kb = t & 15;
      n0 = nb * 32; k0 = kb * 32; ldk = HID; dst = W2t;
      if (n0 < 768 || n0 >= 896) {
        int n2 = (n0 < 768) ? n0 : n0 - 896;
        int hb = (n0 < 768) ? 0 : 2;
        int hh = hb + n2 / 384, r = n2 % 384, sel = r >> 7;
        c0 = hh * CH + (r & (CH - 1));
        W = sel == 0 ? Wq2 : sel == 1 ? Wk2 : Wv2;
        ldw = HID;
      } else {
        c0 = n0 - 768; W = Ws2; ldw = CH;
      }
    }
    int col = threadIdx.x & 31, rw = threadIdx.x >> 5;
#pragma unroll
    for (int ph = 0; ph < 4; ++ph) {
      int kk = rw + ph * 8;
      tile[kk][col] = W[(size_t)(k0 + kk) * ldw + c0 + col];
    }
    __syncthreads();
#pragma unroll
    for (int ph = 0; ph < 4; ++ph) {
      int dn = rw + ph * 8;
      dst[(size_t)(n0 + dn) * ldk + k0 + col] = f2bf(tile[col][dn]);
    }
    return;
  }
  blk -= NB_TP;
  if (blk < NB_BIAS) {
    int n = blk * 256 + threadIdx.x;
    if (n < 2048) {
      int p = n >> 10, n1 = n & 1023, hh = n1 >> 9, sel = (n1 >> 7) & 3;
      int c = (2 * p + hh) * CH + (n1 & (CH - 1));
      const float* bb = sel == 0 ? bq1 : sel == 1 ? bk1 : sel == 2 ? bv1 : bs1;
      Bh1[n] = bb[c];
    } else if (n < 2048 + 1664) {
      int n2 = n - 2048;
      if (n2 < 768 || n2 >= 896) {
        int nn = (n2 < 768) ? n2 : n2 - 896;
        int hb = (n2 < 768) ? 0 : 2;
        int hh = hb + nn / 384, r = nn % 384, sel = r >> 7;
        int c = hh * CH + (r & (CH - 1));
        const float* bb = sel == 0 ? bq2 : sel == 1 ? bk2 : bv2;
        Bh2[n2] = bb[c];
      } else {
        Bh2[n2] = bs2[n2 - 768];
      }
    }
    return;
  }
  blk -= NB_BIAS;
  {
    int i = blk * 256 + threadIdx.x;
    if (i < N_NODES) deg[i] = 0;
    if (i < NGRAPH) { gstart[i] = 0; gend[i] = 0; }
    if (i == 0) counter[0] = 0;
  }
}

// ---------------------------------------------------------------------------
// CSR build: hist+bounds -> alloc (wave atomic) -> scatter
// ---------------------------------------------------------------------------
__global__ void hist_bounds_kernel(const int* __restrict__ dst, int* __restrict__ deg,
                                   const int* __restrict__ batch,
                                   int* __restrict__ gstart, int* __restrict__ gend) {
  int t = blockIdx.x * blockDim.x + threadIdx.x;
  if (t < EDGES) atomicAdd(&deg[dst[t]], 1);
  if (t < N_NODES) {
    int b = batch[t];
    if (t == 0 || batch[t - 1] != b) gstart[b] = t;
    if (t == N_NODES - 1 || batch[t + 1] != b) gend[b] = t + 1;
  }
}

__global__ void alloc_kernel(const int* __restrict__ deg, int* __restrict__ counter,
                             int* __restrict__ start, int* __restrict__ cursor) {
  int i = blockIdx.x * blockDim.x + threadIdx.x;
  int lane = threadIdx.x & 63;
  int v = (i < N_NODES) ? deg[i] : 0;
  int sum = v;
#pragma unroll
  for (int off = 1; off < 64; off <<= 1) {
    int t = __shfl_up(sum, off);
    if (lane >= off) sum += t;
  }
  int excl = sum - v;
  int waveTot = __shfl(sum, 63);
  int base = 0;
  if (lane == 63) base = atomicAdd(counter, waveTot);
  base = __shfl(base, 63);
  if (i < N_NODES) {
    start[i] = base + excl;
    cursor[i] = base + excl;
  }
}

__global__ void scatter_kernel(const int* __restrict__ src, const int* __restrict__ dst,
                               int* __restrict__ cursor, int* __restrict__ csr) {
  int e = blockIdx.x * blockDim.x + threadIdx.x;
  if (e < EDGES) {
    int pos = atomicAdd(&cursor[dst[e]], 1);
    csr[pos] = src[e];
  }
}

// ---------------------------------------------------------------------------
// Attention. attn1 (round-17 form): dual-head waves + fused kv gathers.
// attn2 (round-19): ONE block per node does ALL FOUR heads — per edge the kv
// reads are a single 1024-B contiguous burst (4 x uint4/lane); one launch,
// one csr walk, f32 head-sum, single bf16 output row POut[i][c].
// ---------------------------------------------------------------------------
#define INV_SQRT_CH 0.08838834764831845f

// layer 1, pair p: row 1536 B: q0 @0, q1 @256, s0 @512, s1 @768,
// kv0 @1024, kv1 @1280. One wave = one node, BOTH heads of the pair.
__global__ __launch_bounds__(256) void attn1_kernel(
    const char* __restrict__ BIG, const int* __restrict__ start,
    const int* __restrict__ deg, const int* __restrict__ csr,
    ushort_t* __restrict__ H1b, int p) {
  int wave = threadIdx.x >> 6, lane = threadIdx.x & 63;
  int li = lane & 15, g = lane >> 4;
  int i = blockIdx.x * 4 + wave;
  if (i >= N_NODES) return;
  int beg = start[i], end = beg + deg[i];
  const char* ip = BIG + (size_t)i * 1536;
  float q0[8], q1[8], sk0[8], sk1[8];
  unpack8(*(const uint4*)(ip + li * 16), q0);
  unpack8(*(const uint4*)(ip + 256 + li * 16), q1);
  unpack8(*(const uint4*)(ip + 512 + li * 16), sk0);   // hoisted: hides in loop
  unpack8(*(const uint4*)(ip + 768 + li * 16), sk1);
  float s0 = 0.f, s1 = 0.f, a0[8] = {}, a1[8] = {};
  for (int e0 = beg; e0 < end; e0 += 4) {
    int eg = e0 + g;
    bool valid = eg < end;
    int j = csr[valid ? eg : beg];
    const char* jp = BIG + (size_t)j * 1536;
    uint4 kv0 = *(const uint4*)(jp + 1024 + li * 16);
    uint4 kv1 = *(const uint4*)(jp + 1280 + li * 16);
    float kf[8];
    unpack8_fp8(make_uint2(kv0.x, kv0.y), kf);
    float p0 = q0[0]*kf[0]+q0[1]*kf[1]+q0[2]*kf[2]+q0[3]*kf[3]+
               q0[4]*kf[4]+q0[5]*kf[5]+q0[6]*kf[6]+q0[7]*kf[7];
    unpack8_fp8(make_uint2(kv1.x, kv1.y), kf);
    float p1 = q1[0]*kf[0]+q1[1]*kf[1]+q1[2]*kf[2]+q1[3]*kf[3]+
               q1[4]*kf[4]+q1[5]*kf[5]+q1[6]*kf[6]+q1[7]*kf[7];
#pragma unroll
    for (int ox = 1; ox <= 8; ox <<= 1) {
      p0 += __shfl_xor(p0, ox);
      p1 += __shfl_xor(p1, ox);
    }
    float w0 = valid ? __expf(p0 * INV_SQRT_CH) : 0.f;
    float w1 = valid ? __expf(p1 * INV_SQRT_CH) : 0.f;
    float vf[8];
    unpack8_fp8(make_uint2(kv0.z, kv0.w), vf);
    s0 += w0;
#pragma unroll
    for (int c = 0; c < 8; ++c) a0[c] = fmaf(w0, vf[c], a0[c]);
    unpack8_fp8(make_uint2(kv1.z, kv1.w), vf);
    s1 += w1;
#pragma unroll
    for (int c = 0; c < 8; ++c) a1[c] = fmaf(w1, vf[c], a1[c]);
  }
#pragma unroll
  for (int ox = 16; ox <= 32; ox <<= 1) {
    s0 += __shfl_xor(s0, ox);
    s1 += __shfl_xor(s1, ox);
#pragma unroll
    for (int c = 0; c < 8; ++c) {
      a0[c] += __shfl_xor(a0[c], ox);
      a1[c] += __shfl_xor(a1[c], ox);
    }
  }
  if (g != 0) return;
  float inv0 = 1.f / (s0 + 1e-16f), inv1 = 1.f / (s1 + 1e-16f);
  uint4 ow0, ow1;
  uint_t* op0 = (uint_t*)&ow0;
  uint_t* op1 = (uint_t*)&ow1;
#pragma unroll
  for (int c = 0; c < 4; ++c) {
    float x0 = a0[2 * c] * inv0 + sk0[2 * c];
    float x1 = a0[2 * c + 1] * inv0 + sk0[2 * c + 1];
    x0 = x0 > 0.f ? x0 : expm1f(x0);
    x1 = x1 > 0.f ? x1 : expm1f(x1);
    op0[c] = (uint_t)f2bf(x0) | ((uint_t)f2bf(x1) << 16);
    float y0 = a1[2 * c] * inv1 + sk1[2 * c];
    float y1 = a1[2 * c + 1] * inv1 + sk1[2 * c + 1];
    y0 = y0 > 0.f ? y0 : expm1f(y0);
    y1 = y1 > 0.f ? y1 : expm1f(y1);
    op1[c] = (uint_t)f2bf(y0) | ((uint_t)f2bf(y1) << 16);
  }
  ushort_t* orow = H1b + (size_t)i * HID + (2 * p) * CH + li * 8;
  *(uint4*)orow = ow0;
  *(uint4*)(orow + CH) = ow1;
}

// layer 2 (round-19 merged): row 2304 B: q_h @h*256, kv_h @1024+h*256,
// skip @2048. ONE block per node, all 4 heads; per edge: 1024-B contiguous
// kv burst. Writes POut[i][c] = 0.25 * sum_h msg_h (bf16); pool adds skip.
__global__ __launch_bounds__(256) void attn2_kernel(
    const char* __restrict__ BIG, const int* __restrict__ start,
    const int* __restrict__ deg, const int* __restrict__ csr,
    ushort_t* __restrict__ POut) {
  int wave = threadIdx.x >> 6, lane = threadIdx.x & 63;
  int li = lane & 15, g = lane >> 4;
  int i = blockIdx.x * 4 + wave;
  if (i >= N_NODES) return;
  int beg = start[i], end = beg + deg[i];
  const char* ip = BIG + (size_t)i * 2304;
  float q[4][8];
#pragma unroll
  for (int h = 0; h < 4; ++h)
    unpack8(*(const uint4*)(ip + h * 256 + li * 16), q[h]);
  float s[4] = {}, a[4][8] = {};
  for (int e0 = beg; e0 < end; e0 += 4) {
    int eg = e0 + g;
    bool valid = eg < end;
    int j = csr[valid ? eg : beg];
    const char* jp = BIG + (size_t)j * 2304 + 1024;
    uint4 kv[4];
#pragma unroll
    for (int h = 0; h < 4; ++h) kv[h] = *(const uint4*)(jp + h * 256 + li * 16);
#pragma unroll
    for (int h = 0; h < 4; ++h) {
      float kf[8];
      unpack8_fp8(make_uint2(kv[h].x, kv[h].y), kf);
      float pd = q[h][0]*kf[0]+q[h][1]*kf[1]+q[h][2]*kf[2]+q[h][3]*kf[3]+
                 q[h][4]*kf[4]+q[h][5]*kf[5]+q[h][6]*kf[6]+q[h][7]*kf[7];
#pragma unroll
      for (int ox = 1; ox <= 8; ox <<= 1) pd += __shfl_xor(pd, ox);
      float w = valid ? __expf(pd * INV_SQRT_CH) : 0.f;
      float vf[8];
      unpack8_fp8(make_uint2(kv[h].z, kv[h].w), vf);
      s[h] += w;
#pragma unroll
      for (int c = 0; c < 8; ++c) a[h][c] = fmaf(w, vf[c], a[h][c]);
    }
  }
#pragma unroll
  for (int ox = 16; ox <= 32; ox <<= 1) {
#pragma unroll
    for (int h = 0; h < 4; ++h) {
      s[h] += __shfl_xor(s[h], ox);
#pragma unroll
      for (int c = 0; c < 8; ++c) a[h][c] += __shfl_xor(a[h][c], ox);
    }
  }
  if (g != 0) return;
  float o[8] = {};
#pragma unroll
  for (int h = 0; h < 4; ++h) {
    float inv = 0.25f / (s[h] + 1e-16f);
#pragma unroll
    for (int c = 0; c < 8; ++c) o[c] = fmaf(a[h][c], inv, o[c]);
  }
  uint4 ow;
  uint_t* op = (uint_t*)&ow;
#pragma unroll
  for (int c = 0; c < 4; ++c)
    op[c] = (uint_t)f2bf(o[2 * c]) | ((uint_t)f2bf(o[2 * c + 1]) << 16);
  *(uint4*)(POut + (size_t)i * CH + li * 8) = ow;
}

// ---------------------------------------------------------------------------
// Fused pool + ELU + classifier + log_softmax. One block of 256 per graph.
// h2[i][c] = elu(skip(BIG@2048) + POut[i][c]).
// ---------------------------------------------------------------------------
__global__ __launch_bounds__(256) void pool_cls(
    const ushort_t* __restrict__ POut, const char* __restrict__ BIG,
    const int* __restrict__ gstart, const int* __restrict__ gend,
    const float* __restrict__ Wfc, const float* __restrict__ bfc,
    float* __restrict__ out) {
  int g = blockIdx.x;
  int t = threadIdx.x;
  int c = t & (CH - 1), rr = t >> 7;
  int s0 = gstart[g], e0 = gend[g];
  float sum = 0.f;
  for (int i = s0 + rr; i < e0; i += 2) {
    float sk = bf2f(*(const ushort_t*)(BIG + (size_t)i * 2304 + 2048 + c * 2));
    float m0 = bf2f(POut[(size_t)i * CH + c]);
    float v = sk + m0;
    v = v > 0.f ? v : expm1f(v);
    sum += v;
  }
  __shared__ float sh[256];
  __shared__ float p[CH];
  __shared__ float red[CH];
  __shared__ float logits[NCLS];
  sh[t] = sum;
  __syncthreads();
  if (t < CH) {
    float cnt = fmaxf((float)(e0 - s0), 1.f);
    p[t] = (sh[t] + sh[t + CH]) / cnt;
  }
  for (int cc = 0; cc < NCLS; ++cc) {
    __syncthreads();
    if (t < CH) red[t] = p[t] * Wfc[t * NCLS + cc];
    __syncthreads();
    for (int off = 64; off > 0; off >>= 1) {
      if (t < off) red[t] += red[t + off];
      __syncthreads();
    }
    if (t == 0) logits[cc] = red[0] + bfc[cc];
  }
  __syncthreads();
  if (t == 0) {
    float mx = -INFINITY;
    for (int cc = 0; cc < NCLS; ++cc) mx = fmaxf(mx, logits[cc]);
    float se = 0.f;
    for (int cc = 0; cc < NCLS; ++cc) se += expf(logits[cc] - mx);
    float ls = mx + logf(se);
    for (int cc = 0; cc < NCLS; ++cc) out[g * NCLS + cc] = logits[cc] - ls;
  }
}

// ---------------------------------------------------------------------------
extern "C" void kernel_launch(void* const* d_in, const int* in_sizes, int n_in,
                              void* d_out, int out_size, void* d_ws, size_t ws_size,
                              hipStream_t stream) {
  const float* x    = (const float*)d_in[0];
  const int*   ei   = (const int*)d_in[1];
  const int*   batch= (const int*)d_in[2];
  const float* Wq1 = (const float*)d_in[3];  const float* bq1 = (const float*)d_in[4];
  const float* Wk1 = (const float*)d_in[5];  const float* bk1 = (const float*)d_in[6];
  const float* Wv1 = (const float*)d_in[7];  const float* bv1 = (const float*)d_in[8];
  const float* Ws1 = (const float*)d_in[9];  const float* bs1 = (const float*)d_in[10];
  const float* Wq2 = (const float*)d_in[11]; const float* bq2 = (const float*)d_in[12];
  const float* Wk2 = (const float*)d_in[13]; const float* bk2 = (const float*)d_in[14];
  const float* Wv2 = (const float*)d_in[15]; const float* bv2 = (const float*)d_in[16];
  const float* Ws2 = (const float*)d_in[17]; const float* bs2 = (const float*)d_in[18];
  const float* Wfc = (const float*)d_in[19]; const float* bfc = (const float*)d_in[20];
  float* out = (float*)d_out;

  // Workspace (~195 MB). POut (bf16 N*128 = 12.8MB) aliases xb (dead after
  // L1 GEMMs). BIG sized for L2's 2304 B rows; L1 uses stride 1536.
  ushort_t* xb     = (ushort_t*)d_ws;                   // N x 256 bf16 (25.6 MB)
  ushort_t* POut   = (ushort_t*)d_ws;                   // N x 128 bf16 (alias)
  char*     BIG    = (char*)(xb + (size_t)N_NODES * FEAT);  // N x 2304 B (115.2 MB)
  ushort_t* H1b    = (ushort_t*)(BIG + (size_t)N_NODES * 2304); // N x 512 bf16
  ushort_t* W1t    = H1b + (size_t)N_NODES * HID;       // 2048*256
  float*    Bh1    = (float*)(W1t + L1_W);              // 2048
  ushort_t* W2t    = (ushort_t*)(Bh1 + 2048);           // 1664*512
  float*    Bh2    = (float*)(W2t + L2_W);              // 1664
  int* deg    = (int*)(Bh2 + 1664);
  int* start  = deg + N_NODES;
  int* cursor = start + N_NODES;
  int* csr    = cursor + N_NODES;
  int* gstart = csr + EDGES;
  int* gend   = gstart + NGRAPH;
  int* counter= gend + NGRAPH;

  const int* srcp = ei;
  const int* dstp = ei + EDGES;

  // ---- prep (single launch) + CSR build ----
  prep_all<<<NB_CVT + NB_TP + NB_BIAS + NB_ZERO, 256, 0, stream>>>(
      x, xb, Wq1, Wk1, Wv1, Ws1, Wq2, Wk2, Wv2, Ws2,
      bq1, bk1, bv1, bs1, bq2, bk2, bv2, bs2,
      W1t, W2t, Bh1, Bh2, deg, counter, gstart, gend);
  hist_bounds_kernel<<<(EDGES + 255) / 256, 256, 0, stream>>>(dstp, deg, batch, gstart, gend);
  alloc_kernel<<<(N_NODES + 255) / 256, 256, 0, stream>>>(deg, counter, start, cursor);
  scatter_kernel<<<(EDGES + 255) / 256, 256, 0, stream>>>(srcp, dstp, cursor, csr);

  const int ga = (N_NODES + 3) / 4;     // 12500

  // ---- layer 1: per head-pair, 128^2 pipelined GEMM + dual-head attn ----
  for (int p = 0; p < 2; ++p) {
    gemm_bt<<<49 * 8 * 8, 256, 0, stream>>>(
        xb, W1t + (size_t)p * 1024 * FEAT, Bh1 + p * 1024, BIG, N_NODES, FEAT, 8, 1);
    attn1_kernel<<<ga, 256, 0, stream>>>(BIG, start, deg, csr, H1b, p);
  }

  // ---- layer 2: ONE GEMM (128^2 pipelined, 13 col tiles, mode 2) ----
  gemm_bt<<<49 * 8 * 13, 256, 0, stream>>>(H1b, W2t, Bh2, BIG, N_NODES, HID, 13, 2);
  // ---- attn2: ONE launch, all 4 heads per node (round-19 merge) ----
  attn2_kernel<<<ga, 256, 0, stream>>>(BIG, start, deg, csr, POut);

  // ---- fused pool + classify ----
  pool_cls<<<NGRAPH, 256, 0, stream>>>(POut, BIG, gstart, gend, Wfc, bfc, out);
}

// Round 10
// 564.792 us; speedup vs baseline: 1.1027x; 1.0087x over previous
//
#include <hip/hip_runtime.h>
#include <math.h>
#include <stdint.h>

#define N_NODES 50000
#define FEAT    256
#define EDGES   200000
#define HEADS   4
#define CH      128
#define HID     512   // HEADS*CH
#define NGRAPH  256
#define NCLS    10

typedef unsigned short ushort_t;
typedef unsigned int uint_t;
typedef __attribute__((ext_vector_type(8))) short bf16x8;
typedef __attribute__((ext_vector_type(4))) float f32x4;
typedef __attribute__((ext_vector_type(2))) float f32x2;

__device__ __forceinline__ ushort_t f2bf(float f) {  // round-to-nearest-even
  uint_t u = __float_as_uint(f);
  u += 0x7FFF + ((u >> 16) & 1);
  return (ushort_t)(u >> 16);
}
__device__ __forceinline__ float bf2f(ushort_t h) {
  return __uint_as_float(((uint_t)h) << 16);
}
__device__ __forceinline__ void unpack8(uint4 w, float* f) {
  f[0] = bf2f((ushort_t)w.x); f[1] = bf2f((ushort_t)(w.x >> 16));
  f[2] = bf2f((ushort_t)w.y); f[3] = bf2f((ushort_t)(w.y >> 16));
  f[4] = bf2f((ushort_t)w.z); f[5] = bf2f((ushort_t)(w.z >> 16));
  f[6] = bf2f((ushort_t)w.w); f[7] = bf2f((ushort_t)(w.w >> 16));
}
// 8 x fp8(e4m3) -> 8 x f32 via v_cvt_pk_f32_fp8 (4 insts)
__device__ __forceinline__ void unpack8_fp8(uint2 w, float* f) {
  f32x2 a = __builtin_amdgcn_cvt_pk_f32_fp8((int)w.x, false);
  f32x2 b = __builtin_amdgcn_cvt_pk_f32_fp8((int)w.x, true);
  f32x2 c = __builtin_amdgcn_cvt_pk_f32_fp8((int)w.y, false);
  f32x2 d = __builtin_amdgcn_cvt_pk_f32_fp8((int)w.y, true);
  f[0] = a[0]; f[1] = a[1]; f[2] = b[0]; f[3] = b[1];
  f[4] = c[0]; f[5] = c[1]; f[6] = d[0]; f[7] = d[1];
}
__device__ __forceinline__ uint_t pack4_fp8(float f0, float f1, float f2, float f3) {
  int v = __builtin_amdgcn_cvt_pk_fp8_f32(f0, f1, 0, false);
  v = __builtin_amdgcn_cvt_pk_fp8_f32(f2, f3, v, true);
  return (uint_t)v;
}

// ---------------------------------------------------------------------------
// Round-20 LAYOUT: unified 2304-B BIG rows for BOTH layers.
//  L1: q_H @H*256, kv_H @1024+H*256 (k @c*16, v @c*16+8), H=0..3;
//      skip s_H routed by the GEMM epilogue DIRECTLY into H1b (stride 1024 B,
//      @H*256) — enables ONE L1 GEMM (N=2048) + ONE all-4-head attn1.
//  L2: q_H @H*256, kv_H @1024+H*256, skip @2048 (unchanged).
// W1t/Bh1 orderings index globally (H=colBase>>9, sel=(colBase>>7)&3), so
// prep_all is untouched. attn1 now mirrors attn2's merged structure and
// should finally be large enough (~150 us) to appear in the top-5 counters.
// ---------------------------------------------------------------------------

// ---------------------------------------------------------------------------
// GEMM (round-8 verified loop: L2 111 us, MfmaUtil 34, Occ 29.4, bank-conf 0):
// 128x128 tile, BK=32, 4 waves (2x2, per-wave 64x64), 256 threads, TRIPLE-
// buffered 48 KB LDS -> 3 blocks/CU. Single-region counted-vmcnt K-tile loop.
// vmcnt(4) at boundary keeps tile t+2's loads in flight (never 0 mid-loop).
// Chunk swizzle (r>>1)&3 on stage-source AND read side. N tiles exact:
// 2048=16x128 (mode 1), 1664=13x128 (mode 2) -> no N clamps.
// Cb2 = second output base (H1b) for mode-1 skip blocks.
// ---------------------------------------------------------------------------
__global__ __launch_bounds__(256) void gemm_bt(
    const ushort_t* __restrict__ A, const ushort_t* __restrict__ Bt,
    const float* __restrict__ bias, char* __restrict__ Cb,
    char* __restrict__ Cb2, int M, int K, int nct, int mode) {
  __shared__ __align__(16) ushort_t smem[24576];   // 3 x 16 KB K-tile buffers
  const int tid = threadIdx.x;
  const int lane = tid & 63, wave = tid >> 6;
  const int wr = wave >> 1, wc = wave & 1;         // 2M x 2N waves

  // XCD-aware decode: rowTile = grp*8 + (b%8), ct = (b/8)%nct
  int b = blockIdx.x;
  int per = nct << 3;
  int grp = b / per;
  int rem = b - grp * per;
  int rloc = rem & 7;
  int ct = rem >> 3;
  const int rowBase = (grp * 8 + rloc) * 128;
  const int colBase = ct * 128;
  if (rowBase >= M) return;

  // ---- staging: 2 A slots + 2 B slots per thread per K-tile (4 GLL) ----
  const int s0 = tid, s1 = tid + 256;              // slot = row*4 + pos
  const int rl0 = s0 >> 2, cg0 = (s0 & 3) ^ ((rl0 >> 1) & 3);
  const int rl1 = s1 >> 2, cg1 = (s1 & 3) ^ ((rl1 >> 1) & 3);
  int ra0 = rowBase + rl0; ra0 = ra0 < M ? ra0 : M - 1;   // M-tail clamp
  int ra1 = rowBase + rl1; ra1 = ra1 < M ? ra1 : M - 1;
  const ushort_t* pa0 = A + (size_t)ra0 * K + cg0 * 8;
  const ushort_t* pa1 = A + (size_t)ra1 * K + cg1 * 8;
  const ushort_t* pb0 = Bt + (size_t)(colBase + rl0) * K + cg0 * 8;
  const ushort_t* pb1 = Bt + (size_t)(colBase + rl1) * K + cg1 * 8;
  const int dA0 = s0 * 8, dA1 = s1 * 8;            // A region [0,4096) elems
  const int dB0 = 4096 + s0 * 8, dB1 = 4096 + s1 * 8;  // B region [4096,8192)

#define GLL(gp, loff)  __builtin_amdgcn_global_load_lds( \
      (const __attribute__((address_space(1))) uint_t*)(gp), \
      (__attribute__((address_space(3))) uint_t*)(smem + (loff)), 16, 0, 0)

  const int nt = K >> 5;                           // K-tiles of 32 (8 or 16)
  // ---- prologue: stage tiles 0 (buf0) and 1 (buf1) ----
  GLL(pa0, dA0);            GLL(pa1, dA1);
  GLL(pb0, dB0);            GLL(pb1, dB1);
  GLL(pa0 + 32, 8192 + dA0); GLL(pa1 + 32, 8192 + dA1);
  GLL(pb0 + 32, 8192 + dB0); GLL(pb1 + 32, 8192 + dB1);
  pa0 += 64; pa1 += 64; pb0 += 64; pb1 += 64;      // now point at tile 2

  // ---- fragment read offsets (element units) ----
  const int fr = lane & 15, c0 = lane >> 4;
  const int pswz = (c0 ^ ((fr >> 1) & 3)) * 8;     // same swizzle as stage
  const int aOff = (wr * 64 + fr) * 32 + pswz;
  const int bOff = 4096 + (wc * 64 + fr) * 32 + pswz;

  f32x4 acc[4][4] = {};
  asm volatile("s_waitcnt vmcnt(4)" ::: "memory"); // tile0 landed, tile1 in flight
  __builtin_amdgcn_s_barrier();
  __builtin_amdgcn_sched_barrier(0);

  int cur = 0, nxt = 2;
  for (int t = 0; t < nt; ++t) {
    const ushort_t* bufc = smem + cur * 8192;
    const bool pf = (t + 2) < nt;
    bf16x8 af[4], bfr[4];
    // reads ordered so the first MFMA (af[0] x bfr[0]) unblocks earliest
    af[0] = *(const bf16x8*)(bufc + aOff);
#pragma unroll
    for (int j = 0; j < 4; ++j) bfr[j] = *(const bf16x8*)(bufc + bOff + j * 512);
#pragma unroll
    for (int i = 1; i < 4; ++i) af[i] = *(const bf16x8*)(bufc + aOff + i * 512);
    // prefetch tile t+2 into buf[nxt] (drained since its lgkmcnt(0) last tile)
    if (pf) {
      int lo = nxt * 8192;
      GLL(pa0, lo + dA0); GLL(pa1, lo + dA1);
      GLL(pb0, lo + dB0); GLL(pb1, lo + dB1);
      pa0 += 32; pa1 += 32; pb0 += 32; pb1 += 32;
    }
#pragma unroll
    for (int i = 0; i < 4; ++i)
#pragma unroll
      for (int j = 0; j < 4; ++j)
        acc[i][j] = __builtin_amdgcn_mfma_f32_16x16x32_bf16(af[i], bfr[j], acc[i][j], 0, 0, 0);
    asm volatile("s_waitcnt lgkmcnt(0)" ::: "memory");  // all reads of bufc drained
    if (pf)                asm volatile("s_waitcnt vmcnt(4)" ::: "memory"); // t+1 landed
    else if (t + 1 < nt)   asm volatile("s_waitcnt vmcnt(0)" ::: "memory"); // tail drain
    __builtin_amdgcn_s_barrier();
    __builtin_amdgcn_sched_barrier(0);
    cur = cur == 2 ? 0 : cur + 1;
    nxt = nxt == 2 ? 0 : nxt + 1;
  }
#undef GLL

  // ---- output block -> (base, stride, byte offset, dtype), wave-uniform ----
  char* obase; int ostride, koff, isfp8;
  if (mode == 1) {
    int H = colBase >> 9, sel = (colBase >> 7) & 3;     // q,k,v,s; H = head
    if (sel == 0)      { obase = Cb;  ostride = 2304; koff = H * 256; isfp8 = 0; }
    else if (sel == 3) { obase = Cb2; ostride = 1024; koff = H * 256; isfp8 = 0; }
    else { obase = Cb; ostride = 2304;
           koff = 1024 + H * 256 + (sel == 2 ? 8 : 0); isfp8 = 1; }
  } else {
    obase = Cb; ostride = 2304;
    if (colBase == 768) { koff = 2048; isfp8 = 0; }
    else {
      int n2 = (colBase < 768) ? colBase : colBase - 896;
      int hb = (colBase < 768) ? 0 : 2;
      int hh = hb + n2 / 384, r = n2 % 384, sel = r >> 7;  // q,k,v
      if (sel == 0) { koff = hh * 256; isfp8 = 0; }
      else          { koff = 1024 + hh * 256 + (sel == 2 ? 8 : 0); isfp8 = 1; }
    }
  }

  // Epilogue: per-wave LDS repack in two 32-row halves (4 KB/wave region).
  // C/D layout col=lane&15, row=(lane>>4)*4+reg (m89-verified).
  ushort_t* wbuf = smem + wave * 2048;             // 32 x 64 bf16
  const int rq = lane >> 4, fc = lane & 15;
  float bv[4];
#pragma unroll
  for (int j = 0; j < 4; ++j) bv[j] = bias[colBase + wc * 64 + j * 16 + fc];
#pragma unroll
  for (int h = 0; h < 2; ++h) {
#pragma unroll
    for (int ii = 0; ii < 2; ++ii) {
      int i = h * 2 + ii;
#pragma unroll
      for (int j = 0; j < 4; ++j)
#pragma unroll
        for (int r = 0; r < 4; ++r) {
          int rl = ii * 16 + rq * 4 + r;          // 0..31 ; (rl>>2)&3 == rq
          int cl = j * 16 + fc;                   // 0..63
          int cs = cl ^ (rq << 4);                // rq -> bank octet
          wbuf[rl * 64 + cs] = f2bf(acc[i][j][r] + bv[j]);
        }
    }
    // read back: lanes 0..7 cover all 32 banks (ci*4); remap chunk by rq
    int ci = lane & 7;
    int rbase = lane >> 3;                         // 0..7
#pragma unroll
    for (int rg = 0; rg < 4; ++rg) {
      int rr = rg * 8 + rbase;                     // 0..31
      int rowg = rowBase + wr * 64 + h * 32 + rr;
      int cg = ci ^ (((rr >> 2) & 3) << 1);
      uint4 val = *(const uint4*)(wbuf + rr * 64 + (ci << 3));
      if (rowg < M) {
        char* dstRow = obase + (size_t)rowg * ostride + koff;
        if (!isfp8) {
          *(uint4*)(dstRow + (wc * 64 + cg * 8) * 2) = val;
        } else {
          float f[8];
          f[0] = bf2f((ushort_t)val.x); f[1] = bf2f((ushort_t)(val.x >> 16));
          f[2] = bf2f((ushort_t)val.y); f[3] = bf2f((ushort_t)(val.y >> 16));
          f[4] = bf2f((ushort_t)val.z); f[5] = bf2f((ushort_t)(val.z >> 16));
          f[6] = bf2f((ushort_t)val.w); f[7] = bf2f((ushort_t)(val.w >> 16));
          uint2 o;
          o.x = pack4_fp8(f[0], f[1], f[2], f[3]);
          o.y = pack4_fp8(f[4], f[5], f[6], f[7]);
          *(uint2*)(dstRow + ((wc * 8 + cg) << 4)) = o;   // kv interleave
        }
      }
    }
  }
}

// ---------------------------------------------------------------------------
// prep_all: one launch, four independent regions branch on blockIdx.x:
//  [0, NB_CVT)           : x fp32 -> bf16 (vectorized)
//  [NB_CVT, +NB_TP)      : weight 32x32 tile transposes -> W1t / W2t
//  [.., +NB_BIAS)        : bias permute -> Bh1 / Bh2
//  [.., +NB_ZERO)        : zero deg/counter/gstart/gend
// ---------------------------------------------------------------------------
#define L1_W   (2048 * FEAT)
#define L2_W   (1664 * HID)
#define T1     512   // (2048/32)*(256/32)
#define T2     832   // (1664/32)*(512/32)
#define NB_CVT  12500
#define NB_TP   (T1 + T2)
#define NB_BIAS 15
#define NB_ZERO 196

__global__ __launch_bounds__(256) void prep_all(
    const float* __restrict__ x, ushort_t* __restrict__ xb,
    const float* __restrict__ Wq1, const float* __restrict__ Wk1,
    const float* __restrict__ Wv1, const float* __restrict__ Ws1,
    const float* __restrict__ Wq2, const float* __restrict__ Wk2,
    const float* __restrict__ Wv2, const float* __restrict__ Ws2,
    const float* __restrict__ bq1, const float* __restrict__ bk1,
    const float* __restrict__ bv1, const float* __restrict__ bs1,
    const float* __restrict__ bq2, const float* __restrict__ bk2,
    const float* __restrict__ bv2, const float* __restrict__ bs2,
    ushort_t* __restrict__ W1t, ushort_t* __restrict__ W2t,
    float* __restrict__ Bh1, float* __restrict__ Bh2,
    int* __restrict__ deg, int* __restrict__ counter,
    int* __restrict__ gstart, int* __restrict__ gend) {
  __shared__ float tile[32][33];
  int blk = blockIdx.x;
  if (blk < NB_CVT) {
    int i = blk * 256 + threadIdx.x;            // n4 = 3.2M exactly
    float4 f = *(const float4*)(x + (size_t)i * 4);
    uint_t lo = (uint_t)f2bf(f.x) | ((uint_t)f2bf(f.y) << 16);
    uint_t hi = (uint_t)f2bf(f.z) | ((uint_t)f2bf(f.w) << 16);
    ((uint2*)xb)[i] = make_uint2(lo, hi);
    return;
  }
  blk -= NB_CVT;
  if (blk < NB_TP) {
    int t = blk;
    const float* W; int ldw, c0, n0, k0, ldk; ushort_t* dst;
    if (t < T1) {
      int nb = t >> 3, kb = t & 7;
      n0 = nb * 32; k0 = kb * 32; ldk = FEAT; dst = W1t;
      int p = n0 >> 10, n1 = n0 & 1023, hh = n1 >> 9, sel = (n1 >> 7) & 3;
      c0 = (2 * p + hh) * CH + (n1 & (CH - 1));
      W = sel == 0 ? Wq1 : sel == 1 ? Wk1 : sel == 2 ? Wv1 : Ws1;
      ldw = HID;
    } else {
      t -= T1;
      int nb = t >> 4, kb = t & 15;
      n0 = nb * 32; k0 = kb * 32; ldk = HID; dst = W2t;
      if (n0 < 768 || n0 >= 896) {
        int n2 = (n0 < 768) ? n0 : n0 - 896;
        int hb = (n0 < 768) ? 0 : 2;
        int hh = hb + n2 / 384, r = n2 % 384, sel = r >> 7;
        c0 = hh * CH + (r & (CH - 1));
        W = sel == 0 ? Wq2 : sel == 1 ? Wk2 : Wv2;
        ldw = HID;
      } else {
        c0 = n0 - 768; W = Ws2; ldw = CH;
      }
    }
    int col = threadIdx.x & 31, rw = threadIdx.x >> 5;
#pragma unroll
    for (int ph = 0; ph < 4; ++ph) {
      int kk = rw + ph * 8;
      tile[kk][col] = W[(size_t)(k0 + kk) * ldw + c0 + col];
    }
    __syncthreads();
#pragma unroll
    for (int ph = 0; ph < 4; ++ph) {
      int dn = rw + ph * 8;
      dst[(size_t)(n0 + dn) * ldk + k0 + col] = f2bf(tile[col][dn]);
    }
    return;
  }
  blk -= NB_TP;
  if (blk < NB_BIAS) {
    int n = blk * 256 + threadIdx.x;
    if (n < 2048) {
      int p = n >> 10, n1 = n & 1023, hh = n1 >> 9, sel = (n1 >> 7) & 3;
      int c = (2 * p + hh) * CH + (n1 & (CH - 1));
      const float* bb = sel == 0 ? bq1 : sel == 1 ? bk1 : sel == 2 ? bv1 : bs1;
      Bh1[n] = bb[c];
    } else if (n < 2048 + 1664) {
      int n2 = n - 2048;
      if (n2 < 768 || n2 >= 896) {
        int nn = (n2 < 768) ? n2 : n2 - 896;
        int hb = (n2 < 768) ? 0 : 2;
        int hh = hb + nn / 384, r = nn % 384, sel = r >> 7;
        int c = hh * CH + (r & (CH - 1));
        const float* bb = sel == 0 ? bq2 : sel == 1 ? bk2 : bv2;
        Bh2[n2] = bb[c];
      } else {
        Bh2[n2] = bs2[n2 - 768];
      }
    }
    return;
  }
  blk -= NB_BIAS;
  {
    int i = blk * 256 + threadIdx.x;
    if (i < N_NODES) deg[i] = 0;
    if (i < NGRAPH) { gstart[i] = 0; gend[i] = 0; }
    if (i == 0) counter[0] = 0;
  }
}

// ---------------------------------------------------------------------------
// CSR build: hist+bounds -> alloc (wave atomic) -> scatter
// ---------------------------------------------------------------------------
__global__ void hist_bounds_kernel(const int* __restrict__ dst, int* __restrict__ deg,
                                   const int* __restrict__ batch,
                                   int* __restrict__ gstart, int* __restrict__ gend) {
  int t = blockIdx.x * blockDim.x + threadIdx.x;
  if (t < EDGES) atomicAdd(&deg[dst[t]], 1);
  if (t < N_NODES) {
    int b = batch[t];
    if (t == 0 || batch[t - 1] != b) gstart[b] = t;
    if (t == N_NODES - 1 || batch[t + 1] != b) gend[b] = t + 1;
  }
}

__global__ void alloc_kernel(const int* __restrict__ deg, int* __restrict__ counter,
                             int* __restrict__ start, int* __restrict__ cursor) {
  int i = blockIdx.x * blockDim.x + threadIdx.x;
  int lane = threadIdx.x & 63;
  int v = (i < N_NODES) ? deg[i] : 0;
  int sum = v;
#pragma unroll
  for (int off = 1; off < 64; off <<= 1) {
    int t = __shfl_up(sum, off);
    if (lane >= off) sum += t;
  }
  int excl = sum - v;
  int waveTot = __shfl(sum, 63);
  int base = 0;
  if (lane == 63) base = atomicAdd(counter, waveTot);
  base = __shfl(base, 63);
  if (i < N_NODES) {
    start[i] = base + excl;
    cursor[i] = base + excl;
  }
}

__global__ void scatter_kernel(const int* __restrict__ src, const int* __restrict__ dst,
                               int* __restrict__ cursor, int* __restrict__ csr) {
  int e = blockIdx.x * blockDim.x + threadIdx.x;
  if (e < EDGES) {
    int pos = atomicAdd(&cursor[dst[e]], 1);
    csr[pos] = src[e];
  }
}

// ---------------------------------------------------------------------------
// Attention (round-20): BOTH layers use the merged all-4-head per-wave form.
// Per edge ONE contiguous 1024-B kv burst (4 x uint4/lane).
// ---------------------------------------------------------------------------
#define INV_SQRT_CH 0.08838834764831845f

// layer 1 (merged): BIG row 2304 B: q_H @H*256, kv_H @1024+H*256.
// skip s_H lives in H1b @H*256 (written by the L1 GEMM). Output overwrites
// H1b[i][H*128..]: elu(msg_H + s_H). One wave per node, all 4 heads.
__global__ __launch_bounds__(256) void attn1_kernel(
    const char* __restrict__ BIG, const int* __restrict__ start,
    const int* __restrict__ deg, const int* __restrict__ csr,
    ushort_t* __restrict__ H1b) {
  int wave = threadIdx.x >> 6, lane = threadIdx.x & 63;
  int li = lane & 15, g = lane >> 4;
  int i = blockIdx.x * 4 + wave;
  if (i >= N_NODES) return;
  int beg = start[i], end = beg + deg[i];
  const char* ip = BIG + (size_t)i * 2304;
  float q[4][8];
#pragma unroll
  for (int h = 0; h < 4; ++h)
    unpack8(*(const uint4*)(ip + h * 256 + li * 16), q[h]);
  float s[4] = {}, a[4][8] = {};
  for (int e0 = beg; e0 < end; e0 += 4) {
    int eg = e0 + g;
    bool valid = eg < end;
    int j = csr[valid ? eg : beg];
    const char* jp = BIG + (size_t)j * 2304 + 1024;
    uint4 kv[4];
#pragma unroll
    for (int h = 0; h < 4; ++h) kv[h] = *(const uint4*)(jp + h * 256 + li * 16);
#pragma unroll
    for (int h = 0; h < 4; ++h) {
      float kf[8];
      unpack8_fp8(make_uint2(kv[h].x, kv[h].y), kf);
      float pd = q[h][0]*kf[0]+q[h][1]*kf[1]+q[h][2]*kf[2]+q[h][3]*kf[3]+
                 q[h][4]*kf[4]+q[h][5]*kf[5]+q[h][6]*kf[6]+q[h][7]*kf[7];
#pragma unroll
      for (int ox = 1; ox <= 8; ox <<= 1) pd += __shfl_xor(pd, ox);
      float w = valid ? __expf(pd * INV_SQRT_CH) : 0.f;
      float vf[8];
      unpack8_fp8(make_uint2(kv[h].z, kv[h].w), vf);
      s[h] += w;
#pragma unroll
      for (int c = 0; c < 8; ++c) a[h][c] = fmaf(w, vf[c], a[h][c]);
    }
  }
#pragma unroll
  for (int ox = 16; ox <= 32; ox <<= 1) {
#pragma unroll
    for (int h = 0; h < 4; ++h) {
      s[h] += __shfl_xor(s[h], ox);
#pragma unroll
      for (int c = 0; c < 8; ++c) a[h][c] += __shfl_xor(a[h][c], ox);
    }
  }
  if (g != 0) return;
  ushort_t* orow = H1b + (size_t)i * HID + li * 8;
#pragma unroll
  for (int h = 0; h < 4; ++h) {
    float inv = 1.f / (s[h] + 1e-16f);
    float sk[8];
    unpack8(*(const uint4*)(orow + h * CH), sk);   // skip written by L1 GEMM
    uint4 ow;
    uint_t* op = (uint_t*)&ow;
#pragma unroll
    for (int c = 0; c < 4; ++c) {
      float o0 = a[h][2 * c] * inv + sk[2 * c];
      float o1 = a[h][2 * c + 1] * inv + sk[2 * c + 1];
      o0 = o0 > 0.f ? o0 : expm1f(o0);
      o1 = o1 > 0.f ? o1 : expm1f(o1);
      op[c] = (uint_t)f2bf(o0) | ((uint_t)f2bf(o1) << 16);
    }
    *(uint4*)(orow + h * CH) = ow;
  }
}

// layer 2 (round-19 merged): row 2304 B: q_h @h*256, kv_h @1024+h*256,
// skip @2048. ONE block per node, all 4 heads; per edge: 1024-B contiguous
// kv burst. Writes POut[i][c] = 0.25 * sum_h msg_h (bf16); pool adds skip.
__global__ __launch_bounds__(256) void attn2_kernel(
    const char* __restrict__ BIG, const int* __restrict__ start,
    const int* __restrict__ deg, const int* __restrict__ csr,
    ushort_t* __restrict__ POut) {
  int wave = threadIdx.x >> 6, lane = threadIdx.x & 63;
  int li = lane & 15, g = lane >> 4;
  int i = blockIdx.x * 4 + wave;
  if (i >= N_NODES) return;
  int beg = start[i], end = beg + deg[i];
  const char* ip = BIG + (size_t)i * 2304;
  float q[4][8];
#pragma unroll
  for (int h = 0; h < 4; ++h)
    unpack8(*(const uint4*)(ip + h * 256 + li * 16), q[h]);
  float s[4] = {}, a[4][8] = {};
  for (int e0 = beg; e0 < end; e0 += 4) {
    int eg = e0 + g;
    bool valid = eg < end;
    int j = csr[valid ? eg : beg];
    const char* jp = BIG + (size_t)j * 2304 + 1024;
    uint4 kv[4];
#pragma unroll
    for (int h = 0; h < 4; ++h) kv[h] = *(const uint4*)(jp + h * 256 + li * 16);
#pragma unroll
    for (int h = 0; h < 4; ++h) {
      float kf[8];
      unpack8_fp8(make_uint2(kv[h].x, kv[h].y), kf);
      float pd = q[h][0]*kf[0]+q[h][1]*kf[1]+q[h][2]*kf[2]+q[h][3]*kf[3]+
                 q[h][4]*kf[4]+q[h][5]*kf[5]+q[h][6]*kf[6]+q[h][7]*kf[7];
#pragma unroll
      for (int ox = 1; ox <= 8; ox <<= 1) pd += __shfl_xor(pd, ox);
      float w = valid ? __expf(pd * INV_SQRT_CH) : 0.f;
      float vf[8];
      unpack8_fp8(make_uint2(kv[h].z, kv[h].w), vf);
      s[h] += w;
#pragma unroll
      for (int c = 0; c < 8; ++c) a[h][c] = fmaf(w, vf[c], a[h][c]);
    }
  }
#pragma unroll
  for (int ox = 16; ox <= 32; ox <<= 1) {
#pragma unroll
    for (int h = 0; h < 4; ++h) {
      s[h] += __shfl_xor(s[h], ox);
#pragma unroll
      for (int c = 0; c < 8; ++c) a[h][c] += __shfl_xor(a[h][c], ox);
    }
  }
  if (g != 0) return;
  float o[8] = {};
#pragma unroll
  for (int h = 0; h < 4; ++h) {
    float inv = 0.25f / (s[h] + 1e-16f);
#pragma unroll
    for (int c = 0; c < 8; ++c) o[c] = fmaf(a[h][c], inv, o[c]);
  }
  uint4 ow;
  uint_t* op = (uint_t*)&ow;
#pragma unroll
  for (int c = 0; c < 4; ++c)
    op[c] = (uint_t)f2bf(o[2 * c]) | ((uint_t)f2bf(o[2 * c + 1]) << 16);
  *(uint4*)(POut + (size_t)i * CH + li * 8) = ow;
}

// ---------------------------------------------------------------------------
// Fused pool + ELU + classifier + log_softmax. One block of 256 per graph.
// h2[i][c] = elu(skip(BIG@2048) + POut[i][c]).
// ---------------------------------------------------------------------------
__global__ __launch_bounds__(256) void pool_cls(
    const ushort_t* __restrict__ POut, const char* __restrict__ BIG,
    const int* __restrict__ gstart, const int* __restrict__ gend,
    const float* __restrict__ Wfc, const float* __restrict__ bfc,
    float* __restrict__ out) {
  int g = blockIdx.x;
  int t = threadIdx.x;
  int c = t & (CH - 1), rr = t >> 7;
  int s0 = gstart[g], e0 = gend[g];
  float sum = 0.f;
  for (int i = s0 + rr; i < e0; i += 2) {
    float sk = bf2f(*(const ushort_t*)(BIG + (size_t)i * 2304 + 2048 + c * 2));
    float m0 = bf2f(POut[(size_t)i * CH + c]);
    float v = sk + m0;
    v = v > 0.f ? v : expm1f(v);
    sum += v;
  }
  __shared__ float sh[256];
  __shared__ float p[CH];
  __shared__ float red[CH];
  __shared__ float logits[NCLS];
  sh[t] = sum;
  __syncthreads();
  if (t < CH) {
    float cnt = fmaxf((float)(e0 - s0), 1.f);
    p[t] = (sh[t] + sh[t + CH]) / cnt;
  }
  for (int cc = 0; cc < NCLS; ++cc) {
    __syncthreads();
    if (t < CH) red[t] = p[t] * Wfc[t * NCLS + cc];
    __syncthreads();
    for (int off = 64; off > 0; off >>= 1) {
      if (t < off) red[t] += red[t + off];
      __syncthreads();
    }
    if (t == 0) logits[cc] = red[0] + bfc[cc];
  }
  __syncthreads();
  if (t == 0) {
    float mx = -INFINITY;
    for (int cc = 0; cc < NCLS; ++cc) mx = fmaxf(mx, logits[cc]);
    float se = 0.f;
    for (int cc = 0; cc < NCLS; ++cc) se += expf(logits[cc] - mx);
    float ls = mx + logf(se);
    for (int cc = 0; cc < NCLS; ++cc) out[g * NCLS + cc] = logits[cc] - ls;
  }
}

// ---------------------------------------------------------------------------
extern "C" void kernel_launch(void* const* d_in, const int* in_sizes, int n_in,
                              void* d_out, int out_size, void* d_ws, size_t ws_size,
                              hipStream_t stream) {
  const float* x    = (const float*)d_in[0];
  const int*   ei   = (const int*)d_in[1];
  const int*   batch= (const int*)d_in[2];
  const float* Wq1 = (const float*)d_in[3];  const float* bq1 = (const float*)d_in[4];
  const float* Wk1 = (const float*)d_in[5];  const float* bk1 = (const float*)d_in[6];
  const float* Wv1 = (const float*)d_in[7];  const float* bv1 = (const float*)d_in[8];
  const float* Ws1 = (const float*)d_in[9];  const float* bs1 = (const float*)d_in[10];
  const float* Wq2 = (const float*)d_in[11]; const float* bq2 = (const float*)d_in[12];
  const float* Wk2 = (const float*)d_in[13]; const float* bk2 = (const float*)d_in[14];
  const float* Wv2 = (const float*)d_in[15]; const float* bv2 = (const float*)d_in[16];
  const float* Ws2 = (const float*)d_in[17]; const float* bs2 = (const float*)d_in[18];
  const float* Wfc = (const float*)d_in[19]; const float* bfc = (const float*)d_in[20];
  float* out = (float*)d_out;

  // Workspace (~195 MB). POut (bf16 N*128 = 12.8MB) aliases xb (dead after
  // L1 GEMM). BIG rows are 2304 B for BOTH layers now.
  ushort_t* xb     = (ushort_t*)d_ws;                   // N x 256 bf16 (25.6 MB)
  ushort_t* POut   = (ushort_t*)d_ws;                   // N x 128 bf16 (alias)
  char*     BIG    = (char*)(xb + (size_t)N_NODES * FEAT);  // N x 2304 B (115.2 MB)
  ushort_t* H1b    = (ushort_t*)(BIG + (size_t)N_NODES * 2304); // N x 512 bf16
  ushort_t* W1t    = H1b + (size_t)N_NODES * HID;       // 2048*256
  float*    Bh1    = (float*)(W1t + L1_W);              // 2048
  ushort_t* W2t    = (ushort_t*)(Bh1 + 2048);           // 1664*512
  float*    Bh2    = (float*)(W2t + L2_W);              // 1664
  int* deg    = (int*)(Bh2 + 1664);
  int* start  = deg + N_NODES;
  int* cursor = start + N_NODES;
  int* csr    = cursor + N_NODES;
  int* gstart = csr + EDGES;
  int* gend   = gstart + NGRAPH;
  int* counter= gend + NGRAPH;

  const int* srcp = ei;
  const int* dstp = ei + EDGES;

  // ---- prep (single launch) + CSR build ----
  prep_all<<<NB_CVT + NB_TP + NB_BIAS + NB_ZERO, 256, 0, stream>>>(
      x, xb, Wq1, Wk1, Wv1, Ws1, Wq2, Wk2, Wv2, Ws2,
      bq1, bk1, bv1, bs1, bq2, bk2, bv2, bs2,
      W1t, W2t, Bh1, Bh2, deg, counter, gstart, gend);
  hist_bounds_kernel<<<(EDGES + 255) / 256, 256, 0, stream>>>(dstp, deg, batch, gstart, gend);
  alloc_kernel<<<(N_NODES + 255) / 256, 256, 0, stream>>>(deg, counter, start, cursor);
  scatter_kernel<<<(EDGES + 255) / 256, 256, 0, stream>>>(srcp, dstp, cursor, csr);

  const int ga = (N_NODES + 3) / 4;     // 12500

  // ---- layer 1: ONE GEMM (N=2048, 16 col tiles; q/kv -> BIG, s -> H1b),
  //      then ONE all-4-head attention (writes elu(msg+s) into H1b) ----
  gemm_bt<<<49 * 8 * 16, 256, 0, stream>>>(
      xb, W1t, Bh1, BIG, (char*)H1b, N_NODES, FEAT, 16, 1);
  attn1_kernel<<<ga, 256, 0, stream>>>(BIG, start, deg, csr, H1b);

  // ---- layer 2: ONE GEMM (13 col tiles, mode 2) + merged attention ----
  gemm_bt<<<49 * 8 * 13, 256, 0, stream>>>(
      H1b, W2t, Bh2, BIG, (char*)H1b, N_NODES, HID, 13, 2);
  attn2_kernel<<<ga, 256, 0, stream>>>(BIG, start, deg, csr, POut);

  // ---- fused pool + classify ----
  pool_cls<<<NGRAPH, 256, 0, stream>>>(POut, BIG, gstart, gend, Wfc, bfc, out);
}

// Round 11
// 520.694 us; speedup vs baseline: 1.1961x; 1.0847x over previous
//
#include <hip/hip_runtime.h>
#include <math.h>
#include <stdint.h>

#define N_NODES 50000
#define FEAT    256
#define EDGES   200000
#define HEADS   4
#define CH      128
#define HID     512   // HEADS*CH
#define NGRAPH  256
#define NCLS    10

typedef unsigned short ushort_t;
typedef unsigned int uint_t;
typedef __attribute__((ext_vector_type(8))) short bf16x8;
typedef __attribute__((ext_vector_type(4))) float f32x4;
typedef __attribute__((ext_vector_type(2))) float f32x2;

__device__ __forceinline__ ushort_t f2bf(float f) {  // round-to-nearest-even
  uint_t u = __float_as_uint(f);
  u += 0x7FFF + ((u >> 16) & 1);
  return (ushort_t)(u >> 16);
}
__device__ __forceinline__ float bf2f(ushort_t h) {
  return __uint_as_float(((uint_t)h) << 16);
}
// Round-11 VALU strength reduction: ELU via __expf (3 insts vs ~12 for
// expm1f; error << bf16 ulp) and softmax denom via v_rcp_f32 (1 inst vs
// ~8-inst Newton division). attn1 top-5 showed VALUBusy 92.7% / hbm 20%.
__device__ __forceinline__ float elu1(float x) {
  return x > 0.f ? x : __expf(x) - 1.f;
}
__device__ __forceinline__ float fastrcp(float x) {
  return __builtin_amdgcn_rcpf(x);
}
__device__ __forceinline__ void unpack8(uint4 w, float* f) {
  f[0] = bf2f((ushort_t)w.x); f[1] = bf2f((ushort_t)(w.x >> 16));
  f[2] = bf2f((ushort_t)w.y); f[3] = bf2f((ushort_t)(w.y >> 16));
  f[4] = bf2f((ushort_t)w.z); f[5] = bf2f((ushort_t)(w.z >> 16));
  f[6] = bf2f((ushort_t)w.w); f[7] = bf2f((ushort_t)(w.w >> 16));
}
// 8 x fp8(e4m3) -> 8 x f32 via v_cvt_pk_f32_fp8 (4 insts)
__device__ __forceinline__ void unpack8_fp8(uint2 w, float* f) {
  f32x2 a = __builtin_amdgcn_cvt_pk_f32_fp8((int)w.x, false);
  f32x2 b = __builtin_amdgcn_cvt_pk_f32_fp8((int)w.x, true);
  f32x2 c = __builtin_amdgcn_cvt_pk_f32_fp8((int)w.y, false);
  f32x2 d = __builtin_amdgcn_cvt_pk_f32_fp8((int)w.y, true);
  f[0] = a[0]; f[1] = a[1]; f[2] = b[0]; f[3] = b[1];
  f[4] = c[0]; f[5] = c[1]; f[6] = d[0]; f[7] = d[1];
}
__device__ __forceinline__ uint_t pack4_fp8(float f0, float f1, float f2, float f3) {
  int v = __builtin_amdgcn_cvt_pk_fp8_f32(f0, f1, 0, false);
  v = __builtin_amdgcn_cvt_pk_fp8_f32(f2, f3, v, true);
  return (uint_t)v;
}

// ---------------------------------------------------------------------------
// Layout (round-20, unchanged): unified 2304-B BIG rows for BOTH layers.
//  L1: q_H @H*256, kv_H @1024+H*256 (k @c*16, v @c*16+8), H=0..3;
//      skip s_H routed by the GEMM epilogue DIRECTLY into H1b @H*256.
//  L2: q_H @H*256, kv_H @1024+H*256, skip @2048.
// ---------------------------------------------------------------------------

// ---------------------------------------------------------------------------
// GEMM (round-8 verified loop: L2 111 us, MfmaUtil 34, Occ 29.4, bank-conf 0):
// 128x128 tile, BK=32, 4 waves (2x2, per-wave 64x64), 256 threads, TRIPLE-
// buffered 48 KB LDS -> 3 blocks/CU. Single-region counted-vmcnt K-tile loop.
// vmcnt(4) at boundary keeps tile t+2's loads in flight (never 0 mid-loop).
// Chunk swizzle (r>>1)&3 on stage-source AND read side. N tiles exact:
// 2048=16x128 (mode 1), 1664=13x128 (mode 2) -> no N clamps.
// Cb2 = second output base (H1b) for mode-1 skip blocks.
// ---------------------------------------------------------------------------
__global__ __launch_bounds__(256) void gemm_bt(
    const ushort_t* __restrict__ A, const ushort_t* __restrict__ Bt,
    const float* __restrict__ bias, char* __restrict__ Cb,
    char* __restrict__ Cb2, int M, int K, int nct, int mode) {
  __shared__ __align__(16) ushort_t smem[24576];   // 3 x 16 KB K-tile buffers
  const int tid = threadIdx.x;
  const int lane = tid & 63, wave = tid >> 6;
  const int wr = wave >> 1, wc = wave & 1;         // 2M x 2N waves

  // XCD-aware decode: rowTile = grp*8 + (b%8), ct = (b/8)%nct
  int b = blockIdx.x;
  int per = nct << 3;
  int grp = b / per;
  int rem = b - grp * per;
  int rloc = rem & 7;
  int ct = rem >> 3;
  const int rowBase = (grp * 8 + rloc) * 128;
  const int colBase = ct * 128;
  if (rowBase >= M) return;

  // ---- staging: 2 A slots + 2 B slots per thread per K-tile (4 GLL) ----
  const int s0 = tid, s1 = tid + 256;              // slot = row*4 + pos
  const int rl0 = s0 >> 2, cg0 = (s0 & 3) ^ ((rl0 >> 1) & 3);
  const int rl1 = s1 >> 2, cg1 = (s1 & 3) ^ ((rl1 >> 1) & 3);
  int ra0 = rowBase + rl0; ra0 = ra0 < M ? ra0 : M - 1;   // M-tail clamp
  int ra1 = rowBase + rl1; ra1 = ra1 < M ? ra1 : M - 1;
  const ushort_t* pa0 = A + (size_t)ra0 * K + cg0 * 8;
  const ushort_t* pa1 = A + (size_t)ra1 * K + cg1 * 8;
  const ushort_t* pb0 = Bt + (size_t)(colBase + rl0) * K + cg0 * 8;
  const ushort_t* pb1 = Bt + (size_t)(colBase + rl1) * K + cg1 * 8;
  const int dA0 = s0 * 8, dA1 = s1 * 8;            // A region [0,4096) elems
  const int dB0 = 4096 + s0 * 8, dB1 = 4096 + s1 * 8;  // B region [4096,8192)

#define GLL(gp, loff)  __builtin_amdgcn_global_load_lds( \
      (const __attribute__((address_space(1))) uint_t*)(gp), \
      (__attribute__((address_space(3))) uint_t*)(smem + (loff)), 16, 0, 0)

  const int nt = K >> 5;                           // K-tiles of 32 (8 or 16)
  // ---- prologue: stage tiles 0 (buf0) and 1 (buf1) ----
  GLL(pa0, dA0);            GLL(pa1, dA1);
  GLL(pb0, dB0);            GLL(pb1, dB1);
  GLL(pa0 + 32, 8192 + dA0); GLL(pa1 + 32, 8192 + dA1);
  GLL(pb0 + 32, 8192 + dB0); GLL(pb1 + 32, 8192 + dB1);
  pa0 += 64; pa1 += 64; pb0 += 64; pb1 += 64;      // now point at tile 2

  // ---- fragment read offsets (element units) ----
  const int fr = lane & 15, c0 = lane >> 4;
  const int pswz = (c0 ^ ((fr >> 1) & 3)) * 8;     // same swizzle as stage
  const int aOff = (wr * 64 + fr) * 32 + pswz;
  const int bOff = 4096 + (wc * 64 + fr) * 32 + pswz;

  f32x4 acc[4][4] = {};
  asm volatile("s_waitcnt vmcnt(4)" ::: "memory"); // tile0 landed, tile1 in flight
  __builtin_amdgcn_s_barrier();
  __builtin_amdgcn_sched_barrier(0);

  int cur = 0, nxt = 2;
  for (int t = 0; t < nt; ++t) {
    const ushort_t* bufc = smem + cur * 8192;
    const bool pf = (t + 2) < nt;
    bf16x8 af[4], bfr[4];
    // reads ordered so the first MFMA (af[0] x bfr[0]) unblocks earliest
    af[0] = *(const bf16x8*)(bufc + aOff);
#pragma unroll
    for (int j = 0; j < 4; ++j) bfr[j] = *(const bf16x8*)(bufc + bOff + j * 512);
#pragma unroll
    for (int i = 1; i < 4; ++i) af[i] = *(const bf16x8*)(bufc + aOff + i * 512);
    // prefetch tile t+2 into buf[nxt] (drained since its lgkmcnt(0) last tile)
    if (pf) {
      int lo = nxt * 8192;
      GLL(pa0, lo + dA0); GLL(pa1, lo + dA1);
      GLL(pb0, lo + dB0); GLL(pb1, lo + dB1);
      pa0 += 32; pa1 += 32; pb0 += 32; pb1 += 32;
    }
#pragma unroll
    for (int i = 0; i < 4; ++i)
#pragma unroll
      for (int j = 0; j < 4; ++j)
        acc[i][j] = __builtin_amdgcn_mfma_f32_16x16x32_bf16(af[i], bfr[j], acc[i][j], 0, 0, 0);
    asm volatile("s_waitcnt lgkmcnt(0)" ::: "memory");  // all reads of bufc drained
    if (pf)                asm volatile("s_waitcnt vmcnt(4)" ::: "memory"); // t+1 landed
    else if (t + 1 < nt)   asm volatile("s_waitcnt vmcnt(0)" ::: "memory"); // tail drain
    __builtin_amdgcn_s_barrier();
    __builtin_amdgcn_sched_barrier(0);
    cur = cur == 2 ? 0 : cur + 1;
    nxt = nxt == 2 ? 0 : nxt + 1;
  }
#undef GLL

  // ---- output block -> (base, stride, byte offset, dtype), wave-uniform ----
  char* obase; int ostride, koff, isfp8;
  if (mode == 1) {
    int H = colBase >> 9, sel = (colBase >> 7) & 3;     // q,k,v,s; H = head
    if (sel == 0)      { obase = Cb;  ostride = 2304; koff = H * 256; isfp8 = 0; }
    else if (sel == 3) { obase = Cb2; ostride = 1024; koff = H * 256; isfp8 = 0; }
    else { obase = Cb; ostride = 2304;
           koff = 1024 + H * 256 + (sel == 2 ? 8 : 0); isfp8 = 1; }
  } else {
    obase = Cb; ostride = 2304;
    if (colBase == 768) { koff = 2048; isfp8 = 0; }
    else {
      int n2 = (colBase < 768) ? colBase : colBase - 896;
      int hb = (colBase < 768) ? 0 : 2;
      int hh = hb + n2 / 384, r = n2 % 384, sel = r >> 7;  // q,k,v
      if (sel == 0) { koff = hh * 256; isfp8 = 0; }
      else          { koff = 1024 + hh * 256 + (sel == 2 ? 8 : 0); isfp8 = 1; }
    }
  }

  // Epilogue: per-wave LDS repack in two 32-row halves (4 KB/wave region).
  // C/D layout col=lane&15, row=(lane>>4)*4+reg (m89-verified).
  ushort_t* wbuf = smem + wave * 2048;             // 32 x 64 bf16
  const int rq = lane >> 4, fc = lane & 15;
  float bv[4];
#pragma unroll
  for (int j = 0; j < 4; ++j) bv[j] = bias[colBase + wc * 64 + j * 16 + fc];
#pragma unroll
  for (int h = 0; h < 2; ++h) {
#pragma unroll
    for (int ii = 0; ii < 2; ++ii) {
      int i = h * 2 + ii;
#pragma unroll
      for (int j = 0; j < 4; ++j)
#pragma unroll
        for (int r = 0; r < 4; ++r) {
          int rl = ii * 16 + rq * 4 + r;          // 0..31 ; (rl>>2)&3 == rq
          int cl = j * 16 + fc;                   // 0..63
          int cs = cl ^ (rq << 4);                // rq -> bank octet
          wbuf[rl * 64 + cs] = f2bf(acc[i][j][r] + bv[j]);
        }
    }
    // read back: lanes 0..7 cover all 32 banks (ci*4); remap chunk by rq
    int ci = lane & 7;
    int rbase = lane >> 3;                         // 0..7
#pragma unroll
    for (int rg = 0; rg < 4; ++rg) {
      int rr = rg * 8 + rbase;                     // 0..31
      int rowg = rowBase + wr * 64 + h * 32 + rr;
      int cg = ci ^ (((rr >> 2) & 3) << 1);
      uint4 val = *(const uint4*)(wbuf + rr * 64 + (ci << 3));
      if (rowg < M) {
        char* dstRow = obase + (size_t)rowg * ostride + koff;
        if (!isfp8) {
          *(uint4*)(dstRow + (wc * 64 + cg * 8) * 2) = val;
        } else {
          float f[8];
          f[0] = bf2f((ushort_t)val.x); f[1] = bf2f((ushort_t)(val.x >> 16));
          f[2] = bf2f((ushort_t)val.y); f[3] = bf2f((ushort_t)(val.y >> 16));
          f[4] = bf2f((ushort_t)val.z); f[5] = bf2f((ushort_t)(val.z >> 16));
          f[6] = bf2f((ushort_t)val.w); f[7] = bf2f((ushort_t)(val.w >> 16));
          uint2 o;
          o.x = pack4_fp8(f[0], f[1], f[2], f[3]);
          o.y = pack4_fp8(f[4], f[5], f[6], f[7]);
          *(uint2*)(dstRow + ((wc * 8 + cg) << 4)) = o;   // kv interleave
        }
      }
    }
  }
}

// ---------------------------------------------------------------------------
// prep_all: one launch, four independent regions branch on blockIdx.x:
//  [0, NB_CVT)           : x fp32 -> bf16 (vectorized)
//  [NB_CVT, +NB_TP)      : weight 32x32 tile transposes -> W1t / W2t
//  [.., +NB_BIAS)        : bias permute -> Bh1 / Bh2
//  [.., +NB_ZERO)        : zero deg/counter/gstart/gend
// ---------------------------------------------------------------------------
#define L1_W   (2048 * FEAT)
#define L2_W   (1664 * HID)
#define T1     512   // (2048/32)*(256/32)
#define T2     832   // (1664/32)*(512/32)
#define NB_CVT  12500
#define NB_TP   (T1 + T2)
#define NB_BIAS 15
#define NB_ZERO 196

__global__ __launch_bounds__(256) void prep_all(
    const float* __restrict__ x, ushort_t* __restrict__ xb,
    const float* __restrict__ Wq1, const float* __restrict__ Wk1,
    const float* __restrict__ Wv1, const float* __restrict__ Ws1,
    const float* __restrict__ Wq2, const float* __restrict__ Wk2,
    const float* __restrict__ Wv2, const float* __restrict__ Ws2,
    const float* __restrict__ bq1, const float* __restrict__ bk1,
    const float* __restrict__ bv1, const float* __restrict__ bs1,
    const float* __restrict__ bq2, const float* __restrict__ bk2,
    const float* __restrict__ bv2, const float* __restrict__ bs2,
    ushort_t* __restrict__ W1t, ushort_t* __restrict__ W2t,
    float* __restrict__ Bh1, float* __restrict__ Bh2,
    int* __restrict__ deg, int* __restrict__ counter,
    int* __restrict__ gstart, int* __restrict__ gend) {
  __shared__ float tile[32][33];
  int blk = blockIdx.x;
  if (blk < NB_CVT) {
    int i = blk * 256 + threadIdx.x;            // n4 = 3.2M exactly
    float4 f = *(const float4*)(x + (size_t)i * 4);
    uint_t lo = (uint_t)f2bf(f.x) | ((uint_t)f2bf(f.y) << 16);
    uint_t hi = (uint_t)f2bf(f.z) | ((uint_t)f2bf(f.w) << 16);
    ((uint2*)xb)[i] = make_uint2(lo, hi);
    return;
  }
  blk -= NB_CVT;
  if (blk < NB_TP) {
    int t = blk;
    const float* W; int ldw, c0, n0, k0, ldk; ushort_t* dst;
    if (t < T1) {
      int nb = t >> 3, kb = t & 7;
      n0 = nb * 32; k0 = kb * 32; ldk = FEAT; dst = W1t;
      int p = n0 >> 10, n1 = n0 & 1023, hh = n1 >> 9, sel = (n1 >> 7) & 3;
      c0 = (2 * p + hh) * CH + (n1 & (CH - 1));
      W = sel == 0 ? Wq1 : sel == 1 ? Wk1 : sel == 2 ? Wv1 : Ws1;
      ldw = HID;
    } else {
      t -= T1;
      int nb = t >> 4, kb = t & 15;
      n0 = nb * 32; k0 = kb * 32; ldk = HID; dst = W2t;
      if (n0 < 768 || n0 >= 896) {
        int n2 = (n0 < 768) ? n0 : n0 - 896;
        int hb = (n0 < 768) ? 0 : 2;
        int hh = hb + n2 / 384, r = n2 % 384, sel = r >> 7;
        c0 = hh * CH + (r & (CH - 1));
        W = sel == 0 ? Wq2 : sel == 1 ? Wk2 : Wv2;
        ldw = HID;
      } else {
        c0 = n0 - 768; W = Ws2; ldw = CH;
      }
    }
    int col = threadIdx.x & 31, rw = threadIdx.x >> 5;
#pragma unroll
    for (int ph = 0; ph < 4; ++ph) {
      int kk = rw + ph * 8;
      tile[kk][col] = W[(size_t)(k0 + kk) * ldw + c0 + col];
    }
    __syncthreads();
#pragma unroll
    for (int ph = 0; ph < 4; ++ph) {
      int dn = rw + ph * 8;
      dst[(size_t)(n0 + dn) * ldk + k0 + col] = f2bf(tile[col][dn]);
    }
    return;
  }
  blk -= NB_TP;
  if (blk < NB_BIAS) {
    int n = blk * 256 + threadIdx.x;
    if (n < 2048) {
      int p = n >> 10, n1 = n & 1023, hh = n1 >> 9, sel = (n1 >> 7) & 3;
      int c = (2 * p + hh) * CH + (n1 & (CH - 1));
      const float* bb = sel == 0 ? bq1 : sel == 1 ? bk1 : sel == 2 ? bv1 : bs1;
      Bh1[n] = bb[c];
    } else if (n < 2048 + 1664) {
      int n2 = n - 2048;
      if (n2 < 768 || n2 >= 896) {
        int nn = (n2 < 768) ? n2 : n2 - 896;
        int hb = (n2 < 768) ? 0 : 2;
        int hh = hb + nn / 384, r = nn % 384, sel = r >> 7;
        int c = hh * CH + (r & (CH - 1));
        const float* bb = sel == 0 ? bq2 : sel == 1 ? bk2 : bv2;
        Bh2[n2] = bb[c];
      } else {
        Bh2[n2] = bs2[n2 - 768];
      }
    }
    return;
  }
  blk -= NB_BIAS;
  {
    int i = blk * 256 + threadIdx.x;
    if (i < N_NODES) deg[i] = 0;
    if (i < NGRAPH) { gstart[i] = 0; gend[i] = 0; }
    if (i == 0) counter[0] = 0;
  }
}

// ---------------------------------------------------------------------------
// CSR build: hist+bounds -> alloc (wave atomic) -> scatter
// ---------------------------------------------------------------------------
__global__ void hist_bounds_kernel(const int* __restrict__ dst, int* __restrict__ deg,
                                   const int* __restrict__ batch,
                                   int* __restrict__ gstart, int* __restrict__ gend) {
  int t = blockIdx.x * blockDim.x + threadIdx.x;
  if (t < EDGES) atomicAdd(&deg[dst[t]], 1);
  if (t < N_NODES) {
    int b = batch[t];
    if (t == 0 || batch[t - 1] != b) gstart[b] = t;
    if (t == N_NODES - 1 || batch[t + 1] != b) gend[b] = t + 1;
  }
}

__global__ void alloc_kernel(const int* __restrict__ deg, int* __restrict__ counter,
                             int* __restrict__ start, int* __restrict__ cursor) {
  int i = blockIdx.x * blockDim.x + threadIdx.x;
  int lane = threadIdx.x & 63;
  int v = (i < N_NODES) ? deg[i] : 0;
  int sum = v;
#pragma unroll
  for (int off = 1; off < 64; off <<= 1) {
    int t = __shfl_up(sum, off);
    if (lane >= off) sum += t;
  }
  int excl = sum - v;
  int waveTot = __shfl(sum, 63);
  int base = 0;
  if (lane == 63) base = atomicAdd(counter, waveTot);
  base = __shfl(base, 63);
  if (i < N_NODES) {
    start[i] = base + excl;
    cursor[i] = base + excl;
  }
}

__global__ void scatter_kernel(const int* __restrict__ src, const int* __restrict__ dst,
                               int* __restrict__ cursor, int* __restrict__ csr) {
  int e = blockIdx.x * blockDim.x + threadIdx.x;
  if (e < EDGES) {
    int pos = atomicAdd(&cursor[dst[e]], 1);
    csr[pos] = src[e];
  }
}

// ---------------------------------------------------------------------------
// Attention: merged all-4-head per-wave form (round-20). Per edge ONE
// contiguous 1024-B kv burst (4 x uint4/lane). Round-11: elu1/fastrcp.
// ---------------------------------------------------------------------------
#define INV_SQRT_CH 0.08838834764831845f

// layer 1 (merged): BIG row 2304 B: q_H @H*256, kv_H @1024+H*256.
// skip s_H lives in H1b @H*256 (written by the L1 GEMM). Output overwrites
// H1b[i][H*128..]: elu(msg_H + s_H). One wave per node, all 4 heads.
__global__ __launch_bounds__(256) void attn1_kernel(
    const char* __restrict__ BIG, const int* __restrict__ start,
    const int* __restrict__ deg, const int* __restrict__ csr,
    ushort_t* __restrict__ H1b) {
  int wave = threadIdx.x >> 6, lane = threadIdx.x & 63;
  int li = lane & 15, g = lane >> 4;
  int i = blockIdx.x * 4 + wave;
  if (i >= N_NODES) return;
  int beg = start[i], end = beg + deg[i];
  const char* ip = BIG + (size_t)i * 2304;
  float q[4][8];
#pragma unroll
  for (int h = 0; h < 4; ++h)
    unpack8(*(const uint4*)(ip + h * 256 + li * 16), q[h]);
  float s[4] = {}, a[4][8] = {};
  for (int e0 = beg; e0 < end; e0 += 4) {
    int eg = e0 + g;
    bool valid = eg < end;
    int j = csr[valid ? eg : beg];
    const char* jp = BIG + (size_t)j * 2304 + 1024;
    uint4 kv[4];
#pragma unroll
    for (int h = 0; h < 4; ++h) kv[h] = *(const uint4*)(jp + h * 256 + li * 16);
#pragma unroll
    for (int h = 0; h < 4; ++h) {
      float kf[8];
      unpack8_fp8(make_uint2(kv[h].x, kv[h].y), kf);
      float pd = q[h][0]*kf[0]+q[h][1]*kf[1]+q[h][2]*kf[2]+q[h][3]*kf[3]+
                 q[h][4]*kf[4]+q[h][5]*kf[5]+q[h][6]*kf[6]+q[h][7]*kf[7];
#pragma unroll
      for (int ox = 1; ox <= 8; ox <<= 1) pd += __shfl_xor(pd, ox);
      float w = valid ? __expf(pd * INV_SQRT_CH) : 0.f;
      float vf[8];
      unpack8_fp8(make_uint2(kv[h].z, kv[h].w), vf);
      s[h] += w;
#pragma unroll
      for (int c = 0; c < 8; ++c) a[h][c] = fmaf(w, vf[c], a[h][c]);
    }
  }
#pragma unroll
  for (int ox = 16; ox <= 32; ox <<= 1) {
#pragma unroll
    for (int h = 0; h < 4; ++h) {
      s[h] += __shfl_xor(s[h], ox);
#pragma unroll
      for (int c = 0; c < 8; ++c) a[h][c] += __shfl_xor(a[h][c], ox);
    }
  }
  if (g != 0) return;
  ushort_t* orow = H1b + (size_t)i * HID + li * 8;
#pragma unroll
  for (int h = 0; h < 4; ++h) {
    float inv = fastrcp(s[h] + 1e-16f);
    float sk[8];
    unpack8(*(const uint4*)(orow + h * CH), sk);   // skip written by L1 GEMM
    uint4 ow;
    uint_t* op = (uint_t*)&ow;
#pragma unroll
    for (int c = 0; c < 4; ++c) {
      float o0 = elu1(a[h][2 * c] * inv + sk[2 * c]);
      float o1 = elu1(a[h][2 * c + 1] * inv + sk[2 * c + 1]);
      op[c] = (uint_t)f2bf(o0) | ((uint_t)f2bf(o1) << 16);
    }
    *(uint4*)(orow + h * CH) = ow;
  }
}

// layer 2 (merged): row 2304 B: q_h @h*256, kv_h @1024+h*256, skip @2048.
// ONE block per node, all 4 heads; per edge: 1024-B contiguous kv burst.
// Writes POut[i][c] = 0.25 * sum_h msg_h (bf16); pool adds skip.
__global__ __launch_bounds__(256) void attn2_kernel(
    const char* __restrict__ BIG, const int* __restrict__ start,
    const int* __restrict__ deg, const int* __restrict__ csr,
    ushort_t* __restrict__ POut) {
  int wave = threadIdx.x >> 6, lane = threadIdx.x & 63;
  int li = lane & 15, g = lane >> 4;
  int i = blockIdx.x * 4 + wave;
  if (i >= N_NODES) return;
  int beg = start[i], end = beg + deg[i];
  const char* ip = BIG + (size_t)i * 2304;
  float q[4][8];
#pragma unroll
  for (int h = 0; h < 4; ++h)
    unpack8(*(const uint4*)(ip + h * 256 + li * 16), q[h]);
  float s[4] = {}, a[4][8] = {};
  for (int e0 = beg; e0 < end; e0 += 4) {
    int eg = e0 + g;
    bool valid = eg < end;
    int j = csr[valid ? eg : beg];
    const char* jp = BIG + (size_t)j * 2304 + 1024;
    uint4 kv[4];
#pragma unroll
    for (int h = 0; h < 4; ++h) kv[h] = *(const uint4*)(jp + h * 256 + li * 16);
#pragma unroll
    for (int h = 0; h < 4; ++h) {
      float kf[8];
      unpack8_fp8(make_uint2(kv[h].x, kv[h].y), kf);
      float pd = q[h][0]*kf[0]+q[h][1]*kf[1]+q[h][2]*kf[2]+q[h][3]*kf[3]+
                 q[h][4]*kf[4]+q[h][5]*kf[5]+q[h][6]*kf[6]+q[h][7]*kf[7];
#pragma unroll
      for (int ox = 1; ox <= 8; ox <<= 1) pd += __shfl_xor(pd, ox);
      float w = valid ? __expf(pd * INV_SQRT_CH) : 0.f;
      float vf[8];
      unpack8_fp8(make_uint2(kv[h].z, kv[h].w), vf);
      s[h] += w;
#pragma unroll
      for (int c = 0; c < 8; ++c) a[h][c] = fmaf(w, vf[c], a[h][c]);
    }
  }
#pragma unroll
  for (int ox = 16; ox <= 32; ox <<= 1) {
#pragma unroll
    for (int h = 0; h < 4; ++h) {
      s[h] += __shfl_xor(s[h], ox);
#pragma unroll
      for (int c = 0; c < 8; ++c) a[h][c] += __shfl_xor(a[h][c], ox);
    }
  }
  if (g != 0) return;
  float o[8] = {};
#pragma unroll
  for (int h = 0; h < 4; ++h) {
    float inv = 0.25f * fastrcp(s[h] + 1e-16f);
#pragma unroll
    for (int c = 0; c < 8; ++c) o[c] = fmaf(a[h][c], inv, o[c]);
  }
  uint4 ow;
  uint_t* op = (uint_t*)&ow;
#pragma unroll
  for (int c = 0; c < 4; ++c)
    op[c] = (uint_t)f2bf(o[2 * c]) | ((uint_t)f2bf(o[2 * c + 1]) << 16);
  *(uint4*)(POut + (size_t)i * CH + li * 8) = ow;
}

// ---------------------------------------------------------------------------
// Fused pool + ELU + classifier + log_softmax. One block of 256 per graph.
// h2[i][c] = elu(skip(BIG@2048) + POut[i][c]).  (elu1: __expf-based)
// ---------------------------------------------------------------------------
__global__ __launch_bounds__(256) void pool_cls(
    const ushort_t* __restrict__ POut, const char* __restrict__ BIG,
    const int* __restrict__ gstart, const int* __restrict__ gend,
    const float* __restrict__ Wfc, const float* __restrict__ bfc,
    float* __restrict__ out) {
  int g = blockIdx.x;
  int t = threadIdx.x;
  int c = t & (CH - 1), rr = t >> 7;
  int s0 = gstart[g], e0 = gend[g];
  float sum = 0.f;
  for (int i = s0 + rr; i < e0; i += 2) {
    float sk = bf2f(*(const ushort_t*)(BIG + (size_t)i * 2304 + 2048 + c * 2));
    float m0 = bf2f(POut[(size_t)i * CH + c]);
    sum += elu1(sk + m0);
  }
  __shared__ float sh[256];
  __shared__ float p[CH];
  __shared__ float red[CH];
  __shared__ float logits[NCLS];
  sh[t] = sum;
  __syncthreads();
  if (t < CH) {
    float cnt = fmaxf((float)(e0 - s0), 1.f);
    p[t] = (sh[t] + sh[t + CH]) / cnt;
  }
  for (int cc = 0; cc < NCLS; ++cc) {
    __syncthreads();
    if (t < CH) red[t] = p[t] * Wfc[t * NCLS + cc];
    __syncthreads();
    for (int off = 64; off > 0; off >>= 1) {
      if (t < off) red[t] += red[t + off];
      __syncthreads();
    }
    if (t == 0) logits[cc] = red[0] + bfc[cc];
  }
  __syncthreads();
  if (t == 0) {
    float mx = -INFINITY;
    for (int cc = 0; cc < NCLS; ++cc) mx = fmaxf(mx, logits[cc]);
    float se = 0.f;
    for (int cc = 0; cc < NCLS; ++cc) se += expf(logits[cc] - mx);
    float ls = mx + logf(se);
    for (int cc = 0; cc < NCLS; ++cc) out[g * NCLS + cc] = logits[cc] - ls;
  }
}

// ---------------------------------------------------------------------------
extern "C" void kernel_launch(void* const* d_in, const int* in_sizes, int n_in,
                              void* d_out, int out_size, void* d_ws, size_t ws_size,
                              hipStream_t stream) {
  const float* x    = (const float*)d_in[0];
  const int*   ei   = (const int*)d_in[1];
  const int*   batch= (const int*)d_in[2];
  const float* Wq1 = (const float*)d_in[3];  const float* bq1 = (const float*)d_in[4];
  const float* Wk1 = (const float*)d_in[5];  const float* bk1 = (const float*)d_in[6];
  const float* Wv1 = (const float*)d_in[7];  const float* bv1 = (const float*)d_in[8];
  const float* Ws1 = (const float*)d_in[9];  const float* bs1 = (const float*)d_in[10];
  const float* Wq2 = (const float*)d_in[11]; const float* bq2 = (const float*)d_in[12];
  const float* Wk2 = (const float*)d_in[13]; const float* bk2 = (const float*)d_in[14];
  const float* Wv2 = (const float*)d_in[15]; const float* bv2 = (const float*)d_in[16];
  const float* Ws2 = (const float*)d_in[17]; const float* bs2 = (const float*)d_in[18];
  const float* Wfc = (const float*)d_in[19]; const float* bfc = (const float*)d_in[20];
  float* out = (float*)d_out;

  // Workspace (~195 MB). POut (bf16 N*128 = 12.8MB) aliases xb (dead after
  // L1 GEMM). BIG rows are 2304 B for BOTH layers.
  ushort_t* xb     = (ushort_t*)d_ws;                   // N x 256 bf16 (25.6 MB)
  ushort_t* POut   = (ushort_t*)d_ws;                   // N x 128 bf16 (alias)
  char*     BIG    = (char*)(xb + (size_t)N_NODES * FEAT);  // N x 2304 B (115.2 MB)
  ushort_t* H1b    = (ushort_t*)(BIG + (size_t)N_NODES * 2304); // N x 512 bf16
  ushort_t* W1t    = H1b + (size_t)N_NODES * HID;       // 2048*256
  float*    Bh1    = (float*)(W1t + L1_W);              // 2048
  ushort_t* W2t    = (ushort_t*)(Bh1 + 2048);           // 1664*512
  float*    Bh2    = (float*)(W2t + L2_W);              // 1664
  int* deg    = (int*)(Bh2 + 1664);
  int* start  = deg + N_NODES;
  int* cursor = start + N_NODES;
  int* csr    = cursor + N_NODES;
  int* gstart = csr + EDGES;
  int* gend   = gstart + NGRAPH;
  int* counter= gend + NGRAPH;

  const int* srcp = ei;
  const int* dstp = ei + EDGES;

  // ---- prep (single launch) + CSR build ----
  prep_all<<<NB_CVT + NB_TP + NB_BIAS + NB_ZERO, 256, 0, stream>>>(
      x, xb, Wq1, Wk1, Wv1, Ws1, Wq2, Wk2, Wv2, Ws2,
      bq1, bk1, bv1, bs1, bq2, bk2, bv2, bs2,
      W1t, W2t, Bh1, Bh2, deg, counter, gstart, gend);
  hist_bounds_kernel<<<(EDGES + 255) / 256, 256, 0, stream>>>(dstp, deg, batch, gstart, gend);
  alloc_kernel<<<(N_NODES + 255) / 256, 256, 0, stream>>>(deg, counter, start, cursor);
  scatter_kernel<<<(EDGES + 255) / 256, 256, 0, stream>>>(srcp, dstp, cursor, csr);

  const int ga = (N_NODES + 3) / 4;     // 12500

  // ---- layer 1: ONE GEMM (N=2048, 16 col tiles; q/kv -> BIG, s -> H1b),
  //      then ONE all-4-head attention (writes elu(msg+s) into H1b) ----
  gemm_bt<<<49 * 8 * 16, 256, 0, stream>>>(
      xb, W1t, Bh1, BIG, (char*)H1b, N_NODES, FEAT, 16, 1);
  attn1_kernel<<<ga, 256, 0, stream>>>(BIG, start, deg, csr, H1b);

  // ---- layer 2: ONE GEMM (13 col tiles, mode 2) + merged attention ----
  gemm_bt<<<49 * 8 * 13, 256, 0, stream>>>(
      H1b, W2t, Bh2, BIG, (char*)H1b, N_NODES, HID, 13, 2);
  attn2_kernel<<<ga, 256, 0, stream>>>(BIG, start, deg, csr, POut);

  // ---- fused pool + classify ----
  pool_cls<<<NGRAPH, 256, 0, stream>>>(POut, BIG, gstart, gend, Wfc, bfc, out);
}

// Round 12
// 472.605 us; speedup vs baseline: 1.3178x; 1.1018x over previous
//
#include <hip/hip_runtime.h>
#include <math.h>
#include <stdint.h>

#define N_NODES 50000
#define FEAT    256
#define EDGES   200000
#define HEADS   4
#define CH      128
#define HID     512   // HEADS*CH
#define NGRAPH  256
#define NCLS    10

typedef unsigned short ushort_t;
typedef unsigned int uint_t;
typedef __attribute__((ext_vector_type(8))) short bf16x8;
typedef __attribute__((ext_vector_type(4))) float f32x4;
typedef __attribute__((ext_vector_type(2))) float f32x2;

__device__ __forceinline__ ushort_t f2bf(float f) {  // round-to-nearest-even
  uint_t u = __float_as_uint(f);
  u += 0x7FFF + ((u >> 16) & 1);
  return (ushort_t)(u >> 16);
}
__device__ __forceinline__ float bf2f(ushort_t h) {
  return __uint_as_float(((uint_t)h) << 16);
}
// VALU strength reduction (round-11 verified: total -44 us): ELU via __expf,
// softmax denom via v_rcp_f32.
__device__ __forceinline__ float elu1(float x) {
  return x > 0.f ? x : __expf(x) - 1.f;
}
__device__ __forceinline__ float fastrcp(float x) {
  return __builtin_amdgcn_rcpf(x);
}
__device__ __forceinline__ void unpack8(uint4 w, float* f) {
  f[0] = bf2f((ushort_t)w.x); f[1] = bf2f((ushort_t)(w.x >> 16));
  f[2] = bf2f((ushort_t)w.y); f[3] = bf2f((ushort_t)(w.y >> 16));
  f[4] = bf2f((ushort_t)w.z); f[5] = bf2f((ushort_t)(w.z >> 16));
  f[6] = bf2f((ushort_t)w.w); f[7] = bf2f((ushort_t)(w.w >> 16));
}
// 8 x fp8(e4m3) -> 8 x f32 via v_cvt_pk_f32_fp8 (4 insts)
__device__ __forceinline__ void unpack8_fp8(uint2 w, float* f) {
  f32x2 a = __builtin_amdgcn_cvt_pk_f32_fp8((int)w.x, false);
  f32x2 b = __builtin_amdgcn_cvt_pk_f32_fp8((int)w.x, true);
  f32x2 c = __builtin_amdgcn_cvt_pk_f32_fp8((int)w.y, false);
  f32x2 d = __builtin_amdgcn_cvt_pk_f32_fp8((int)w.y, true);
  f[0] = a[0]; f[1] = a[1]; f[2] = b[0]; f[3] = b[1];
  f[4] = c[0]; f[5] = c[1]; f[6] = d[0]; f[7] = d[1];
}
__device__ __forceinline__ uint_t pack4_fp8(float f0, float f1, float f2, float f3) {
  int v = __builtin_amdgcn_cvt_pk_fp8_f32(f0, f1, 0, false);
  v = __builtin_amdgcn_cvt_pk_fp8_f32(f2, f3, v, true);
  return (uint_t)v;
}

// ---------------------------------------------------------------------------
// Layout (round-20, unchanged): unified 2304-B BIG rows for BOTH layers.
//  L1: q_H @H*256, kv_H @1024+H*256 (k @c*16, v @c*16+8), H=0..3;
//      skip s_H routed by the GEMM epilogue DIRECTLY into H1b @H*256.
//  L2: q_H @H*256, kv_H @1024+H*256, skip @2048.
// ---------------------------------------------------------------------------

// ---------------------------------------------------------------------------
// GEMM (round-8 verified loop: L2 110 us, MfmaUtil 34, Occ 29.4, bank-conf 0):
// 128x128 tile, BK=32, 4 waves (2x2, per-wave 64x64), 256 threads, TRIPLE-
// buffered 48 KB LDS -> 3 blocks/CU. Single-region counted-vmcnt K-tile loop.
// vmcnt(4) at boundary keeps tile t+2's loads in flight (never 0 mid-loop).
// Chunk swizzle (r>>1)&3 on stage-source AND read side. N tiles exact:
// 2048=16x128 (mode 1), 1664=13x128 (mode 2) -> no N clamps.
// Cb2 = second output base (H1b) for mode-1 skip blocks.
// ---------------------------------------------------------------------------
__global__ __launch_bounds__(256) void gemm_bt(
    const ushort_t* __restrict__ A, const ushort_t* __restrict__ Bt,
    const float* __restrict__ bias, char* __restrict__ Cb,
    char* __restrict__ Cb2, int M, int K, int nct, int mode) {
  __shared__ __align__(16) ushort_t smem[24576];   // 3 x 16 KB K-tile buffers
  const int tid = threadIdx.x;
  const int lane = tid & 63, wave = tid >> 6;
  const int wr = wave >> 1, wc = wave & 1;         // 2M x 2N waves

  // XCD-aware decode: rowTile = grp*8 + (b%8), ct = (b/8)%nct
  int b = blockIdx.x;
  int per = nct << 3;
  int grp = b / per;
  int rem = b - grp * per;
  int rloc = rem & 7;
  int ct = rem >> 3;
  const int rowBase = (grp * 8 + rloc) * 128;
  const int colBase = ct * 128;
  if (rowBase >= M) return;

  // ---- staging: 2 A slots + 2 B slots per thread per K-tile (4 GLL) ----
  const int s0 = tid, s1 = tid + 256;              // slot = row*4 + pos
  const int rl0 = s0 >> 2, cg0 = (s0 & 3) ^ ((rl0 >> 1) & 3);
  const int rl1 = s1 >> 2, cg1 = (s1 & 3) ^ ((rl1 >> 1) & 3);
  int ra0 = rowBase + rl0; ra0 = ra0 < M ? ra0 : M - 1;   // M-tail clamp
  int ra1 = rowBase + rl1; ra1 = ra1 < M ? ra1 : M - 1;
  const ushort_t* pa0 = A + (size_t)ra0 * K + cg0 * 8;
  const ushort_t* pa1 = A + (size_t)ra1 * K + cg1 * 8;
  const ushort_t* pb0 = Bt + (size_t)(colBase + rl0) * K + cg0 * 8;
  const ushort_t* pb1 = Bt + (size_t)(colBase + rl1) * K + cg1 * 8;
  const int dA0 = s0 * 8, dA1 = s1 * 8;            // A region [0,4096) elems
  const int dB0 = 4096 + s0 * 8, dB1 = 4096 + s1 * 8;  // B region [4096,8192)

#define GLL(gp, loff)  __builtin_amdgcn_global_load_lds( \
      (const __attribute__((address_space(1))) uint_t*)(gp), \
      (__attribute__((address_space(3))) uint_t*)(smem + (loff)), 16, 0, 0)

  const int nt = K >> 5;                           // K-tiles of 32 (8 or 16)
  // ---- prologue: stage tiles 0 (buf0) and 1 (buf1) ----
  GLL(pa0, dA0);            GLL(pa1, dA1);
  GLL(pb0, dB0);            GLL(pb1, dB1);
  GLL(pa0 + 32, 8192 + dA0); GLL(pa1 + 32, 8192 + dA1);
  GLL(pb0 + 32, 8192 + dB0); GLL(pb1 + 32, 8192 + dB1);
  pa0 += 64; pa1 += 64; pb0 += 64; pb1 += 64;      // now point at tile 2

  // ---- fragment read offsets (element units) ----
  const int fr = lane & 15, c0 = lane >> 4;
  const int pswz = (c0 ^ ((fr >> 1) & 3)) * 8;     // same swizzle as stage
  const int aOff = (wr * 64 + fr) * 32 + pswz;
  const int bOff = 4096 + (wc * 64 + fr) * 32 + pswz;

  f32x4 acc[4][4] = {};
  asm volatile("s_waitcnt vmcnt(4)" ::: "memory"); // tile0 landed, tile1 in flight
  __builtin_amdgcn_s_barrier();
  __builtin_amdgcn_sched_barrier(0);

  int cur = 0, nxt = 2;
  for (int t = 0; t < nt; ++t) {
    const ushort_t* bufc = smem + cur * 8192;
    const bool pf = (t + 2) < nt;
    bf16x8 af[4], bfr[4];
    // reads ordered so the first MFMA (af[0] x bfr[0]) unblocks earliest
    af[0] = *(const bf16x8*)(bufc + aOff);
#pragma unroll
    for (int j = 0; j < 4; ++j) bfr[j] = *(const bf16x8*)(bufc + bOff + j * 512);
#pragma unroll
    for (int i = 1; i < 4; ++i) af[i] = *(const bf16x8*)(bufc + aOff + i * 512);
    // prefetch tile t+2 into buf[nxt] (drained since its lgkmcnt(0) last tile)
    if (pf) {
      int lo = nxt * 8192;
      GLL(pa0, lo + dA0); GLL(pa1, lo + dA1);
      GLL(pb0, lo + dB0); GLL(pb1, lo + dB1);
      pa0 += 32; pa1 += 32; pb0 += 32; pb1 += 32;
    }
#pragma unroll
    for (int i = 0; i < 4; ++i)
#pragma unroll
      for (int j = 0; j < 4; ++j)
        acc[i][j] = __builtin_amdgcn_mfma_f32_16x16x32_bf16(af[i], bfr[j], acc[i][j], 0, 0, 0);
    asm volatile("s_waitcnt lgkmcnt(0)" ::: "memory");  // all reads of bufc drained
    if (pf)                asm volatile("s_waitcnt vmcnt(4)" ::: "memory"); // t+1 landed
    else if (t + 1 < nt)   asm volatile("s_waitcnt vmcnt(0)" ::: "memory"); // tail drain
    __builtin_amdgcn_s_barrier();
    __builtin_amdgcn_sched_barrier(0);
    cur = cur == 2 ? 0 : cur + 1;
    nxt = nxt == 2 ? 0 : nxt + 1;
  }
#undef GLL

  // ---- output block -> (base, stride, byte offset, dtype), wave-uniform ----
  char* obase; int ostride, koff, isfp8;
  if (mode == 1) {
    int H = colBase >> 9, sel = (colBase >> 7) & 3;     // q,k,v,s; H = head
    if (sel == 0)      { obase = Cb;  ostride = 2304; koff = H * 256; isfp8 = 0; }
    else if (sel == 3) { obase = Cb2; ostride = 1024; koff = H * 256; isfp8 = 0; }
    else { obase = Cb; ostride = 2304;
           koff = 1024 + H * 256 + (sel == 2 ? 8 : 0); isfp8 = 1; }
  } else {
    obase = Cb; ostride = 2304;
    if (colBase == 768) { koff = 2048; isfp8 = 0; }
    else {
      int n2 = (colBase < 768) ? colBase : colBase - 896;
      int hb = (colBase < 768) ? 0 : 2;
      int hh = hb + n2 / 384, r = n2 % 384, sel = r >> 7;  // q,k,v
      if (sel == 0) { koff = hh * 256; isfp8 = 0; }
      else          { koff = 1024 + hh * 256 + (sel == 2 ? 8 : 0); isfp8 = 1; }
    }
  }

  // Epilogue: per-wave LDS repack in two 32-row halves (4 KB/wave region).
  // C/D layout col=lane&15, row=(lane>>4)*4+reg (m89-verified).
  ushort_t* wbuf = smem + wave * 2048;             // 32 x 64 bf16
  const int rq = lane >> 4, fc = lane & 15;
  float bv[4];
#pragma unroll
  for (int j = 0; j < 4; ++j) bv[j] = bias[colBase + wc * 64 + j * 16 + fc];
#pragma unroll
  for (int h = 0; h < 2; ++h) {
#pragma unroll
    for (int ii = 0; ii < 2; ++ii) {
      int i = h * 2 + ii;
#pragma unroll
      for (int j = 0; j < 4; ++j)
#pragma unroll
        for (int r = 0; r < 4; ++r) {
          int rl = ii * 16 + rq * 4 + r;          // 0..31 ; (rl>>2)&3 == rq
          int cl = j * 16 + fc;                   // 0..63
          int cs = cl ^ (rq << 4);                // rq -> bank octet
          wbuf[rl * 64 + cs] = f2bf(acc[i][j][r] + bv[j]);
        }
    }
    // read back: lanes 0..7 cover all 32 banks (ci*4); remap chunk by rq
    int ci = lane & 7;
    int rbase = lane >> 3;                         // 0..7
#pragma unroll
    for (int rg = 0; rg < 4; ++rg) {
      int rr = rg * 8 + rbase;                     // 0..31
      int rowg = rowBase + wr * 64 + h * 32 + rr;
      int cg = ci ^ (((rr >> 2) & 3) << 1);
      uint4 val = *(const uint4*)(wbuf + rr * 64 + (ci << 3));
      if (rowg < M) {
        char* dstRow = obase + (size_t)rowg * ostride + koff;
        if (!isfp8) {
          *(uint4*)(dstRow + (wc * 64 + cg * 8) * 2) = val;
        } else {
          float f[8];
          f[0] = bf2f((ushort_t)val.x); f[1] = bf2f((ushort_t)(val.x >> 16));
          f[2] = bf2f((ushort_t)val.y); f[3] = bf2f((ushort_t)(val.y >> 16));
          f[4] = bf2f((ushort_t)val.z); f[5] = bf2f((ushort_t)(val.z >> 16));
          f[6] = bf2f((ushort_t)val.w); f[7] = bf2f((ushort_t)(val.w >> 16));
          uint2 o;
          o.x = pack4_fp8(f[0], f[1], f[2], f[3]);
          o.y = pack4_fp8(f[4], f[5], f[6], f[7]);
          *(uint2*)(dstRow + ((wc * 8 + cg) << 4)) = o;   // kv interleave
        }
      }
    }
  }
}

// ---------------------------------------------------------------------------
// prep_all: one launch, four independent regions branch on blockIdx.x:
//  [0, NB_CVT)           : x fp32 -> bf16 (vectorized)
//  [NB_CVT, +NB_TP)      : weight 32x32 tile transposes -> W1t / W2t
//  [.., +NB_BIAS)        : bias permute -> Bh1 / Bh2
//  [.., +NB_ZERO)        : zero deg/counter/gstart/gend
// ---------------------------------------------------------------------------
#define L1_W   (2048 * FEAT)
#define L2_W   (1664 * HID)
#define T1     512   // (2048/32)*(256/32)
#define T2     832   // (1664/32)*(512/32)
#define NB_CVT  12500
#define NB_TP   (T1 + T2)
#define NB_BIAS 15
#define NB_ZERO 196

__global__ __launch_bounds__(256) void prep_all(
    const float* __restrict__ x, ushort_t* __restrict__ xb,
    const float* __restrict__ Wq1, const float* __restrict__ Wk1,
    const float* __restrict__ Wv1, const float* __restrict__ Ws1,
    const float* __restrict__ Wq2, const float* __restrict__ Wk2,
    const float* __restrict__ Wv2, const float* __restrict__ Ws2,
    const float* __restrict__ bq1, const float* __restrict__ bk1,
    const float* __restrict__ bv1, const float* __restrict__ bs1,
    const float* __restrict__ bq2, const float* __restrict__ bk2,
    const float* __restrict__ bv2, const float* __restrict__ bs2,
    ushort_t* __restrict__ W1t, ushort_t* __restrict__ W2t,
    float* __restrict__ Bh1, float* __restrict__ Bh2,
    int* __restrict__ deg, int* __restrict__ counter,
    int* __restrict__ gstart, int* __restrict__ gend) {
  __shared__ float tile[32][33];
  int blk = blockIdx.x;
  if (blk < NB_CVT) {
    int i = blk * 256 + threadIdx.x;            // n4 = 3.2M exactly
    float4 f = *(const float4*)(x + (size_t)i * 4);
    uint_t lo = (uint_t)f2bf(f.x) | ((uint_t)f2bf(f.y) << 16);
    uint_t hi = (uint_t)f2bf(f.z) | ((uint_t)f2bf(f.w) << 16);
    ((uint2*)xb)[i] = make_uint2(lo, hi);
    return;
  }
  blk -= NB_CVT;
  if (blk < NB_TP) {
    int t = blk;
    const float* W; int ldw, c0, n0, k0, ldk; ushort_t* dst;
    if (t < T1) {
      int nb = t >> 3, kb = t & 7;
      n0 = nb * 32; k0 = kb * 32; ldk = FEAT; dst = W1t;
      int p = n0 >> 10, n1 = n0 & 1023, hh = n1 >> 9, sel = (n1 >> 7) & 3;
      c0 = (2 * p + hh) * CH + (n1 & (CH - 1));
      W = sel == 0 ? Wq1 : sel == 1 ? Wk1 : sel == 2 ? Wv1 : Ws1;
      ldw = HID;
    } else {
      t -= T1;
      int nb = t >> 4, kb = t & 15;
      n0 = nb * 32; k0 = kb * 32; ldk = HID; dst = W2t;
      if (n0 < 768 || n0 >= 896) {
        int n2 = (n0 < 768) ? n0 : n0 - 896;
        int hb = (n0 < 768) ? 0 : 2;
        int hh = hb + n2 / 384, r = n2 % 384, sel = r >> 7;
        c0 = hh * CH + (r & (CH - 1));
        W = sel == 0 ? Wq2 : sel == 1 ? Wk2 : Wv2;
        ldw = HID;
      } else {
        c0 = n0 - 768; W = Ws2; ldw = CH;
      }
    }
    int col = threadIdx.x & 31, rw = threadIdx.x >> 5;
#pragma unroll
    for (int ph = 0; ph < 4; ++ph) {
      int kk = rw + ph * 8;
      tile[kk][col] = W[(size_t)(k0 + kk) * ldw + c0 + col];
    }
    __syncthreads();
#pragma unroll
    for (int ph = 0; ph < 4; ++ph) {
      int dn = rw + ph * 8;
      dst[(size_t)(n0 + dn) * ldk + k0 + col] = f2bf(tile[col][dn]);
    }
    return;
  }
  blk -= NB_TP;
  if (blk < NB_BIAS) {
    int n = blk * 256 + threadIdx.x;
    if (n < 2048) {
      int p = n >> 10, n1 = n & 1023, hh = n1 >> 9, sel = (n1 >> 7) & 3;
      int c = (2 * p + hh) * CH + (n1 & (CH - 1));
      const float* bb = sel == 0 ? bq1 : sel == 1 ? bk1 : sel == 2 ? bv1 : bs1;
      Bh1[n] = bb[c];
    } else if (n < 2048 + 1664) {
      int n2 = n - 2048;
      if (n2 < 768 || n2 >= 896) {
        int nn = (n2 < 768) ? n2 : n2 - 896;
        int hb = (n2 < 768) ? 0 : 2;
        int hh = hb + nn / 384, r = nn % 384, sel = r >> 7;
        int c = hh * CH + (r & (CH - 1));
        const float* bb = sel == 0 ? bq2 : sel == 1 ? bk2 : bv2;
        Bh2[n2] = bb[c];
      } else {
        Bh2[n2] = bs2[n2 - 768];
      }
    }
    return;
  }
  blk -= NB_BIAS;
  {
    int i = blk * 256 + threadIdx.x;
    if (i < N_NODES) deg[i] = 0;
    if (i < NGRAPH) { gstart[i] = 0; gend[i] = 0; }
    if (i == 0) counter[0] = 0;
  }
}

// ---------------------------------------------------------------------------
// CSR build: hist+bounds -> alloc (wave atomic) -> scatter
// ---------------------------------------------------------------------------
__global__ void hist_bounds_kernel(const int* __restrict__ dst, int* __restrict__ deg,
                                   const int* __restrict__ batch,
                                   int* __restrict__ gstart, int* __restrict__ gend) {
  int t = blockIdx.x * blockDim.x + threadIdx.x;
  if (t < EDGES) atomicAdd(&deg[dst[t]], 1);
  if (t < N_NODES) {
    int b = batch[t];
    if (t == 0 || batch[t - 1] != b) gstart[b] = t;
    if (t == N_NODES - 1 || batch[t + 1] != b) gend[b] = t + 1;
  }
}

__global__ void alloc_kernel(const int* __restrict__ deg, int* __restrict__ counter,
                             int* __restrict__ start, int* __restrict__ cursor) {
  int i = blockIdx.x * blockDim.x + threadIdx.x;
  int lane = threadIdx.x & 63;
  int v = (i < N_NODES) ? deg[i] : 0;
  int sum = v;
#pragma unroll
  for (int off = 1; off < 64; off <<= 1) {
    int t = __shfl_up(sum, off);
    if (lane >= off) sum += t;
  }
  int excl = sum - v;
  int waveTot = __shfl(sum, 63);
  int base = 0;
  if (lane == 63) base = atomicAdd(counter, waveTot);
  base = __shfl(base, 63);
  if (i < N_NODES) {
    start[i] = base + excl;
    cursor[i] = base + excl;
  }
}

__global__ void scatter_kernel(const int* __restrict__ src, const int* __restrict__ dst,
                               int* __restrict__ cursor, int* __restrict__ csr) {
  int e = blockIdx.x * blockDim.x + threadIdx.x;
  if (e < EDGES) {
    int pos = atomicAdd(&cursor[dst[e]], 1);
    csr[pos] = src[e];
  }
}

// ---------------------------------------------------------------------------
// Attention (round-12 rewrite): HEAD-PER-GROUP. Each 16-lane group owns one
// head end-to-end; edges iterate serially with next-edge kv prefetch.
// Rationale (round-10/11 counters: VALUBusy 92.7%, hbm 20%): the old
// 4-edge-parallel form spent ~63% of wave-insts on the 36-value cross-group
// butterfly merge + single-group epilogue (48/64 lanes idle). Head-per-group
// eliminates the attn1 merge entirely (each group writes its own head) and
// shrinks attn2's merge to 8 values; epilogue runs on all 64 lanes.
// Per-edge cost unchanged: the wave's kv load is the same one coalesced
// 1024-B burst (group g reads bytes [g*256, g*256+256)).
// ---------------------------------------------------------------------------
#define INV_SQRT_CH 0.08838834764831845f

// layer 1: BIG row 2304 B: q_H @H*256, kv_H @1024+H*256. skip s_H in H1b
// @H*256 (written by L1 GEMM). Group g = head g; writes elu(msg_g + s_g).
__global__ __launch_bounds__(256) void attn1_kernel(
    const char* __restrict__ BIG, const int* __restrict__ start,
    const int* __restrict__ deg, const int* __restrict__ csr,
    ushort_t* __restrict__ H1b) {
  int wave = threadIdx.x >> 6, lane = threadIdx.x & 63;
  int li = lane & 15, g = lane >> 4;               // g = head
  int i = blockIdx.x * 4 + wave;
  if (i >= N_NODES) return;
  int beg = start[i], end = beg + deg[i];
  const int kvoff = 1024 + g * 256 + li * 16;      // this lane's kv slot
  float q[8];
  unpack8(*(const uint4*)(BIG + (size_t)i * 2304 + g * 256 + li * 16), q);
  float s = 0.f, a[8] = {};
  if (beg < end) {
    int j = csr[beg];
    uint4 kv = *(const uint4*)(BIG + (size_t)j * 2304 + kvoff);
    for (int e = beg; e < end; ++e) {
      // prefetch next edge's kv before this edge's compute (1-deep pipeline)
      int en = e + 1 < end ? e + 1 : e;
      int jn = csr[en];
      uint4 kvn = *(const uint4*)(BIG + (size_t)jn * 2304 + kvoff);
      float kf[8];
      unpack8_fp8(make_uint2(kv.x, kv.y), kf);
      float pd = q[0]*kf[0]+q[1]*kf[1]+q[2]*kf[2]+q[3]*kf[3]+
                 q[4]*kf[4]+q[5]*kf[5]+q[6]*kf[6]+q[7]*kf[7];
      pd += __shfl_xor(pd, 1);
      pd += __shfl_xor(pd, 2);
      pd += __shfl_xor(pd, 4);
      pd += __shfl_xor(pd, 8);
      float w = __expf(pd * INV_SQRT_CH);
      float vf[8];
      unpack8_fp8(make_uint2(kv.z, kv.w), vf);
      s += w;
#pragma unroll
      for (int c = 0; c < 8; ++c) a[c] = fmaf(w, vf[c], a[c]);
      kv = kvn;
    }
  }
  // epilogue: ALL groups active; group g writes head g's 128 channels
  float inv = fastrcp(s + 1e-16f);
  ushort_t* op8 = H1b + (size_t)i * HID + g * CH + li * 8;
  float sk[8];
  unpack8(*(const uint4*)op8, sk);                 // skip written by L1 GEMM
  uint4 ow;
  uint_t* op = (uint_t*)&ow;
#pragma unroll
  for (int c = 0; c < 4; ++c) {
    float o0 = elu1(a[2 * c] * inv + sk[2 * c]);
    float o1 = elu1(a[2 * c + 1] * inv + sk[2 * c + 1]);
    op[c] = (uint_t)f2bf(o0) | ((uint_t)f2bf(o1) << 16);
  }
  *(uint4*)op8 = ow;
}

// layer 2: row 2304 B: q_H @H*256, kv_H @1024+H*256, skip @2048.
// Group g = head g; per-group normalize (0.25/s_g), then 8-value cross-group
// sum (2 butterfly stages); group 0 writes POut[i][c]. pool adds skip.
__global__ __launch_bounds__(256) void attn2_kernel(
    const char* __restrict__ BIG, const int* __restrict__ start,
    const int* __restrict__ deg, const int* __restrict__ csr,
    ushort_t* __restrict__ POut) {
  int wave = threadIdx.x >> 6, lane = threadIdx.x & 63;
  int li = lane & 15, g = lane >> 4;               // g = head
  int i = blockIdx.x * 4 + wave;
  if (i >= N_NODES) return;
  int beg = start[i], end = beg + deg[i];
  const int kvoff = 1024 + g * 256 + li * 16;
  float q[8];
  unpack8(*(const uint4*)(BIG + (size_t)i * 2304 + g * 256 + li * 16), q);
  float s = 0.f, a[8] = {};
  if (beg < end) {
    int j = csr[beg];
    uint4 kv = *(const uint4*)(BIG + (size_t)j * 2304 + kvoff);
    for (int e = beg; e < end; ++e) {
      int en = e + 1 < end ? e + 1 : e;
      int jn = csr[en];
      uint4 kvn = *(const uint4*)(BIG + (size_t)jn * 2304 + kvoff);
      float kf[8];
      unpack8_fp8(make_uint2(kv.x, kv.y), kf);
      float pd = q[0]*kf[0]+q[1]*kf[1]+q[2]*kf[2]+q[3]*kf[3]+
                 q[4]*kf[4]+q[5]*kf[5]+q[6]*kf[6]+q[7]*kf[7];
      pd += __shfl_xor(pd, 1);
      pd += __shfl_xor(pd, 2);
      pd += __shfl_xor(pd, 4);
      pd += __shfl_xor(pd, 8);
      float w = __expf(pd * INV_SQRT_CH);
      float vf[8];
      unpack8_fp8(make_uint2(kv.z, kv.w), vf);
      s += w;
#pragma unroll
      for (int c = 0; c < 8; ++c) a[c] = fmaf(w, vf[c], a[c]);
      kv = kvn;
    }
  }
  // per-group normalize, then sum heads: 8 values x 2 butterfly stages
  float inv = 0.25f * fastrcp(s + 1e-16f);
  float o[8];
#pragma unroll
  for (int c = 0; c < 8; ++c) o[c] = a[c] * inv;
#pragma unroll
  for (int ox = 16; ox <= 32; ox <<= 1)
#pragma unroll
    for (int c = 0; c < 8; ++c) o[c] += __shfl_xor(o[c], ox);
  if (g != 0) return;
  uint4 ow;
  uint_t* op = (uint_t*)&ow;
#pragma unroll
  for (int c = 0; c < 4; ++c)
    op[c] = (uint_t)f2bf(o[2 * c]) | ((uint_t)f2bf(o[2 * c + 1]) << 16);
  *(uint4*)(POut + (size_t)i * CH + li * 8) = ow;
}

// ---------------------------------------------------------------------------
// Fused pool + ELU + classifier + log_softmax. One block of 256 per graph.
// h2[i][c] = elu(skip(BIG@2048) + POut[i][c]).  (elu1: __expf-based)
// ---------------------------------------------------------------------------
__global__ __launch_bounds__(256) void pool_cls(
    const ushort_t* __restrict__ POut, const char* __restrict__ BIG,
    const int* __restrict__ gstart, const int* __restrict__ gend,
    const float* __restrict__ Wfc, const float* __restrict__ bfc,
    float* __restrict__ out) {
  int g = blockIdx.x;
  int t = threadIdx.x;
  int c = t & (CH - 1), rr = t >> 7;
  int s0 = gstart[g], e0 = gend[g];
  float sum = 0.f;
  for (int i = s0 + rr; i < e0; i += 2) {
    float sk = bf2f(*(const ushort_t*)(BIG + (size_t)i * 2304 + 2048 + c * 2));
    float m0 = bf2f(POut[(size_t)i * CH + c]);
    sum += elu1(sk + m0);
  }
  __shared__ float sh[256];
  __shared__ float p[CH];
  __shared__ float red[CH];
  __shared__ float logits[NCLS];
  sh[t] = sum;
  __syncthreads();
  if (t < CH) {
    float cnt = fmaxf((float)(e0 - s0), 1.f);
    p[t] = (sh[t] + sh[t + CH]) / cnt;
  }
  for (int cc = 0; cc < NCLS; ++cc) {
    __syncthreads();
    if (t < CH) red[t] = p[t] * Wfc[t * NCLS + cc];
    __syncthreads();
    for (int off = 64; off > 0; off >>= 1) {
      if (t < off) red[t] += red[t + off];
      __syncthreads();
    }
    if (t == 0) logits[cc] = red[0] + bfc[cc];
  }
  __syncthreads();
  if (t == 0) {
    float mx = -INFINITY;
    for (int cc = 0; cc < NCLS; ++cc) mx = fmaxf(mx, logits[cc]);
    float se = 0.f;
    for (int cc = 0; cc < NCLS; ++cc) se += expf(logits[cc] - mx);
    float ls = mx + logf(se);
    for (int cc = 0; cc < NCLS; ++cc) out[g * NCLS + cc] = logits[cc] - ls;
  }
}

// ---------------------------------------------------------------------------
extern "C" void kernel_launch(void* const* d_in, const int* in_sizes, int n_in,
                              void* d_out, int out_size, void* d_ws, size_t ws_size,
                              hipStream_t stream) {
  const float* x    = (const float*)d_in[0];
  const int*   ei   = (const int*)d_in[1];
  const int*   batch= (const int*)d_in[2];
  const float* Wq1 = (const float*)d_in[3];  const float* bq1 = (const float*)d_in[4];
  const float* Wk1 = (const float*)d_in[5];  const float* bk1 = (const float*)d_in[6];
  const float* Wv1 = (const float*)d_in[7];  const float* bv1 = (const float*)d_in[8];
  const float* Ws1 = (const float*)d_in[9];  const float* bs1 = (const float*)d_in[10];
  const float* Wq2 = (const float*)d_in[11]; const float* bq2 = (const float*)d_in[12];
  const float* Wk2 = (const float*)d_in[13]; const float* bk2 = (const float*)d_in[14];
  const float* Wv2 = (const float*)d_in[15]; const float* bv2 = (const float*)d_in[16];
  const float* Ws2 = (const float*)d_in[17]; const float* bs2 = (const float*)d_in[18];
  const float* Wfc = (const float*)d_in[19]; const float* bfc = (const float*)d_in[20];
  float* out = (float*)d_out;

  // Workspace (~195 MB). POut (bf16 N*128 = 12.8MB) aliases xb (dead after
  // L1 GEMM). BIG rows are 2304 B for BOTH layers.
  ushort_t* xb     = (ushort_t*)d_ws;                   // N x 256 bf16 (25.6 MB)
  ushort_t* POut   = (ushort_t*)d_ws;                   // N x 128 bf16 (alias)
  char*     BIG    = (char*)(xb + (size_t)N_NODES * FEAT);  // N x 2304 B (115.2 MB)
  ushort_t* H1b    = (ushort_t*)(BIG + (size_t)N_NODES * 2304); // N x 512 bf16
  ushort_t* W1t    = H1b + (size_t)N_NODES * HID;       // 2048*256
  float*    Bh1    = (float*)(W1t + L1_W);              // 2048
  ushort_t* W2t    = (ushort_t*)(Bh1 + 2048);           // 1664*512
  float*    Bh2    = (float*)(W2t + L2_W);              // 1664
  int* deg    = (int*)(Bh2 + 1664);
  int* start  = deg + N_NODES;
  int* cursor = start + N_NODES;
  int* csr    = cursor + N_NODES;
  int* gstart = csr + EDGES;
  int* gend   = gstart + NGRAPH;
  int* counter= gend + NGRAPH;

  const int* srcp = ei;
  const int* dstp = ei + EDGES;

  // ---- prep (single launch) + CSR build ----
  prep_all<<<NB_CVT + NB_TP + NB_BIAS + NB_ZERO, 256, 0, stream>>>(
      x, xb, Wq1, Wk1, Wv1, Ws1, Wq2, Wk2, Wv2, Ws2,
      bq1, bk1, bv1, bs1, bq2, bk2, bv2, bs2,
      W1t, W2t, Bh1, Bh2, deg, counter, gstart, gend);
  hist_bounds_kernel<<<(EDGES + 255) / 256, 256, 0, stream>>>(dstp, deg, batch, gstart, gend);
  alloc_kernel<<<(N_NODES + 255) / 256, 256, 0, stream>>>(deg, counter, start, cursor);
  scatter_kernel<<<(EDGES + 255) / 256, 256, 0, stream>>>(srcp, dstp, cursor, csr);

  const int ga = (N_NODES + 3) / 4;     // 12500

  // ---- layer 1: ONE GEMM (N=2048, 16 col tiles; q/kv -> BIG, s -> H1b),
  //      then ONE all-4-head attention (writes elu(msg+s) into H1b) ----
  gemm_bt<<<49 * 8 * 16, 256, 0, stream>>>(
      xb, W1t, Bh1, BIG, (char*)H1b, N_NODES, FEAT, 16, 1);
  attn1_kernel<<<ga, 256, 0, stream>>>(BIG, start, deg, csr, H1b);

  // ---- layer 2: ONE GEMM (13 col tiles, mode 2) + merged attention ----
  gemm_bt<<<49 * 8 * 13, 256, 0, stream>>>(
      H1b, W2t, Bh2, BIG, (char*)H1b, N_NODES, HID, 13, 2);
  attn2_kernel<<<ga, 256, 0, stream>>>(BIG, start, deg, csr, POut);

  // ---- fused pool + classify ----
  pool_cls<<<NGRAPH, 256, 0, stream>>>(POut, BIG, gstart, gend, Wfc, bfc, out);
}

// Round 13
// 450.798 us; speedup vs baseline: 1.3816x; 1.0484x over previous
//
#include <hip/hip_runtime.h>
#include <math.h>
#include <stdint.h>

#define N_NODES 50000
#define FEAT    256
#define EDGES   200000
#define HEADS   4
#define CH      128
#define HID     512   // HEADS*CH
#define NGRAPH  256
#define NCLS    10

typedef unsigned short ushort_t;
typedef unsigned int uint_t;
typedef __attribute__((ext_vector_type(8))) short bf16x8;
typedef __attribute__((ext_vector_type(4))) float f32x4;
typedef __attribute__((ext_vector_type(2))) float f32x2;

__device__ __forceinline__ ushort_t f2bf(float f) {  // round-to-nearest-even
  uint_t u = __float_as_uint(f);
  u += 0x7FFF + ((u >> 16) & 1);
  return (ushort_t)(u >> 16);
}
__device__ __forceinline__ float bf2f(ushort_t h) {
  return __uint_as_float(((uint_t)h) << 16);
}
// VALU strength reduction (round-11 verified: total -44 us): ELU via __expf,
// softmax denom via v_rcp_f32.
__device__ __forceinline__ float elu1(float x) {
  return x > 0.f ? x : __expf(x) - 1.f;
}
__device__ __forceinline__ float fastrcp(float x) {
  return __builtin_amdgcn_rcpf(x);
}
__device__ __forceinline__ void unpack8(uint4 w, float* f) {
  f[0] = bf2f((ushort_t)w.x); f[1] = bf2f((ushort_t)(w.x >> 16));
  f[2] = bf2f((ushort_t)w.y); f[3] = bf2f((ushort_t)(w.y >> 16));
  f[4] = bf2f((ushort_t)w.z); f[5] = bf2f((ushort_t)(w.z >> 16));
  f[6] = bf2f((ushort_t)w.w); f[7] = bf2f((ushort_t)(w.w >> 16));
}
// 8 x fp8(e4m3) -> 8 x f32 via v_cvt_pk_f32_fp8 (4 insts)
__device__ __forceinline__ void unpack8_fp8(uint2 w, float* f) {
  f32x2 a = __builtin_amdgcn_cvt_pk_f32_fp8((int)w.x, false);
  f32x2 b = __builtin_amdgcn_cvt_pk_f32_fp8((int)w.x, true);
  f32x2 c = __builtin_amdgcn_cvt_pk_f32_fp8((int)w.y, false);
  f32x2 d = __builtin_amdgcn_cvt_pk_f32_fp8((int)w.y, true);
  f[0] = a[0]; f[1] = a[1]; f[2] = b[0]; f[3] = b[1];
  f[4] = c[0]; f[5] = c[1]; f[6] = d[0]; f[7] = d[1];
}
__device__ __forceinline__ uint_t pack4_fp8(float f0, float f1, float f2, float f3) {
  int v = __builtin_amdgcn_cvt_pk_fp8_f32(f0, f1, 0, false);
  v = __builtin_amdgcn_cvt_pk_fp8_f32(f2, f3, v, true);
  return (uint_t)v;
}

// ---------------------------------------------------------------------------
// Layout (unchanged): unified 2304-B BIG rows for BOTH layers.
//  L1: q_H @H*256, kv_H @1024+H*256 (k @c*16, v @c*16+8), H=0..3;
//      skip s_H routed by the GEMM epilogue DIRECTLY into H1b @H*256.
//  L2: q_H @H*256, kv_H @1024+H*256, skip @2048.
// ---------------------------------------------------------------------------

// ---------------------------------------------------------------------------
// GEMM (round-8 verified loop: L2 111 us, MfmaUtil 34, Occ 29.4, bank-conf 0):
// 128x128 tile, BK=32, 4 waves (2x2, per-wave 64x64), 256 threads, TRIPLE-
// buffered 48 KB LDS -> 3 blocks/CU. Single-region counted-vmcnt K-tile loop.
// vmcnt(4) at boundary keeps tile t+2's loads in flight (never 0 mid-loop).
// Chunk swizzle (r>>1)&3 on stage-source AND read side. N tiles exact:
// 2048=16x128 (mode 1), 1664=13x128 (mode 2) -> no N clamps.
// Cb2 = second output base (H1b) for mode-1 skip blocks.
// ---------------------------------------------------------------------------
__global__ __launch_bounds__(256) void gemm_bt(
    const ushort_t* __restrict__ A, const ushort_t* __restrict__ Bt,
    const float* __restrict__ bias, char* __restrict__ Cb,
    char* __restrict__ Cb2, int M, int K, int nct, int mode) {
  __shared__ __align__(16) ushort_t smem[24576];   // 3 x 16 KB K-tile buffers
  const int tid = threadIdx.x;
  const int lane = tid & 63, wave = tid >> 6;
  const int wr = wave >> 1, wc = wave & 1;         // 2M x 2N waves

  // XCD-aware decode: rowTile = grp*8 + (b%8), ct = (b/8)%nct
  int b = blockIdx.x;
  int per = nct << 3;
  int grp = b / per;
  int rem = b - grp * per;
  int rloc = rem & 7;
  int ct = rem >> 3;
  const int rowBase = (grp * 8 + rloc) * 128;
  const int colBase = ct * 128;
  if (rowBase >= M) return;

  // ---- staging: 2 A slots + 2 B slots per thread per K-tile (4 GLL) ----
  const int s0 = tid, s1 = tid + 256;              // slot = row*4 + pos
  const int rl0 = s0 >> 2, cg0 = (s0 & 3) ^ ((rl0 >> 1) & 3);
  const int rl1 = s1 >> 2, cg1 = (s1 & 3) ^ ((rl1 >> 1) & 3);
  int ra0 = rowBase + rl0; ra0 = ra0 < M ? ra0 : M - 1;   // M-tail clamp
  int ra1 = rowBase + rl1; ra1 = ra1 < M ? ra1 : M - 1;
  const ushort_t* pa0 = A + (size_t)ra0 * K + cg0 * 8;
  const ushort_t* pa1 = A + (size_t)ra1 * K + cg1 * 8;
  const ushort_t* pb0 = Bt + (size_t)(colBase + rl0) * K + cg0 * 8;
  const ushort_t* pb1 = Bt + (size_t)(colBase + rl1) * K + cg1 * 8;
  const int dA0 = s0 * 8, dA1 = s1 * 8;            // A region [0,4096) elems
  const int dB0 = 4096 + s0 * 8, dB1 = 4096 + s1 * 8;  // B region [4096,8192)

#define GLL(gp, loff)  __builtin_amdgcn_global_load_lds( \
      (const __attribute__((address_space(1))) uint_t*)(gp), \
      (__attribute__((address_space(3))) uint_t*)(smem + (loff)), 16, 0, 0)

  const int nt = K >> 5;                           // K-tiles of 32 (8 or 16)
  // ---- prologue: stage tiles 0 (buf0) and 1 (buf1) ----
  GLL(pa0, dA0);            GLL(pa1, dA1);
  GLL(pb0, dB0);            GLL(pb1, dB1);
  GLL(pa0 + 32, 8192 + dA0); GLL(pa1 + 32, 8192 + dA1);
  GLL(pb0 + 32, 8192 + dB0); GLL(pb1 + 32, 8192 + dB1);
  pa0 += 64; pa1 += 64; pb0 += 64; pb1 += 64;      // now point at tile 2

  // ---- fragment read offsets (element units) ----
  const int fr = lane & 15, c0 = lane >> 4;
  const int pswz = (c0 ^ ((fr >> 1) & 3)) * 8;     // same swizzle as stage
  const int aOff = (wr * 64 + fr) * 32 + pswz;
  const int bOff = 4096 + (wc * 64 + fr) * 32 + pswz;

  f32x4 acc[4][4] = {};
  asm volatile("s_waitcnt vmcnt(4)" ::: "memory"); // tile0 landed, tile1 in flight
  __builtin_amdgcn_s_barrier();
  __builtin_amdgcn_sched_barrier(0);

  int cur = 0, nxt = 2;
  for (int t = 0; t < nt; ++t) {
    const ushort_t* bufc = smem + cur * 8192;
    const bool pf = (t + 2) < nt;
    bf16x8 af[4], bfr[4];
    // reads ordered so the first MFMA (af[0] x bfr[0]) unblocks earliest
    af[0] = *(const bf16x8*)(bufc + aOff);
#pragma unroll
    for (int j = 0; j < 4; ++j) bfr[j] = *(const bf16x8*)(bufc + bOff + j * 512);
#pragma unroll
    for (int i = 1; i < 4; ++i) af[i] = *(const bf16x8*)(bufc + aOff + i * 512);
    // prefetch tile t+2 into buf[nxt] (drained since its lgkmcnt(0) last tile)
    if (pf) {
      int lo = nxt * 8192;
      GLL(pa0, lo + dA0); GLL(pa1, lo + dA1);
      GLL(pb0, lo + dB0); GLL(pb1, lo + dB1);
      pa0 += 32; pa1 += 32; pb0 += 32; pb1 += 32;
    }
#pragma unroll
    for (int i = 0; i < 4; ++i)
#pragma unroll
      for (int j = 0; j < 4; ++j)
        acc[i][j] = __builtin_amdgcn_mfma_f32_16x16x32_bf16(af[i], bfr[j], acc[i][j], 0, 0, 0);
    asm volatile("s_waitcnt lgkmcnt(0)" ::: "memory");  // all reads of bufc drained
    if (pf)                asm volatile("s_waitcnt vmcnt(4)" ::: "memory"); // t+1 landed
    else if (t + 1 < nt)   asm volatile("s_waitcnt vmcnt(0)" ::: "memory"); // tail drain
    __builtin_amdgcn_s_barrier();
    __builtin_amdgcn_sched_barrier(0);
    cur = cur == 2 ? 0 : cur + 1;
    nxt = nxt == 2 ? 0 : nxt + 1;
  }
#undef GLL

  // ---- output block -> (base, stride, byte offset, dtype), wave-uniform ----
  char* obase; int ostride, koff, isfp8;
  if (mode == 1) {
    int H = colBase >> 9, sel = (colBase >> 7) & 3;     // q,k,v,s; H = head
    if (sel == 0)      { obase = Cb;  ostride = 2304; koff = H * 256; isfp8 = 0; }
    else if (sel == 3) { obase = Cb2; ostride = 1024; koff = H * 256; isfp8 = 0; }
    else { obase = Cb; ostride = 2304;
           koff = 1024 + H * 256 + (sel == 2 ? 8 : 0); isfp8 = 1; }
  } else {
    obase = Cb; ostride = 2304;
    if (colBase == 768) { koff = 2048; isfp8 = 0; }
    else {
      int n2 = (colBase < 768) ? colBase : colBase - 896;
      int hb = (colBase < 768) ? 0 : 2;
      int hh = hb + n2 / 384, r = n2 % 384, sel = r >> 7;  // q,k,v
      if (sel == 0) { koff = hh * 256; isfp8 = 0; }
      else          { koff = 1024 + hh * 256 + (sel == 2 ? 8 : 0); isfp8 = 1; }
    }
  }

  // Epilogue: per-wave LDS repack in two 32-row halves (4 KB/wave region).
  // C/D layout col=lane&15, row=(lane>>4)*4+reg (m89-verified).
  ushort_t* wbuf = smem + wave * 2048;             // 32 x 64 bf16
  const int rq = lane >> 4, fc = lane & 15;
  float bv[4];
#pragma unroll
  for (int j = 0; j < 4; ++j) bv[j] = bias[colBase + wc * 64 + j * 16 + fc];
#pragma unroll
  for (int h = 0; h < 2; ++h) {
#pragma unroll
    for (int ii = 0; ii < 2; ++ii) {
      int i = h * 2 + ii;
#pragma unroll
      for (int j = 0; j < 4; ++j)
#pragma unroll
        for (int r = 0; r < 4; ++r) {
          int rl = ii * 16 + rq * 4 + r;          // 0..31 ; (rl>>2)&3 == rq
          int cl = j * 16 + fc;                   // 0..63
          int cs = cl ^ (rq << 4);                // rq -> bank octet
          wbuf[rl * 64 + cs] = f2bf(acc[i][j][r] + bv[j]);
        }
    }
    // read back: lanes 0..7 cover all 32 banks (ci*4); remap chunk by rq
    int ci = lane & 7;
    int rbase = lane >> 3;                         // 0..7
#pragma unroll
    for (int rg = 0; rg < 4; ++rg) {
      int rr = rg * 8 + rbase;                     // 0..31
      int rowg = rowBase + wr * 64 + h * 32 + rr;
      int cg = ci ^ (((rr >> 2) & 3) << 1);
      uint4 val = *(const uint4*)(wbuf + rr * 64 + (ci << 3));
      if (rowg < M) {
        char* dstRow = obase + (size_t)rowg * ostride + koff;
        if (!isfp8) {
          *(uint4*)(dstRow + (wc * 64 + cg * 8) * 2) = val;
        } else {
          float f[8];
          f[0] = bf2f((ushort_t)val.x); f[1] = bf2f((ushort_t)(val.x >> 16));
          f[2] = bf2f((ushort_t)val.y); f[3] = bf2f((ushort_t)(val.y >> 16));
          f[4] = bf2f((ushort_t)val.z); f[5] = bf2f((ushort_t)(val.z >> 16));
          f[6] = bf2f((ushort_t)val.w); f[7] = bf2f((ushort_t)(val.w >> 16));
          uint2 o;
          o.x = pack4_fp8(f[0], f[1], f[2], f[3]);
          o.y = pack4_fp8(f[4], f[5], f[6], f[7]);
          *(uint2*)(dstRow + ((wc * 8 + cg) << 4)) = o;   // kv interleave
        }
      }
    }
  }
}

// ---------------------------------------------------------------------------
// prep_all: one launch, four independent regions branch on blockIdx.x:
//  [0, NB_CVT)           : x fp32 -> bf16 (vectorized)
//  [NB_CVT, +NB_TP)      : weight 32x32 tile transposes -> W1t / W2t
//  [.., +NB_BIAS)        : bias permute -> Bh1 / Bh2
//  [.., +NB_ZERO)        : zero deg/counter/gstart/gend/pooled
// ---------------------------------------------------------------------------
#define L1_W   (2048 * FEAT)
#define L2_W   (1664 * HID)
#define T1     512   // (2048/32)*(256/32)
#define T2     832   // (1664/32)*(512/32)
#define NB_CVT  12500
#define NB_TP   (T1 + T2)
#define NB_BIAS 15
#define NB_ZERO 196

__global__ __launch_bounds__(256) void prep_all(
    const float* __restrict__ x, ushort_t* __restrict__ xb,
    const float* __restrict__ Wq1, const float* __restrict__ Wk1,
    const float* __restrict__ Wv1, const float* __restrict__ Ws1,
    const float* __restrict__ Wq2, const float* __restrict__ Wk2,
    const float* __restrict__ Wv2, const float* __restrict__ Ws2,
    const float* __restrict__ bq1, const float* __restrict__ bk1,
    const float* __restrict__ bv1, const float* __restrict__ bs1,
    const float* __restrict__ bq2, const float* __restrict__ bk2,
    const float* __restrict__ bv2, const float* __restrict__ bs2,
    ushort_t* __restrict__ W1t, ushort_t* __restrict__ W2t,
    float* __restrict__ Bh1, float* __restrict__ Bh2,
    int* __restrict__ deg, int* __restrict__ counter,
    int* __restrict__ gstart, int* __restrict__ gend,
    float* __restrict__ pooled) {
  __shared__ float tile[32][33];
  int blk = blockIdx.x;
  if (blk < NB_CVT) {
    int i = blk * 256 + threadIdx.x;            // n4 = 3.2M exactly
    float4 f = *(const float4*)(x + (size_t)i * 4);
    uint_t lo = (uint_t)f2bf(f.x) | ((uint_t)f2bf(f.y) << 16);
    uint_t hi = (uint_t)f2bf(f.z) | ((uint_t)f2bf(f.w) << 16);
    ((uint2*)xb)[i] = make_uint2(lo, hi);
    return;
  }
  blk -= NB_CVT;
  if (blk < NB_TP) {
    int t = blk;
    const float* W; int ldw, c0, n0, k0, ldk; ushort_t* dst;
    if (t < T1) {
      int nb = t >> 3, kb = t & 7;
      n0 = nb * 32; k0 = kb * 32; ldk = FEAT; dst = W1t;
      int p = n0 >> 10, n1 = n0 & 1023, hh = n1 >> 9, sel = (n1 >> 7) & 3;
      c0 = (2 * p + hh) * CH + (n1 & (CH - 1));
      W = sel == 0 ? Wq1 : sel == 1 ? Wk1 : sel == 2 ? Wv1 : Ws1;
      ldw = HID;
    } else {
      t -= T1;
      int nb = t >> 4, kb = t & 15;
      n0 = nb * 32; k0 = kb * 32; ldk = HID; dst = W2t;
      if (n0 < 768 || n0 >= 896) {
        int n2 = (n0 < 768) ? n0 : n0 - 896;
        int hb = (n0 < 768) ? 0 : 2;
        int hh = hb + n2 / 384, r = n2 % 384, sel = r >> 7;
        c0 = hh * CH + (r & (CH - 1));
        W = sel == 0 ? Wq2 : sel == 1 ? Wk2 : Wv2;
        ldw = HID;
      } else {
        c0 = n0 - 768; W = Ws2; ldw = CH;
      }
    }
    int col = threadIdx.x & 31, rw = threadIdx.x >> 5;
#pragma unroll
    for (int ph = 0; ph < 4; ++ph) {
      int kk = rw + ph * 8;
      tile[kk][col] = W[(size_t)(k0 + kk) * ldw + c0 + col];
    }
    __syncthreads();
#pragma unroll
    for (int ph = 0; ph < 4; ++ph) {
      int dn = rw + ph * 8;
      dst[(size_t)(n0 + dn) * ldk + k0 + col] = f2bf(tile[col][dn]);
    }
    return;
  }
  blk -= NB_TP;
  if (blk < NB_BIAS) {
    int n = blk * 256 + threadIdx.x;
    if (n < 2048) {
      int p = n >> 10, n1 = n & 1023, hh = n1 >> 9, sel = (n1 >> 7) & 3;
      int c = (2 * p + hh) * CH + (n1 & (CH - 1));
      const float* bb = sel == 0 ? bq1 : sel == 1 ? bk1 : sel == 2 ? bv1 : bs1;
      Bh1[n] = bb[c];
    } else if (n < 2048 + 1664) {
      int n2 = n - 2048;
      if (n2 < 768 || n2 >= 896) {
        int nn = (n2 < 768) ? n2 : n2 - 896;
        int hb = (n2 < 768) ? 0 : 2;
        int hh = hb + nn / 384, r = nn % 384, sel = r >> 7;
        int c = hh * CH + (r & (CH - 1));
        const float* bb = sel == 0 ? bq2 : sel == 1 ? bk2 : bv2;
        Bh2[n2] = bb[c];
      } else {
        Bh2[n2] = bs2[n2 - 768];
      }
    }
    return;
  }
  blk -= NB_BIAS;
  {
    int i = blk * 256 + threadIdx.x;
    if (i < N_NODES) deg[i] = 0;
    if (i < NGRAPH) { gstart[i] = 0; gend[i] = 0; }
    if (i < NGRAPH * CH) pooled[i] = 0.f;
    if (i == 0) counter[0] = 0;
  }
}

// ---------------------------------------------------------------------------
// CSR build: hist+bounds -> alloc (wave atomic) -> scatter
// ---------------------------------------------------------------------------
__global__ void hist_bounds_kernel(const int* __restrict__ dst, int* __restrict__ deg,
                                   const int* __restrict__ batch,
                                   int* __restrict__ gstart, int* __restrict__ gend) {
  int t = blockIdx.x * blockDim.x + threadIdx.x;
  if (t < EDGES) atomicAdd(&deg[dst[t]], 1);
  if (t < N_NODES) {
    int b = batch[t];
    if (t == 0 || batch[t - 1] != b) gstart[b] = t;
    if (t == N_NODES - 1 || batch[t + 1] != b) gend[b] = t + 1;
  }
}

__global__ void alloc_kernel(const int* __restrict__ deg, int* __restrict__ counter,
                             int* __restrict__ start, int* __restrict__ cursor) {
  int i = blockIdx.x * blockDim.x + threadIdx.x;
  int lane = threadIdx.x & 63;
  int v = (i < N_NODES) ? deg[i] : 0;
  int sum = v;
#pragma unroll
  for (int off = 1; off < 64; off <<= 1) {
    int t = __shfl_up(sum, off);
    if (lane >= off) sum += t;
  }
  int excl = sum - v;
  int waveTot = __shfl(sum, 63);
  int base = 0;
  if (lane == 63) base = atomicAdd(counter, waveTot);
  base = __shfl(base, 63);
  if (i < N_NODES) {
    start[i] = base + excl;
    cursor[i] = base + excl;
  }
}

__global__ void scatter_kernel(const int* __restrict__ src, const int* __restrict__ dst,
                               int* __restrict__ cursor, int* __restrict__ csr) {
  int e = blockIdx.x * blockDim.x + threadIdx.x;
  if (e < EDGES) {
    int pos = atomicAdd(&cursor[dst[e]], 1);
    csr[pos] = src[e];
  }
}

// ---------------------------------------------------------------------------
// Attention (round-13): HEAD-PER-GROUP + 2-wide edge unroll. Each 16-lane
// group owns one head; edges processed 2 at a time with dual accumulator
// chains and 2-deep kv prefetch (~4 gathers in flight/wave) to hide the
// L3/HBM random-gather latency the 1-deep form left exposed.
// ---------------------------------------------------------------------------
#define INV_SQRT_CH 0.08838834764831845f

// layer 1: BIG row 2304 B: q_H @H*256, kv_H @1024+H*256. skip s_H in H1b
// @H*256 (written by L1 GEMM; loaded EARLY to hide under the edge loop).
// Group g = head g; writes elu(msg_g + s_g) over H1b in place.
__global__ __launch_bounds__(256) void attn1_kernel(
    const char* __restrict__ BIG, const int* __restrict__ start,
    const int* __restrict__ deg, const int* __restrict__ csr,
    ushort_t* __restrict__ H1b) {
  int wave = threadIdx.x >> 6, lane = threadIdx.x & 63;
  int li = lane & 15, g = lane >> 4;               // g = head
  int i = blockIdx.x * 4 + wave;
  if (i >= N_NODES) return;
  int beg = start[i], end = beg + deg[i];
  const int kvoff = 1024 + g * 256 + li * 16;      // this lane's kv slot
  float q[8];
  unpack8(*(const uint4*)(BIG + (size_t)i * 2304 + g * 256 + li * 16), q);
  ushort_t* op8 = H1b + (size_t)i * HID + g * CH + li * 8;
  uint4 skw = *(const uint4*)op8;                  // early skip load
  float sA = 0.f, sB = 0.f, aA[8] = {}, aB[8] = {};
  uint4 kv0 = make_uint4(0, 0, 0, 0), kv1 = make_uint4(0, 0, 0, 0);
  int e = beg;
  if (e < end)     kv0 = *(const uint4*)(BIG + (size_t)csr[e] * 2304 + kvoff);
  if (e + 1 < end) kv1 = *(const uint4*)(BIG + (size_t)csr[e + 1] * 2304 + kvoff);
  for (; e + 2 <= end; e += 2) {
    int i2 = e + 2 < end ? e + 2 : end - 1;
    int i3 = e + 3 < end ? e + 3 : end - 1;
    uint4 kn0 = *(const uint4*)(BIG + (size_t)csr[i2] * 2304 + kvoff);
    uint4 kn1 = *(const uint4*)(BIG + (size_t)csr[i3] * 2304 + kvoff);
    float kf[8];
    unpack8_fp8(make_uint2(kv0.x, kv0.y), kf);
    float p0 = q[0]*kf[0]+q[1]*kf[1]+q[2]*kf[2]+q[3]*kf[3]+
               q[4]*kf[4]+q[5]*kf[5]+q[6]*kf[6]+q[7]*kf[7];
    unpack8_fp8(make_uint2(kv1.x, kv1.y), kf);
    float p1 = q[0]*kf[0]+q[1]*kf[1]+q[2]*kf[2]+q[3]*kf[3]+
               q[4]*kf[4]+q[5]*kf[5]+q[6]*kf[6]+q[7]*kf[7];
#pragma unroll
    for (int ox = 1; ox <= 8; ox <<= 1) {
      p0 += __shfl_xor(p0, ox);
      p1 += __shfl_xor(p1, ox);
    }
    float w0 = __expf(p0 * INV_SQRT_CH);
    float w1 = __expf(p1 * INV_SQRT_CH);
    float vf[8];
    unpack8_fp8(make_uint2(kv0.z, kv0.w), vf);
    sA += w0;
#pragma unroll
    for (int c = 0; c < 8; ++c) aA[c] = fmaf(w0, vf[c], aA[c]);
    unpack8_fp8(make_uint2(kv1.z, kv1.w), vf);
    sB += w1;
#pragma unroll
    for (int c = 0; c < 8; ++c) aB[c] = fmaf(w1, vf[c], aB[c]);
    kv0 = kn0; kv1 = kn1;
  }
  if (e < end) {                                   // odd tail (edge in kv0)
    float kf[8];
    unpack8_fp8(make_uint2(kv0.x, kv0.y), kf);
    float p0 = q[0]*kf[0]+q[1]*kf[1]+q[2]*kf[2]+q[3]*kf[3]+
               q[4]*kf[4]+q[5]*kf[5]+q[6]*kf[6]+q[7]*kf[7];
#pragma unroll
    for (int ox = 1; ox <= 8; ox <<= 1) p0 += __shfl_xor(p0, ox);
    float w0 = __expf(p0 * INV_SQRT_CH);
    float vf[8];
    unpack8_fp8(make_uint2(kv0.z, kv0.w), vf);
    sA += w0;
#pragma unroll
    for (int c = 0; c < 8; ++c) aA[c] = fmaf(w0, vf[c], aA[c]);
  }
  float s = sA + sB;
  float inv = fastrcp(s + 1e-16f);
  float sk[8];
  unpack8(skw, sk);
  uint4 ow;
  uint_t* op = (uint_t*)&ow;
#pragma unroll
  for (int c = 0; c < 4; ++c) {
    float o0 = elu1((aA[2 * c] + aB[2 * c]) * inv + sk[2 * c]);
    float o1 = elu1((aA[2 * c + 1] + aB[2 * c + 1]) * inv + sk[2 * c + 1]);
    op[c] = (uint_t)f2bf(o0) | ((uint_t)f2bf(o1) << 16);
  }
  *(uint4*)op8 = ow;
}

// layer 2: row 2304 B: q_H @H*256, kv_H @1024+H*256, skip @2048.
// Group g = head g; 2-wide edge unroll; per-group normalize (0.25/s_g),
// 8-value cross-group sum; group 0 writes POut[i][c]. pool adds skip.
__global__ __launch_bounds__(256) void attn2_kernel(
    const char* __restrict__ BIG, const int* __restrict__ start,
    const int* __restrict__ deg, const int* __restrict__ csr,
    ushort_t* __restrict__ POut) {
  int wave = threadIdx.x >> 6, lane = threadIdx.x & 63;
  int li = lane & 15, g = lane >> 4;               // g = head
  int i = blockIdx.x * 4 + wave;
  if (i >= N_NODES) return;
  int beg = start[i], end = beg + deg[i];
  const int kvoff = 1024 + g * 256 + li * 16;
  float q[8];
  unpack8(*(const uint4*)(BIG + (size_t)i * 2304 + g * 256 + li * 16), q);
  float sA = 0.f, sB = 0.f, aA[8] = {}, aB[8] = {};
  uint4 kv0 = make_uint4(0, 0, 0, 0), kv1 = make_uint4(0, 0, 0, 0);
  int e = beg;
  if (e < end)     kv0 = *(const uint4*)(BIG + (size_t)csr[e] * 2304 + kvoff);
  if (e + 1 < end) kv1 = *(const uint4*)(BIG + (size_t)csr[e + 1] * 2304 + kvoff);
  for (; e + 2 <= end; e += 2) {
    int i2 = e + 2 < end ? e + 2 : end - 1;
    int i3 = e + 3 < end ? e + 3 : end - 1;
    uint4 kn0 = *(const uint4*)(BIG + (size_t)csr[i2] * 2304 + kvoff);
    uint4 kn1 = *(const uint4*)(BIG + (size_t)csr[i3] * 2304 + kvoff);
    float kf[8];
    unpack8_fp8(make_uint2(kv0.x, kv0.y), kf);
    float p0 = q[0]*kf[0]+q[1]*kf[1]+q[2]*kf[2]+q[3]*kf[3]+
               q[4]*kf[4]+q[5]*kf[5]+q[6]*kf[6]+q[7]*kf[7];
    unpack8_fp8(make_uint2(kv1.x, kv1.y), kf);
    float p1 = q[0]*kf[0]+q[1]*kf[1]+q[2]*kf[2]+q[3]*kf[3]+
               q[4]*kf[4]+q[5]*kf[5]+q[6]*kf[6]+q[7]*kf[7];
#pragma unroll
    for (int ox = 1; ox <= 8; ox <<= 1) {
      p0 += __shfl_xor(p0, ox);
      p1 += __shfl_xor(p1, ox);
    }
    float w0 = __expf(p0 * INV_SQRT_CH);
    float w1 = __expf(p1 * INV_SQRT_CH);
    float vf[8];
    unpack8_fp8(make_uint2(kv0.z, kv0.w), vf);
    sA += w0;
#pragma unroll
    for (int c = 0; c < 8; ++c) aA[c] = fmaf(w0, vf[c], aA[c]);
    unpack8_fp8(make_uint2(kv1.z, kv1.w), vf);
    sB += w1;
#pragma unroll
    for (int c = 0; c < 8; ++c) aB[c] = fmaf(w1, vf[c], aB[c]);
    kv0 = kn0; kv1 = kn1;
  }
  if (e < end) {
    float kf[8];
    unpack8_fp8(make_uint2(kv0.x, kv0.y), kf);
    float p0 = q[0]*kf[0]+q[1]*kf[1]+q[2]*kf[2]+q[3]*kf[3]+
               q[4]*kf[4]+q[5]*kf[5]+q[6]*kf[6]+q[7]*kf[7];
#pragma unroll
    for (int ox = 1; ox <= 8; ox <<= 1) p0 += __shfl_xor(p0, ox);
    float w0 = __expf(p0 * INV_SQRT_CH);
    float vf[8];
    unpack8_fp8(make_uint2(kv0.z, kv0.w), vf);
    sA += w0;
#pragma unroll
    for (int c = 0; c < 8; ++c) aA[c] = fmaf(w0, vf[c], aA[c]);
  }
  float s = sA + sB;
  float inv = 0.25f * fastrcp(s + 1e-16f);
  float o[8];
#pragma unroll
  for (int c = 0; c < 8; ++c) o[c] = (aA[c] + aB[c]) * inv;
#pragma unroll
  for (int ox = 16; ox <= 32; ox <<= 1)
#pragma unroll
    for (int c = 0; c < 8; ++c) o[c] += __shfl_xor(o[c], ox);
  if (g != 0) return;
  uint4 ow;
  uint_t* op = (uint_t*)&ow;
#pragma unroll
  for (int c = 0; c < 4; ++c)
    op[c] = (uint_t)f2bf(o[2 * c]) | ((uint_t)f2bf(o[2 * c + 1]) << 16);
  *(uint4*)(POut + (size_t)i * CH + li * 8) = ow;
}

// ---------------------------------------------------------------------------
// Pool (round-13 split): pool_partial runs 256x8 blocks (8 chunks/graph,
// kills the old 1-block/CU serial tail) accumulating f32 partials into
// pooled[g][c] via atomics; cls_final (1 block) does divide + logits +
// log_softmax per graph.
// ---------------------------------------------------------------------------
__global__ __launch_bounds__(256) void pool_partial(
    const ushort_t* __restrict__ POut, const char* __restrict__ BIG,
    const int* __restrict__ gstart, const int* __restrict__ gend,
    float* __restrict__ pooled) {
  int g = blockIdx.x, chunk = blockIdx.y;          // 8 chunks per graph
  int t = threadIdx.x;
  int c = t & (CH - 1), rr = t >> 7;
  int s0 = gstart[g], e0 = gend[g];
  float sum = 0.f;
  for (int i = s0 + chunk * 2 + rr; i < e0; i += 16) {
    float sk = bf2f(*(const ushort_t*)(BIG + (size_t)i * 2304 + 2048 + c * 2));
    float m0 = bf2f(POut[(size_t)i * CH + c]);
    sum += elu1(sk + m0);
  }
  atomicAdd(&pooled[g * CH + c], sum);
}

__global__ __launch_bounds__(256) void cls_final(
    const float* __restrict__ pooled, const int* __restrict__ gstart,
    const int* __restrict__ gend, const float* __restrict__ Wfc,
    const float* __restrict__ bfc, float* __restrict__ out) {
  int g = blockIdx.x * blockDim.x + threadIdx.x;   // one thread per graph
  if (g >= NGRAPH) return;
  float inv = 1.f / fmaxf((float)(gend[g] - gstart[g]), 1.f);
  float logits[NCLS];
#pragma unroll
  for (int cc = 0; cc < NCLS; ++cc) logits[cc] = bfc[cc];
  for (int c = 0; c < CH; ++c) {
    float p = pooled[g * CH + c] * inv;
#pragma unroll
    for (int cc = 0; cc < NCLS; ++cc)
      logits[cc] = fmaf(p, Wfc[c * NCLS + cc], logits[cc]);
  }
  float mx = -INFINITY;
#pragma unroll
  for (int cc = 0; cc < NCLS; ++cc) mx = fmaxf(mx, logits[cc]);
  float se = 0.f;
#pragma unroll
  for (int cc = 0; cc < NCLS; ++cc) se += expf(logits[cc] - mx);
  float ls = mx + logf(se);
#pragma unroll
  for (int cc = 0; cc < NCLS; ++cc) out[g * NCLS + cc] = logits[cc] - ls;
}

// ---------------------------------------------------------------------------
extern "C" void kernel_launch(void* const* d_in, const int* in_sizes, int n_in,
                              void* d_out, int out_size, void* d_ws, size_t ws_size,
                              hipStream_t stream) {
  const float* x    = (const float*)d_in[0];
  const int*   ei   = (const int*)d_in[1];
  const int*   batch= (const int*)d_in[2];
  const float* Wq1 = (const float*)d_in[3];  const float* bq1 = (const float*)d_in[4];
  const float* Wk1 = (const float*)d_in[5];  const float* bk1 = (const float*)d_in[6];
  const float* Wv1 = (const float*)d_in[7];  const float* bv1 = (const float*)d_in[8];
  const float* Ws1 = (const float*)d_in[9];  const float* bs1 = (const float*)d_in[10];
  const float* Wq2 = (const float*)d_in[11]; const float* bq2 = (const float*)d_in[12];
  const float* Wk2 = (const float*)d_in[13]; const float* bk2 = (const float*)d_in[14];
  const float* Wv2 = (const float*)d_in[15]; const float* bv2 = (const float*)d_in[16];
  const float* Ws2 = (const float*)d_in[17]; const float* bs2 = (const float*)d_in[18];
  const float* Wfc = (const float*)d_in[19]; const float* bfc = (const float*)d_in[20];
  float* out = (float*)d_out;

  // Workspace (~195 MB). POut (bf16 N*128 = 12.8MB) aliases xb (dead after
  // L1 GEMM). BIG rows are 2304 B for BOTH layers.
  ushort_t* xb     = (ushort_t*)d_ws;                   // N x 256 bf16 (25.6 MB)
  ushort_t* POut   = (ushort_t*)d_ws;                   // N x 128 bf16 (alias)
  char*     BIG    = (char*)(xb + (size_t)N_NODES * FEAT);  // N x 2304 B (115.2 MB)
  ushort_t* H1b    = (ushort_t*)(BIG + (size_t)N_NODES * 2304); // N x 512 bf16
  ushort_t* W1t    = H1b + (size_t)N_NODES * HID;       // 2048*256
  float*    Bh1    = (float*)(W1t + L1_W);              // 2048
  ushort_t* W2t    = (ushort_t*)(Bh1 + 2048);           // 1664*512
  float*    Bh2    = (float*)(W2t + L2_W);              // 1664
  int* deg    = (int*)(Bh2 + 1664);
  int* start  = deg + N_NODES;
  int* cursor = start + N_NODES;
  int* csr    = cursor + N_NODES;
  int* gstart = csr + EDGES;
  int* gend   = gstart + NGRAPH;
  int* counter= gend + NGRAPH;
  float* pooled = (float*)(counter + 1);                // 256*128 f32 (128 KB)

  const int* srcp = ei;
  const int* dstp = ei + EDGES;

  // ---- prep (single launch) + CSR build ----
  prep_all<<<NB_CVT + NB_TP + NB_BIAS + NB_ZERO, 256, 0, stream>>>(
      x, xb, Wq1, Wk1, Wv1, Ws1, Wq2, Wk2, Wv2, Ws2,
      bq1, bk1, bv1, bs1, bq2, bk2, bv2, bs2,
      W1t, W2t, Bh1, Bh2, deg, counter, gstart, gend, pooled);
  hist_bounds_kernel<<<(EDGES + 255) / 256, 256, 0, stream>>>(dstp, deg, batch, gstart, gend);
  alloc_kernel<<<(N_NODES + 255) / 256, 256, 0, stream>>>(deg, counter, start, cursor);
  scatter_kernel<<<(EDGES + 255) / 256, 256, 0, stream>>>(srcp, dstp, cursor, csr);

  const int ga = (N_NODES + 3) / 4;     // 12500

  // ---- layer 1: ONE GEMM (N=2048, 16 col tiles; q/kv -> BIG, s -> H1b),
  //      then ONE all-4-head attention (writes elu(msg+s) into H1b) ----
  gemm_bt<<<49 * 8 * 16, 256, 0, stream>>>(
      xb, W1t, Bh1, BIG, (char*)H1b, N_NODES, FEAT, 16, 1);
  attn1_kernel<<<ga, 256, 0, stream>>>(BIG, start, deg, csr, H1b);

  // ---- layer 2: ONE GEMM (13 col tiles, mode 2) + merged attention ----
  gemm_bt<<<49 * 8 * 13, 256, 0, stream>>>(
      H1b, W2t, Bh2, BIG, (char*)H1b, N_NODES, HID, 13, 2);
  attn2_kernel<<<ga, 256, 0, stream>>>(BIG, start, deg, csr, POut);

  // ---- pool (parallel partials + atomics) + classifier ----
  pool_partial<<<dim3(NGRAPH, 8), 256, 0, stream>>>(POut, BIG, gstart, gend, pooled);
  cls_final<<<1, 256, 0, stream>>>(pooled, gstart, gend, Wfc, bfc, out);
}